// Round 2
// baseline (10789.964 us; speedup 1.0000x reference)
//
#include <hip/hip_runtime.h>

#define N_NODES  50000
#define N_EDGES  400000
#define DIM      128
#define N_MOVIE  20400
#define N_GENRE  30
#define L_MAX    680
#define NROWS    (N_GENRE * L_MAX)   /* 20400 */
#define FF       2048
#define N_LAYERS 4

typedef __attribute__((ext_vector_type(8))) short bf16x8;
typedef __attribute__((ext_vector_type(4))) float f32x4;

#define MFMA16 __builtin_amdgcn_mfma_f32_16x16x32_bf16

__device__ __forceinline__ ushort f2b(float f) {
    union { float f; unsigned i; } c; c.f = f;
    unsigned u = c.i;
    u += 0x7FFFu + ((u >> 16) & 1u);   // RNE
    return (ushort)(u >> 16);
}

// fp32 -> bf16x8 fragment (two float4 loads + RNE round)
__device__ __forceinline__ bf16x8 load8f(const float* p) {
    const float4* q = (const float4*)p;
    float4 a = q[0], b = q[1];
    bf16x8 r;
    r[0] = (short)f2b(a.x); r[1] = (short)f2b(a.y);
    r[2] = (short)f2b(a.z); r[3] = (short)f2b(a.w);
    r[4] = (short)f2b(b.x); r[5] = (short)f2b(b.y);
    r[6] = (short)f2b(b.z); r[7] = (short)f2b(b.w);
    return r;
}

// C[M,N] = epi( A[M,K] @ W[N,K]^T + bias )   (A, W fp32; bf16 MFMA internally)
// ACT: 0 none, 1 leaky(0.01), 2 relu.  EPI: 0 store, 1 C += scale*v.
template<int ACT, int EPI>
__global__ __launch_bounds__(256) void gemm_bt(
    const float* __restrict__ A, const float* __restrict__ W,
    const float* __restrict__ bias, float* __restrict__ C,
    int M, int N, int K, float scale)
{
    const int tid  = threadIdx.x;
    const int wave = tid >> 6, lane = tid & 63;
    const int quad = lane >> 4, l16 = lane & 15;
    const int m0 = blockIdx.x * 64 + (wave & 1) * 32;
    const int n0 = blockIdx.y * 64 + (wave >> 1) * 32;

    f32x4 acc[2][2] = {};
    for (int k0 = 0; k0 < K; k0 += 32) {
        const int kk = k0 + quad * 8;
        int r0 = m0 + l16;      if (r0 >= M) r0 = M - 1;
        int r1 = m0 + 16 + l16; if (r1 >= M) r1 = M - 1;
        bf16x8 a0 = load8f(A + (size_t)r0 * K + kk);
        bf16x8 a1 = load8f(A + (size_t)r1 * K + kk);
        bf16x8 b0 = load8f(W + (size_t)(n0 + l16) * K + kk);
        bf16x8 b1 = load8f(W + (size_t)(n0 + 16 + l16) * K + kk);
        acc[0][0] = MFMA16(a0, b0, acc[0][0], 0, 0, 0);
        acc[0][1] = MFMA16(a0, b1, acc[0][1], 0, 0, 0);
        acc[1][0] = MFMA16(a1, b0, acc[1][0], 0, 0, 0);
        acc[1][1] = MFMA16(a1, b1, acc[1][1], 0, 0, 0);
    }
#pragma unroll
    for (int j = 0; j < 2; j++) {
        const int col = n0 + j * 16 + l16;
        const float bv = bias ? bias[col] : 0.f;
#pragma unroll
        for (int i = 0; i < 2; i++) {
#pragma unroll
            for (int r = 0; r < 4; r++) {
                const int row = m0 + i * 16 + quad * 4 + r;
                if (row < M) {
                    float v = acc[i][j][r] + bv;
                    if (ACT == 1) v = (v >= 0.f) ? v : 0.01f * v;
                    if (ACT == 2) v = fmaxf(v, 0.f);
                    const size_t idx = (size_t)row * N + col;
                    if (EPI == 1) C[idx] += scale * v;
                    else          C[idx] = v;
                }
            }
        }
    }
}

// per-(node,head) attention logit halves
__global__ void gat_al(const float* __restrict__ h,
                       const float* __restrict__ asrc, const float* __restrict__ adst,
                       float* __restrict__ als, float* __restrict__ ald, int N)
{
    int idx = blockIdx.x * blockDim.x + threadIdx.x;
    if (idx >= N * 4) return;
    int n = idx >> 2, hh = idx & 3;
    const float* hp = h + (size_t)n * DIM + hh * 32;
    float s = 0.f, d = 0.f;
#pragma unroll 8
    for (int c = 0; c < 32; c++) {
        float v = hp[c];
        s += v * asrc[hh * 32 + c];
        d += v * adst[hh * 32 + c];
    }
    als[idx] = s; ald[idx] = d;
}

// one wave per edge (incl. self loops): out[dst] += w_h * h[src], den[dst] += w_h
__global__ __launch_bounds__(256) void gat_edge(
    const int* __restrict__ esrc, const int* __restrict__ edst, int E, int N,
    const float* __restrict__ h, const float* __restrict__ als,
    const float* __restrict__ ald, float* __restrict__ outbuf, float* __restrict__ den)
{
    int gw = (blockIdx.x * 256 + threadIdx.x) >> 6;
    int lane = threadIdx.x & 63;
    if (gw >= E + N) return;
    int s, d;
    if (gw < E) { s = esrc[gw]; d = edst[gw]; } else { s = d = gw - E; }
    float4 as4 = *(const float4*)(als + (size_t)s * 4);
    float4 ad4 = *(const float4*)(ald + (size_t)d * 4);
    float w[4];
#pragma unroll
    for (int hh = 0; hh < 4; hh++) {
        float e = (&as4.x)[hh] + (&ad4.x)[hh];
        e = (e >= 0.f) ? e : 0.2f * e;
        w[hh] = __expf(e);   // logits |e| small by construction: max-subtract cancels
    }
    if (lane < 4) atomicAdd(den + (size_t)d * 4 + lane, w[lane]);
    float h0 = h[(size_t)s * DIM + lane];
    float h1 = h[(size_t)s * DIM + 64 + lane];
    atomicAdd(outbuf + (size_t)d * DIM + lane,      w[lane >> 5] * h0);
    atomicAdd(outbuf + (size_t)d * DIM + 64 + lane, w[2 + (lane >> 5)] * h1);
}

__global__ void gat_norm(float* __restrict__ outbuf, const float* __restrict__ den,
                         const float* __restrict__ bias)
{
    int idx = blockIdx.x * 256 + threadIdx.x;   // N_NODES*128 total
    int n = idx >> 7, c = idx & 127;
    outbuf[idx] = outbuf[idx] / den[(size_t)n * 4 + (c >> 5)] + bias[c];
}

__global__ void calc_pos(const int* __restrict__ genre, int* __restrict__ pos,
                         int* __restrict__ cnt, int NM)
{
    int i = blockIdx.x * blockDim.x + threadIdx.x;
    if (i < NM) pos[i] = atomicAdd(&cnt[genre[i]], 1);
}

__global__ void build_y(const float* __restrict__ acc, const int* __restrict__ midx,
                        const int* __restrict__ genre, const int* __restrict__ pos,
                        float* __restrict__ y)
{
    int i = blockIdx.x, c = threadIdx.x;
    int g = genre[i], p = pos[i];
    y[((size_t)g * L_MAX + p) * DIM + c] = acc[(size_t)midx[i] * DIM + c];
}

// one block per (q-pos, head, local-genre); qkv is a 6-genre chunk [6*L_MAX, 384]
__global__ __launch_bounds__(256) void attn_kernel(
    const float* __restrict__ qkv, const int* __restrict__ cnt, int gbase,
    float* __restrict__ o)
{
    __shared__ float sc[L_MAX];
    __shared__ float qsh[32];
    __shared__ float wsum[4];
    __shared__ float av[8][33];

    const int s = blockIdx.x, hh = blockIdx.y, b = blockIdx.z;
    const int t = threadIdx.x;
    const int L = cnt[gbase + b];
    const size_t rowbase = (size_t)(b * L_MAX + s) * 384;

    if (s >= L) {                       // padding position: output unused, zero it
        if (t < 32) o[(size_t)(b * L_MAX + s) * DIM + hh * 32 + t] = 0.f;
        return;
    }
    if (t < 32) qsh[t] = qkv[rowbase + hh * 32 + t];
    __syncthreads();

    const float scale = 0.17677669529663687f;   // 1/sqrt(32)
    for (int k = t; k < L; k += 256) {
        const float* krow = qkv + (size_t)(b * L_MAX + k) * 384 + 128 + hh * 32;
        float a = 0.f;
#pragma unroll 8
        for (int c = 0; c < 32; c++) a += qsh[c] * krow[c];
        sc[k] = __expf(a * scale);      // logits provably small: skip max-subtract
    }
    __syncthreads();

    float psum = 0.f;
    for (int k = t; k < L; k += 256) psum += sc[k];
    for (int off = 32; off; off >>= 1) psum += __shfl_down(psum, off, 64);
    if ((t & 63) == 0) wsum[t >> 6] = psum;
    __syncthreads();
    const float inv = 1.f / (wsum[0] + wsum[1] + wsum[2] + wsum[3]);

    const int d = t & 31, grp = t >> 5;
    float a = 0.f;
    for (int k = grp; k < L; k += 8)
        a += sc[k] * qkv[(size_t)(b * L_MAX + k) * 384 + 256 + hh * 32 + d];
    av[grp][d] = a;
    __syncthreads();
    if (t < 32) {
        float r = 0.f;
#pragma unroll
        for (int g2 = 0; g2 < 8; g2++) r += av[g2][t];
        o[(size_t)(b * L_MAX + s) * DIM + hh * 32 + t] = r * inv;
    }
}

// y = LN(y + res) * g + b   (one 128-thread block per row)
__global__ __launch_bounds__(128) void ln_res(
    float* __restrict__ y, const float* __restrict__ res,
    const float* __restrict__ g, const float* __restrict__ b)
{
    __shared__ float sh[2], sh2[2];
    const int r = blockIdx.x, t = threadIdx.x;
    const size_t base = (size_t)r * DIM;
    float v = y[base + t] + res[base + t];
    float s = v;
    for (int off = 32; off; off >>= 1) s += __shfl_down(s, off, 64);
    if ((t & 63) == 0) sh[t >> 6] = s;
    __syncthreads();
    const float mean = (sh[0] + sh[1]) * (1.f / 128.f);
    const float d = v - mean;
    float q = d * d;
    for (int off = 32; off; off >>= 1) q += __shfl_down(q, off, 64);
    if ((t & 63) == 0) sh2[t >> 6] = q;
    __syncthreads();
    const float var = (sh2[0] + sh2[1]) * (1.f / 128.f);
    y[base + t] = d * rsqrtf(var + 1e-5f) * g[t] + b[t];
}

__global__ void pool_kernel(const float* __restrict__ y, const int* __restrict__ cnt,
                            float* __restrict__ pooled)
{
    const int g = blockIdx.x, c = threadIdx.x;
    const int L = cnt[g];
    float s = 0.f;
    for (int k = 0; k < L; k++) s += y[((size_t)g * L_MAX + k) * DIM + c];
    pooled[g * DIM + c] = s / (float)max(L, 1);
}

__global__ void build_fin(const float* __restrict__ acc, const float* __restrict__ pooled,
                          const int* __restrict__ midx, const int* __restrict__ genre,
                          float* __restrict__ A2)
{
    const int i = blockIdx.x, t = threadIdx.x;
    A2[(size_t)i * 256 + t] = (t < 128)
        ? acc[(size_t)midx[i] * DIM + t]
        : pooled[genre[i] * DIM + (t - 128)];
}

__global__ void scatter_movies(const float* __restrict__ fused, const int* __restrict__ midx,
                               float* __restrict__ out)
{
    const int i = blockIdx.x, c = threadIdx.x;
    out[(size_t)midx[i] * DIM + c] = fused[(size_t)i * DIM + c];
}

extern "C" void kernel_launch(void* const* d_in, const int* in_sizes, int n_in,
                              void* d_out, int out_size, void* d_ws, size_t ws_size,
                              hipStream_t stream)
{
    const float* x      = (const float*)d_in[0];
    const int* e[3]     = { (const int*)d_in[1], (const int*)d_in[2], (const int*)d_in[3] };
    const int* midx     = (const int*)d_in[4];
    const int* genre    = (const int*)d_in[5];
    const float* gatW   = (const float*)d_in[6];
    const float* attS   = (const float*)d_in[7];
    const float* attD   = (const float*)d_in[8];
    const float* gatB   = (const float*)d_in[9];
    const float* decW   = (const float*)d_in[10];
    const float* decB   = (const float*)d_in[11];
    const float* qkvW   = (const float*)d_in[12];
    const float* qkvB   = (const float*)d_in[13];
    const float* outW   = (const float*)d_in[14];
    const float* outB   = (const float*)d_in[15];
    const float* ln1g   = (const float*)d_in[16];
    const float* ln1b   = (const float*)d_in[17];
    const float* ln2g   = (const float*)d_in[18];
    const float* ln2b   = (const float*)d_in[19];
    const float* fw1    = (const float*)d_in[20];
    const float* fb1    = (const float*)d_in[21];
    const float* fw2    = (const float*)d_in[22];
    const float* fb2    = (const float*)d_in[23];
    const float* fusW   = (const float*)d_in[24];
    const float* fusB   = (const float*)d_in[25];
    float* out = (float*)d_out;

    // ---- workspace layout (floats); peak ~97 MB ----
    float* ws   = (float*)d_ws;
    float* acc  = ws;                       // 6,400,000
    float* R    = ws + 6400000;
    // stage A:
    float* hbuf = R;                        // 6,400,000
    float* gbuf = hbuf + 6400000;           // 6,400,000
    float* als  = gbuf + 6400000;           // 200,000
    float* ald  = als + 200000;             // 200,000
    float* den  = ald + 200000;             // 200,000
    // stage B (aliases stage A region):
    float* ybuf   = R;                      // 2,611,200
    float* tmp    = ybuf + 2611200;         // 2,611,200
    float* attnb  = tmp + 2611200;          // 2,611,200 (also fused output)
    float* qkvc   = attnb + 2611200;        // 1,566,720 (6-genre qkv chunk)
    float* mid    = qkvc + 1566720;         // 8,355,840 (FFN chunk; also A2)
    float* pooled = mid + 8355840;          // 3,840
    int*   cntb   = (int*)(pooled + 3840);  // 32
    int*   posb   = cntb + 32;              // 20,400

    const float decay[3] = { 1.0f, 0.90483741803595952f, 0.81873075307798182f };

    // ================= Stage A: 3-hop GAT =================
    hipMemsetAsync(acc, 0, (size_t)6400000 * 4, stream);
    for (int k = 0; k < 3; k++) {
        gemm_bt<0, 0><<<dim3(782, 2), 256, 0, stream>>>(
            x, gatW + k * DIM * DIM, (const float*)nullptr, hbuf, N_NODES, DIM, DIM, 1.f);
        gat_al<<<(N_NODES * 4 + 255) / 256, 256, 0, stream>>>(
            hbuf, attS + k * DIM, attD + k * DIM, als, ald, N_NODES);
        hipMemsetAsync(gbuf, 0, (size_t)6400000 * 4, stream);
        hipMemsetAsync(den, 0, (size_t)200000 * 4, stream);
        {
            int waves = N_EDGES + N_NODES;   // 450000, exactly divisible by 4
            gat_edge<<<waves / 4, 256, 0, stream>>>(
                e[k], e[k] + N_EDGES, N_EDGES, N_NODES, hbuf, als, ald, gbuf, den);
        }
        gat_norm<<<25000, 256, 0, stream>>>(gbuf, den, gatB + k * DIM);
        gemm_bt<1, 1><<<dim3(782, 2), 256, 0, stream>>>(
            gbuf, decW + k * DIM * DIM, decB + k * DIM, acc, N_NODES, DIM, DIM, decay[k]);
    }

    // ================= Stage B: genre transformer =================
    hipMemsetAsync(cntb, 0, 32 * 4, stream);
    calc_pos<<<(N_MOVIE + 255) / 256, 256, 0, stream>>>(genre, posb, cntb, N_MOVIE);
    hipMemsetAsync(ybuf, 0, (size_t)2611200 * 4, stream);
    build_y<<<N_MOVIE, 128, 0, stream>>>(acc, midx, genre, posb, ybuf);

    const int CH_ROWS = 6 * L_MAX;   // 4080 rows = 6 genres per chunk
    for (int l = 0; l < N_LAYERS; l++) {
        for (int ch = 0; ch < 5; ch++) {
            const size_t ro = (size_t)ch * CH_ROWS * DIM;
            gemm_bt<0, 0><<<dim3(64, 6), 256, 0, stream>>>(
                ybuf + ro, qkvW + (size_t)l * 384 * DIM, qkvB + l * 384,
                qkvc, CH_ROWS, 384, DIM, 1.f);
            attn_kernel<<<dim3(L_MAX, 4, 6), 256, 0, stream>>>(
                qkvc, cntb, ch * 6, attnb + ro);
            gemm_bt<0, 0><<<dim3(64, 2), 256, 0, stream>>>(
                attnb + ro, outW + (size_t)l * DIM * DIM, outB + l * DIM,
                tmp + ro, CH_ROWS, DIM, DIM, 1.f);
        }
        ln_res<<<NROWS, 128, 0, stream>>>(ybuf, tmp, ln1g + l * DIM, ln1b + l * DIM);
        for (int ch = 0; ch < 5; ch++) {
            const size_t ro = (size_t)ch * CH_ROWS * DIM;
            gemm_bt<2, 0><<<dim3(64, 32), 256, 0, stream>>>(
                ybuf + ro, fw1 + (size_t)l * FF * DIM, fb1 + l * FF,
                mid, CH_ROWS, FF, DIM, 1.f);
            gemm_bt<0, 0><<<dim3(64, 2), 256, 0, stream>>>(
                mid, fw2 + (size_t)l * FF * DIM, fb2 + l * DIM,
                tmp + ro, CH_ROWS, DIM, FF, 1.f);
        }
        ln_res<<<NROWS, 128, 0, stream>>>(ybuf, tmp, ln2g + l * DIM, ln2b + l * DIM);
    }

    pool_kernel<<<N_GENRE, 128, 0, stream>>>(ybuf, cntb, pooled);
    build_fin<<<N_MOVIE, 256, 0, stream>>>(acc, pooled, midx, genre, mid);
    gemm_bt<1, 0><<<dim3(319, 2), 256, 0, stream>>>(
        mid, fusW, fusB, attnb, NROWS, DIM, 256, 1.f);

    hipMemcpyAsync(out, acc, (size_t)6400000 * 4, hipMemcpyDeviceToDevice, stream);
    scatter_movies<<<N_MOVIE, 128, 0, stream>>>(attnb, midx, out);
}

// Round 3
// 4984.651 us; speedup vs baseline: 2.1646x; 2.1646x over previous
//
#include <hip/hip_runtime.h>

#define N_NODES  50000
#define N_EDGES  400000
#define DIM      128
#define N_MOVIE  20400
#define N_GENRE  30
#define L_MAX    680
#define NROWS    (N_GENRE * L_MAX)   /* 20400 */
#define FF       2048
#define N_LAYERS 4

typedef __attribute__((ext_vector_type(8))) short bf16x8;
typedef __attribute__((ext_vector_type(4))) float f32x4;

#define MFMA16 __builtin_amdgcn_mfma_f32_16x16x32_bf16

__device__ __forceinline__ ushort f2b(float f) {
    union { float f; unsigned i; } c; c.f = f;
    unsigned u = c.i;
    u += 0x7FFFu + ((u >> 16) & 1u);   // RNE
    return (ushort)(u >> 16);
}

// fp32 -> bf16x8 fragment (two float4 loads + RNE round)
__device__ __forceinline__ bf16x8 load8f(const float* p) {
    const float4* q = (const float4*)p;
    float4 a = q[0], b = q[1];
    bf16x8 r;
    r[0] = (short)f2b(a.x); r[1] = (short)f2b(a.y);
    r[2] = (short)f2b(a.z); r[3] = (short)f2b(a.w);
    r[4] = (short)f2b(b.x); r[5] = (short)f2b(b.y);
    r[6] = (short)f2b(b.z); r[7] = (short)f2b(b.w);
    return r;
}

__device__ __forceinline__ bf16x8 load8s(const ushort* p) {
    return *(const bf16x8*)p;
}

// C[M,N] = epi( A[M,K] @ W[N,K]^T + bias )   (A, W fp32; bf16 MFMA internally)
// ACT: 0 none, 1 leaky(0.01), 2 relu.  EPI: 0 store, 1 C += scale*v.
template<int ACT, int EPI>
__global__ __launch_bounds__(256) void gemm_bt(
    const float* __restrict__ A, const float* __restrict__ W,
    const float* __restrict__ bias, float* __restrict__ C,
    int M, int N, int K, float scale)
{
    const int tid  = threadIdx.x;
    const int wave = tid >> 6, lane = tid & 63;
    const int quad = lane >> 4, l16 = lane & 15;
    const int m0 = blockIdx.x * 64 + (wave & 1) * 32;
    const int n0 = blockIdx.y * 64 + (wave >> 1) * 32;

    f32x4 acc[2][2] = {};
    for (int k0 = 0; k0 < K; k0 += 32) {
        const int kk = k0 + quad * 8;
        int r0 = m0 + l16;      if (r0 >= M) r0 = M - 1;
        int r1 = m0 + 16 + l16; if (r1 >= M) r1 = M - 1;
        bf16x8 a0 = load8f(A + (size_t)r0 * K + kk);
        bf16x8 a1 = load8f(A + (size_t)r1 * K + kk);
        bf16x8 b0 = load8f(W + (size_t)(n0 + l16) * K + kk);
        bf16x8 b1 = load8f(W + (size_t)(n0 + 16 + l16) * K + kk);
        acc[0][0] = MFMA16(a0, b0, acc[0][0], 0, 0, 0);
        acc[0][1] = MFMA16(a0, b1, acc[0][1], 0, 0, 0);
        acc[1][0] = MFMA16(a1, b0, acc[1][0], 0, 0, 0);
        acc[1][1] = MFMA16(a1, b1, acc[1][1], 0, 0, 0);
    }
#pragma unroll
    for (int j = 0; j < 2; j++) {
        const int col = n0 + j * 16 + l16;
        const float bv = bias ? bias[col] : 0.f;
#pragma unroll
        for (int i = 0; i < 2; i++) {
#pragma unroll
            for (int r = 0; r < 4; r++) {
                const int row = m0 + i * 16 + quad * 4 + r;
                if (row < M) {
                    float v = acc[i][j][r] + bv;
                    if (ACT == 1) v = (v >= 0.f) ? v : 0.01f * v;
                    if (ACT == 2) v = fmaxf(v, 0.f);
                    const size_t idx = (size_t)row * N + col;
                    if (EPI == 1) C[idx] += scale * v;
                    else          C[idx] = v;
                }
            }
        }
    }
}

// per-(node,head) attention logit halves
__global__ void gat_al(const float* __restrict__ h,
                       const float* __restrict__ asrc, const float* __restrict__ adst,
                       float* __restrict__ als, float* __restrict__ ald, int N)
{
    int idx = blockIdx.x * blockDim.x + threadIdx.x;
    if (idx >= N * 4) return;
    int n = idx >> 2, hh = idx & 3;
    const float* hp = h + (size_t)n * DIM + hh * 32;
    float s = 0.f, d = 0.f;
#pragma unroll 8
    for (int c = 0; c < 32; c++) {
        float v = hp[c];
        s += v * asrc[hh * 32 + c];
        d += v * adst[hh * 32 + c];
    }
    als[idx] = s; ald[idx] = d;
}

// one wave per edge (incl. self loops): out[dst] += w_h * h[src], den[dst] += w_h
__global__ __launch_bounds__(256) void gat_edge(
    const int* __restrict__ esrc, const int* __restrict__ edst, int E, int N,
    const float* __restrict__ h, const float* __restrict__ als,
    const float* __restrict__ ald, float* __restrict__ outbuf, float* __restrict__ den)
{
    int gw = (blockIdx.x * 256 + threadIdx.x) >> 6;
    int lane = threadIdx.x & 63;
    if (gw >= E + N) return;
    int s, d;
    if (gw < E) { s = esrc[gw]; d = edst[gw]; } else { s = d = gw - E; }
    float4 as4 = *(const float4*)(als + (size_t)s * 4);
    float4 ad4 = *(const float4*)(ald + (size_t)d * 4);
    float w[4];
#pragma unroll
    for (int hh = 0; hh < 4; hh++) {
        float e = (&as4.x)[hh] + (&ad4.x)[hh];
        e = (e >= 0.f) ? e : 0.2f * e;
        w[hh] = __expf(e);   // logits |e| small by construction: max-subtract cancels
    }
    if (lane < 4) atomicAdd(den + (size_t)d * 4 + lane, w[lane]);
    float h0 = h[(size_t)s * DIM + lane];
    float h1 = h[(size_t)s * DIM + 64 + lane];
    atomicAdd(outbuf + (size_t)d * DIM + lane,      w[lane >> 5] * h0);
    atomicAdd(outbuf + (size_t)d * DIM + 64 + lane, w[2 + (lane >> 5)] * h1);
}

__global__ void gat_norm(float* __restrict__ outbuf, const float* __restrict__ den,
                         const float* __restrict__ bias)
{
    int idx = blockIdx.x * 256 + threadIdx.x;   // N_NODES*128 total
    int n = idx >> 7, c = idx & 127;
    outbuf[idx] = outbuf[idx] / den[(size_t)n * 4 + (c >> 5)] + bias[c];
}

__global__ void calc_pos(const int* __restrict__ genre, int* __restrict__ pos,
                         int* __restrict__ cnt, int NM)
{
    int i = blockIdx.x * blockDim.x + threadIdx.x;
    if (i < NM) pos[i] = atomicAdd(&cnt[genre[i]], 1);
}

__global__ void build_y(const float* __restrict__ acc, const int* __restrict__ midx,
                        const int* __restrict__ genre, const int* __restrict__ pos,
                        float* __restrict__ y)
{
    int i = blockIdx.x, c = threadIdx.x;
    int g = genre[i], p = pos[i];
    y[((size_t)g * L_MAX + p) * DIM + c] = acc[(size_t)midx[i] * DIM + c];
}

// ===================== MFMA flash attention =====================
// grid (qt=6, head=4, genre=30); block 256 = 4 waves, each wave 32 q-rows.
#define SV 712   /* vT row stride in shorts: 1424 B = 89*16, aligned b128 rows */
#define SP 40    /* P row stride in shorts: 80 B, aligned b128 rows */

__global__ __launch_bounds__(256) void flash_attn(
    const float* __restrict__ qkv, const int* __restrict__ cnt,
    float* __restrict__ o)
{
    __shared__ ushort vT[32 * SV];        // 45568 B
    __shared__ ushort Pb[4][32 * SP];     // 10240 B  (per-wave P tile)

    const int qt = blockIdx.x, hh = blockIdx.y, g = blockIdx.z;
    const int t = threadIdx.x, wave = t >> 6, lane = t & 63;
    const int quad = lane >> 4, l16 = lane & 15;
    const int L = cnt[g];
    const float scale = 0.17677669529663687f;   // 1/sqrt(32)
    const float* base = qkv + (size_t)g * L_MAX * 384;

    // stage 1: V^T (bf16) into LDS, zero-padded to k=704
    for (int i = t; i < L_MAX * 32; i += 256) {
        int k = i >> 5, d = i & 31;
        float v = (k < L) ? base[(size_t)k * 384 + 256 + hh * 32 + d] : 0.f;
        vT[d * SV + k] = f2b(v);
    }
    for (int i = t; i < 32 * 32; i += 256) {
        int k = L_MAX + (i & 31), d = i >> 5;
        if (k < 704) vT[d * SV + k] = 0;
    }
    __syncthreads();

    // Q fragments for this wave's 32 rows (held across the whole k-loop)
    const int q0 = qt * 128 + wave * 32;
    const int rq0 = min(q0 + l16, L_MAX - 1);
    const int rq1 = min(q0 + 16 + l16, L_MAX - 1);
    bf16x8 a0 = load8f(base + (size_t)rq0 * 384 + hh * 32 + quad * 8);
    bf16x8 a1 = load8f(base + (size_t)rq1 * 384 + hh * 32 + quad * 8);

    f32x4 oacc[2][2] = {};
    float rsum[2][4] = {};
    ushort* P = Pb[wave];

    for (int kt = 0; kt < 704; kt += 32) {
        const int rk0 = min(kt + l16, L_MAX - 1);
        const int rk1 = min(kt + 16 + l16, L_MAX - 1);
        bf16x8 b0 = load8f(base + (size_t)rk0 * 384 + 128 + hh * 32 + quad * 8);
        bf16x8 b1 = load8f(base + (size_t)rk1 * 384 + 128 + hh * 32 + quad * 8);
        f32x4 z = {};
        f32x4 s[2][2];
        s[0][0] = MFMA16(a0, b0, z, 0, 0, 0);
        s[0][1] = MFMA16(a0, b1, z, 0, 0, 0);
        s[1][0] = MFMA16(a1, b0, z, 0, 0, 0);
        s[1][1] = MFMA16(a1, b1, z, 0, 0, 0);

#pragma unroll
        for (int mi = 0; mi < 2; mi++)
#pragma unroll
            for (int j = 0; j < 2; j++) {
                const int kc = kt + j * 16 + l16;
                const bool ok = kc < L;
#pragma unroll
                for (int r = 0; r < 4; r++) {
                    float w = ok ? __expf(s[mi][j][r] * scale) : 0.f;
                    rsum[mi][r] += w;
                    P[(mi * 16 + quad * 4 + r) * SP + j * 16 + l16] = f2b(w);
                }
            }
        __syncthreads();   // make wave's P writes readable (and defeat reorder)

        bf16x8 p0 = load8s(P + (size_t)l16 * SP + quad * 8);
        bf16x8 p1 = load8s(P + (size_t)(16 + l16) * SP + quad * 8);
        bf16x8 v0 = load8s(vT + (size_t)l16 * SV + kt + quad * 8);
        bf16x8 v1 = load8s(vT + (size_t)(16 + l16) * SV + kt + quad * 8);
        oacc[0][0] = MFMA16(p0, v0, oacc[0][0], 0, 0, 0);
        oacc[0][1] = MFMA16(p0, v1, oacc[0][1], 0, 0, 0);
        oacc[1][0] = MFMA16(p1, v0, oacc[1][0], 0, 0, 0);
        oacc[1][1] = MFMA16(p1, v1, oacc[1][1], 0, 0, 0);
        __syncthreads();   // WAR: next iter rewrites P
    }

    // row-sum: reduce across the 16 lanes of each row group (lane bits 0..3)
#pragma unroll
    for (int mi = 0; mi < 2; mi++)
#pragma unroll
        for (int r = 0; r < 4; r++) {
            float s = rsum[mi][r];
            s += __shfl_xor(s, 1, 64);
            s += __shfl_xor(s, 2, 64);
            s += __shfl_xor(s, 4, 64);
            s += __shfl_xor(s, 8, 64);
            rsum[mi][r] = s;
        }

#pragma unroll
    for (int mi = 0; mi < 2; mi++)
#pragma unroll
        for (int j = 0; j < 2; j++)
#pragma unroll
            for (int r = 0; r < 4; r++) {
                const int q = q0 + mi * 16 + quad * 4 + r;
                if (q < L_MAX)
                    o[((size_t)(g * L_MAX + q)) * DIM + hh * 32 + j * 16 + l16] =
                        oacc[mi][j][r] / rsum[mi][r];
            }
}

// y = LN(y + res) * g + b   (one 128-thread block per row)
__global__ __launch_bounds__(128) void ln_res(
    float* __restrict__ y, const float* __restrict__ res,
    const float* __restrict__ g, const float* __restrict__ b)
{
    __shared__ float sh[2], sh2[2];
    const int r = blockIdx.x, t = threadIdx.x;
    const size_t base = (size_t)r * DIM;
    float v = y[base + t] + res[base + t];
    float s = v;
    for (int off = 32; off; off >>= 1) s += __shfl_down(s, off, 64);
    if ((t & 63) == 0) sh[t >> 6] = s;
    __syncthreads();
    const float mean = (sh[0] + sh[1]) * (1.f / 128.f);
    const float d = v - mean;
    float q = d * d;
    for (int off = 32; off; off >>= 1) q += __shfl_down(q, off, 64);
    if ((t & 63) == 0) sh2[t >> 6] = q;
    __syncthreads();
    const float var = (sh2[0] + sh2[1]) * (1.f / 128.f);
    y[base + t] = d * rsqrtf(var + 1e-5f) * g[t] + b[t];
}

__global__ void pool_kernel(const float* __restrict__ y, const int* __restrict__ cnt,
                            float* __restrict__ pooled)
{
    const int g = blockIdx.x, c = threadIdx.x;
    const int L = cnt[g];
    float s = 0.f;
    for (int k = 0; k < L; k++) s += y[((size_t)g * L_MAX + k) * DIM + c];
    pooled[g * DIM + c] = s / (float)max(L, 1);
}

__global__ void build_fin(const float* __restrict__ acc, const float* __restrict__ pooled,
                          const int* __restrict__ midx, const int* __restrict__ genre,
                          float* __restrict__ A2)
{
    const int i = blockIdx.x, t = threadIdx.x;
    A2[(size_t)i * 256 + t] = (t < 128)
        ? acc[(size_t)midx[i] * DIM + t]
        : pooled[genre[i] * DIM + (t - 128)];
}

__global__ void scatter_movies(const float* __restrict__ fused, const int* __restrict__ midx,
                               float* __restrict__ out)
{
    const int i = blockIdx.x, c = threadIdx.x;
    out[(size_t)midx[i] * DIM + c] = fused[(size_t)i * DIM + c];
}

extern "C" void kernel_launch(void* const* d_in, const int* in_sizes, int n_in,
                              void* d_out, int out_size, void* d_ws, size_t ws_size,
                              hipStream_t stream)
{
    const float* x      = (const float*)d_in[0];
    const int* e[3]     = { (const int*)d_in[1], (const int*)d_in[2], (const int*)d_in[3] };
    const int* midx     = (const int*)d_in[4];
    const int* genre    = (const int*)d_in[5];
    const float* gatW   = (const float*)d_in[6];
    const float* attS   = (const float*)d_in[7];
    const float* attD   = (const float*)d_in[8];
    const float* gatB   = (const float*)d_in[9];
    const float* decW   = (const float*)d_in[10];
    const float* decB   = (const float*)d_in[11];
    const float* qkvW   = (const float*)d_in[12];
    const float* qkvB   = (const float*)d_in[13];
    const float* outW   = (const float*)d_in[14];
    const float* outB   = (const float*)d_in[15];
    const float* ln1g   = (const float*)d_in[16];
    const float* ln1b   = (const float*)d_in[17];
    const float* ln2g   = (const float*)d_in[18];
    const float* ln2b   = (const float*)d_in[19];
    const float* fw1    = (const float*)d_in[20];
    const float* fb1    = (const float*)d_in[21];
    const float* fw2    = (const float*)d_in[22];
    const float* fb2    = (const float*)d_in[23];
    const float* fusW   = (const float*)d_in[24];
    const float* fusB   = (const float*)d_in[25];
    float* out = (float*)d_out;

    // ---- workspace layout (floats); peak ~90 MB ----
    float* ws   = (float*)d_ws;
    float* acc  = ws;                       // 6,400,000
    float* R    = ws + 6400000;
    // stage A:
    float* hbuf = R;                        // 6,400,000
    float* gbuf = hbuf + 6400000;           // 6,400,000
    float* als  = gbuf + 6400000;           // 200,000
    float* ald  = als + 200000;             // 200,000
    float* den  = ald + 200000;             // 200,000
    // stage B (aliases stage A region):
    float* ybuf   = R;                      // 2,611,200
    float* tmp    = ybuf + 2611200;         // 2,611,200
    float* attnb  = tmp + 2611200;          // 2,611,200 (also fused output)
    float* big    = attnb + 2611200;        // 8,355,840 (qkvb / FFN mid / A2 — never co-live)
    float* pooled = big + 8355840;          // 3,840
    int*   cntb   = (int*)(pooled + 3840);  // 32
    int*   posb   = cntb + 32;              // 20,400

    const float decay[3] = { 1.0f, 0.90483741803595952f, 0.81873075307798182f };

    // ================= Stage A: 3-hop GAT =================
    hipMemsetAsync(acc, 0, (size_t)6400000 * 4, stream);
    for (int k = 0; k < 3; k++) {
        gemm_bt<0, 0><<<dim3(782, 2), 256, 0, stream>>>(
            x, gatW + k * DIM * DIM, (const float*)nullptr, hbuf, N_NODES, DIM, DIM, 1.f);
        gat_al<<<(N_NODES * 4 + 255) / 256, 256, 0, stream>>>(
            hbuf, attS + k * DIM, attD + k * DIM, als, ald, N_NODES);
        hipMemsetAsync(gbuf, 0, (size_t)6400000 * 4, stream);
        hipMemsetAsync(den, 0, (size_t)200000 * 4, stream);
        {
            int waves = N_EDGES + N_NODES;   // 450000, divisible by 4
            gat_edge<<<waves / 4, 256, 0, stream>>>(
                e[k], e[k] + N_EDGES, N_EDGES, N_NODES, hbuf, als, ald, gbuf, den);
        }
        gat_norm<<<25000, 256, 0, stream>>>(gbuf, den, gatB + k * DIM);
        gemm_bt<1, 1><<<dim3(782, 2), 256, 0, stream>>>(
            gbuf, decW + k * DIM * DIM, decB + k * DIM, acc, N_NODES, DIM, DIM, decay[k]);
    }

    // ================= Stage B: genre transformer =================
    hipMemsetAsync(cntb, 0, 32 * 4, stream);
    calc_pos<<<(N_MOVIE + 255) / 256, 256, 0, stream>>>(genre, posb, cntb, N_MOVIE);
    hipMemsetAsync(ybuf, 0, (size_t)2611200 * 4, stream);
    build_y<<<N_MOVIE, 128, 0, stream>>>(acc, midx, genre, posb, ybuf);

    const int CH_ROWS = 6 * L_MAX;   // 4080 rows, FFN chunking only
    for (int l = 0; l < N_LAYERS; l++) {
        float* qkvb = big;
        gemm_bt<0, 0><<<dim3(319, 6), 256, 0, stream>>>(
            ybuf, qkvW + (size_t)l * 384 * DIM, qkvB + l * 384, qkvb, NROWS, 384, DIM, 1.f);
        flash_attn<<<dim3(6, 4, 30), 256, 0, stream>>>(qkvb, cntb, attnb);
        gemm_bt<0, 0><<<dim3(319, 2), 256, 0, stream>>>(
            attnb, outW + (size_t)l * DIM * DIM, outB + l * DIM, tmp, NROWS, DIM, DIM, 1.f);
        ln_res<<<NROWS, 128, 0, stream>>>(ybuf, tmp, ln1g + l * DIM, ln1b + l * DIM);
        for (int ch = 0; ch < 5; ch++) {
            const size_t ro = (size_t)ch * CH_ROWS * DIM;
            gemm_bt<2, 0><<<dim3(64, 32), 256, 0, stream>>>(
                ybuf + ro, fw1 + (size_t)l * FF * DIM, fb1 + l * FF,
                big, CH_ROWS, FF, DIM, 1.f);
            gemm_bt<0, 0><<<dim3(64, 2), 256, 0, stream>>>(
                big, fw2 + (size_t)l * FF * DIM, fb2 + l * DIM,
                tmp + ro, CH_ROWS, DIM, FF, 1.f);
        }
        ln_res<<<NROWS, 128, 0, stream>>>(ybuf, tmp, ln2g + l * DIM, ln2b + l * DIM);
    }

    pool_kernel<<<N_GENRE, 128, 0, stream>>>(ybuf, cntb, pooled);
    build_fin<<<N_MOVIE, 256, 0, stream>>>(acc, pooled, midx, genre, big);
    gemm_bt<1, 0><<<dim3(319, 2), 256, 0, stream>>>(
        big, fusW, fusB, attnb, NROWS, DIM, 256, 1.f);

    hipMemcpyAsync(out, acc, (size_t)6400000 * 4, hipMemcpyDeviceToDevice, stream);
    scatter_movies<<<N_MOVIE, 128, 0, stream>>>(attnb, midx, out);
}

// Round 4
// 2881.638 us; speedup vs baseline: 3.7444x; 1.7298x over previous
//
#include <hip/hip_runtime.h>

#define N_NODES  50000
#define N_EDGES  400000
#define DIM      128
#define N_MOVIE  20400
#define N_GENRE  30
#define L_MAX    680
#define NROWS    (N_GENRE * L_MAX)   /* 20400 */
#define FF       2048
#define N_LAYERS 4

typedef __attribute__((ext_vector_type(8))) short bf16x8;
typedef __attribute__((ext_vector_type(4))) float f32x4;

#define MFMA16 __builtin_amdgcn_mfma_f32_16x16x32_bf16

__device__ __forceinline__ ushort f2b(float f) {
    union { float f; unsigned i; } c; c.f = f;
    unsigned u = c.i;
    u += 0x7FFFu + ((u >> 16) & 1u);   // RNE
    return (ushort)(u >> 16);
}

__device__ __forceinline__ bf16x8 load8s(const ushort* p) {
    return *(const bf16x8*)p;          // 16B aligned
}

// fp32 -> bf16, 8 elems/thread, fully coalesced
__global__ void cvt32(const float* __restrict__ s, ushort* __restrict__ d, int n8)
{
    int i = blockIdx.x * blockDim.x + threadIdx.x;
    if (i >= n8) return;
    const float4* q = (const float4*)(s + (size_t)i * 8);
    float4 a = q[0], b = q[1];
    bf16x8 r;
    r[0] = (short)f2b(a.x); r[1] = (short)f2b(a.y);
    r[2] = (short)f2b(a.z); r[3] = (short)f2b(a.w);
    r[4] = (short)f2b(b.x); r[5] = (short)f2b(b.y);
    r[6] = (short)f2b(b.z); r[7] = (short)f2b(b.w);
    *(bf16x8*)(d + (size_t)i * 8) = r;
}

// C[M,N] = epi( A[M,K] @ W[N,K]^T + bias )   A,W bf16; fp32 accumulate.
// ACT: 0 none, 1 leaky(0.01), 2 relu.  EPI: 0 store, 1 C += scale*v.  OBF: 1 = bf16 out.
template<int ACT, int EPI, int OBF>
__global__ __launch_bounds__(256) void gemm_bt(
    const ushort* __restrict__ A, const ushort* __restrict__ W,
    const float* __restrict__ bias, void* __restrict__ Cv,
    int M, int N, int K, float scale)
{
    const int tid  = threadIdx.x;
    const int wave = tid >> 6, lane = tid & 63;
    const int quad = lane >> 4, l16 = lane & 15;
    const int m0 = blockIdx.x * 64 + (wave & 1) * 32;
    const int n0 = blockIdx.y * 64 + (wave >> 1) * 32;

    f32x4 acc[2][2] = {};
    for (int k0 = 0; k0 < K; k0 += 32) {
        const int kk = k0 + quad * 8;
        int r0 = m0 + l16;      if (r0 >= M) r0 = M - 1;
        int r1 = m0 + 16 + l16; if (r1 >= M) r1 = M - 1;
        bf16x8 a0 = load8s(A + (size_t)r0 * K + kk);
        bf16x8 a1 = load8s(A + (size_t)r1 * K + kk);
        bf16x8 b0 = load8s(W + (size_t)(n0 + l16) * K + kk);
        bf16x8 b1 = load8s(W + (size_t)(n0 + 16 + l16) * K + kk);
        acc[0][0] = MFMA16(a0, b0, acc[0][0], 0, 0, 0);
        acc[0][1] = MFMA16(a0, b1, acc[0][1], 0, 0, 0);
        acc[1][0] = MFMA16(a1, b0, acc[1][0], 0, 0, 0);
        acc[1][1] = MFMA16(a1, b1, acc[1][1], 0, 0, 0);
    }
#pragma unroll
    for (int j = 0; j < 2; j++) {
        const int col = n0 + j * 16 + l16;
        const float bv = bias ? bias[col] : 0.f;
#pragma unroll
        for (int i = 0; i < 2; i++) {
#pragma unroll
            for (int r = 0; r < 4; r++) {
                const int row = m0 + i * 16 + quad * 4 + r;
                if (row < M) {
                    float v = acc[i][j][r] + bv;
                    if (ACT == 1) v = (v >= 0.f) ? v : 0.01f * v;
                    if (ACT == 2) v = fmaxf(v, 0.f);
                    const size_t idx = (size_t)row * N + col;
                    if (OBF) ((ushort*)Cv)[idx] = f2b(v);
                    else if (EPI == 1) ((float*)Cv)[idx] += scale * v;
                    else ((float*)Cv)[idx] = v;
                }
            }
        }
    }
}

// per-(node,head) attention logit halves
__global__ void gat_al(const float* __restrict__ h,
                       const float* __restrict__ asrc, const float* __restrict__ adst,
                       float* __restrict__ als, float* __restrict__ ald, int N)
{
    int idx = blockIdx.x * blockDim.x + threadIdx.x;
    if (idx >= N * 4) return;
    int n = idx >> 2, hh = idx & 3;
    const float* hp = h + (size_t)n * DIM + hh * 32;
    float s = 0.f, d = 0.f;
#pragma unroll 8
    for (int c = 0; c < 32; c++) {
        float v = hp[c];
        s += v * asrc[hh * 32 + c];
        d += v * adst[hh * 32 + c];
    }
    als[idx] = s; ald[idx] = d;
}

// one wave per edge (incl. self loops): out[dst] += w_h * h[src], den[dst] += w_h
__global__ __launch_bounds__(256) void gat_edge(
    const int* __restrict__ esrc, const int* __restrict__ edst, int E, int N,
    const float* __restrict__ h, const float* __restrict__ als,
    const float* __restrict__ ald, float* __restrict__ outbuf, float* __restrict__ den)
{
    int gw = (blockIdx.x * 256 + threadIdx.x) >> 6;
    int lane = threadIdx.x & 63;
    if (gw >= E + N) return;
    int s, d;
    if (gw < E) { s = esrc[gw]; d = edst[gw]; } else { s = d = gw - E; }
    float4 as4 = *(const float4*)(als + (size_t)s * 4);
    float4 ad4 = *(const float4*)(ald + (size_t)d * 4);
    float w[4];
#pragma unroll
    for (int hh = 0; hh < 4; hh++) {
        float e = (&as4.x)[hh] + (&ad4.x)[hh];
        e = (e >= 0.f) ? e : 0.2f * e;
        w[hh] = __expf(e);
    }
    if (lane < 4) atomicAdd(den + (size_t)d * 4 + lane, w[lane]);
    float h0 = h[(size_t)s * DIM + lane];
    float h1 = h[(size_t)s * DIM + 64 + lane];
    atomicAdd(outbuf + (size_t)d * DIM + lane,      w[lane >> 5] * h0);
    atomicAdd(outbuf + (size_t)d * DIM + 64 + lane, w[2 + (lane >> 5)] * h1);
}

// normalize + bias, write bf16 (feeds dec GEMM)
__global__ void gat_norm(const float* __restrict__ outbuf, const float* __restrict__ den,
                         const float* __restrict__ bias, ushort* __restrict__ ob)
{
    int idx = blockIdx.x * 256 + threadIdx.x;   // N_NODES*128 total
    int n = idx >> 7, c = idx & 127;
    ob[idx] = f2b(outbuf[idx] / den[(size_t)n * 4 + (c >> 5)] + bias[c]);
}

__global__ void calc_pos(const int* __restrict__ genre, int* __restrict__ pos,
                         int* __restrict__ cnt, int NM)
{
    int i = blockIdx.x * blockDim.x + threadIdx.x;
    if (i < NM) pos[i] = atomicAdd(&cnt[genre[i]], 1);
}

__global__ void build_y(const float* __restrict__ acc, const int* __restrict__ midx,
                        const int* __restrict__ genre, const int* __restrict__ pos,
                        float* __restrict__ y, ushort* __restrict__ yb)
{
    int i = blockIdx.x, c = threadIdx.x;
    int g = genre[i], p = pos[i];
    float v = acc[(size_t)midx[i] * DIM + c];
    size_t o = ((size_t)g * L_MAX + p) * DIM + c;
    y[o] = v; yb[o] = f2b(v);
}

// ===================== MFMA flash attention (bf16 in/out) =====================
#define SV 712   /* vT row stride in shorts */
#define SP 40    /* P row stride in shorts */

__global__ __launch_bounds__(256) void flash_attn(
    const ushort* __restrict__ qkv, const int* __restrict__ cnt,
    ushort* __restrict__ o)
{
    __shared__ ushort vT[32 * SV];        // 45568 B
    __shared__ ushort Pb[4][32 * SP];     // 10240 B

    const int qt = blockIdx.x, hh = blockIdx.y, g = blockIdx.z;
    const int t = threadIdx.x, wave = t >> 6, lane = t & 63;
    const int quad = lane >> 4, l16 = lane & 15;
    const int L = cnt[g];
    const float scale = 0.17677669529663687f;   // 1/sqrt(32)
    const ushort* base = qkv + (size_t)g * L_MAX * 384;

    for (int i = t; i < L_MAX * 32; i += 256) {
        int k = i >> 5, d = i & 31;
        vT[d * SV + k] = (k < L) ? base[(size_t)k * 384 + 256 + hh * 32 + d] : (ushort)0;
    }
    for (int i = t; i < 32 * 32; i += 256) {
        int k = L_MAX + (i & 31), d = i >> 5;
        if (k < 704) vT[d * SV + k] = 0;
    }
    __syncthreads();

    const int q0 = qt * 128 + wave * 32;
    const int rq0 = min(q0 + l16, L_MAX - 1);
    const int rq1 = min(q0 + 16 + l16, L_MAX - 1);
    bf16x8 a0 = load8s(base + (size_t)rq0 * 384 + hh * 32 + quad * 8);
    bf16x8 a1 = load8s(base + (size_t)rq1 * 384 + hh * 32 + quad * 8);

    f32x4 oacc[2][2] = {};
    float rsum[2][4] = {};
    ushort* P = Pb[wave];

    for (int kt = 0; kt < 704; kt += 32) {
        const int rk0 = min(kt + l16, L_MAX - 1);
        const int rk1 = min(kt + 16 + l16, L_MAX - 1);
        bf16x8 b0 = load8s(base + (size_t)rk0 * 384 + 128 + hh * 32 + quad * 8);
        bf16x8 b1 = load8s(base + (size_t)rk1 * 384 + 128 + hh * 32 + quad * 8);
        f32x4 z = {};
        f32x4 s[2][2];
        s[0][0] = MFMA16(a0, b0, z, 0, 0, 0);
        s[0][1] = MFMA16(a0, b1, z, 0, 0, 0);
        s[1][0] = MFMA16(a1, b0, z, 0, 0, 0);
        s[1][1] = MFMA16(a1, b1, z, 0, 0, 0);

#pragma unroll
        for (int mi = 0; mi < 2; mi++)
#pragma unroll
            for (int j = 0; j < 2; j++) {
                const int kc = kt + j * 16 + l16;
                const bool ok = kc < L;
#pragma unroll
                for (int r = 0; r < 4; r++) {
                    float w = ok ? __expf(s[mi][j][r] * scale) : 0.f;
                    rsum[mi][r] += w;
                    P[(mi * 16 + quad * 4 + r) * SP + j * 16 + l16] = f2b(w);
                }
            }
        __syncthreads();

        bf16x8 p0 = load8s(P + (size_t)l16 * SP + quad * 8);
        bf16x8 p1 = load8s(P + (size_t)(16 + l16) * SP + quad * 8);
        bf16x8 v0 = load8s(vT + (size_t)l16 * SV + kt + quad * 8);
        bf16x8 v1 = load8s(vT + (size_t)(16 + l16) * SV + kt + quad * 8);
        oacc[0][0] = MFMA16(p0, v0, oacc[0][0], 0, 0, 0);
        oacc[0][1] = MFMA16(p0, v1, oacc[0][1], 0, 0, 0);
        oacc[1][0] = MFMA16(p1, v0, oacc[1][0], 0, 0, 0);
        oacc[1][1] = MFMA16(p1, v1, oacc[1][1], 0, 0, 0);
        __syncthreads();
    }

#pragma unroll
    for (int mi = 0; mi < 2; mi++)
#pragma unroll
        for (int r = 0; r < 4; r++) {
            float s = rsum[mi][r];
            s += __shfl_xor(s, 1, 64);
            s += __shfl_xor(s, 2, 64);
            s += __shfl_xor(s, 4, 64);
            s += __shfl_xor(s, 8, 64);
            rsum[mi][r] = s;
        }

#pragma unroll
    for (int mi = 0; mi < 2; mi++)
#pragma unroll
        for (int j = 0; j < 2; j++)
#pragma unroll
            for (int r = 0; r < 4; r++) {
                const int q = q0 + mi * 16 + quad * 4 + r;
                if (q < L_MAX)
                    o[((size_t)(g * L_MAX + q)) * DIM + hh * 32 + j * 16 + l16] =
                        f2b(oacc[mi][j][r] / rsum[mi][r]);
            }
}

// y = LN(y + res) * g + b; writes fp32 y and bf16 yb
__global__ __launch_bounds__(128) void ln_res(
    float* __restrict__ y, const float* __restrict__ res,
    const float* __restrict__ g, const float* __restrict__ b,
    ushort* __restrict__ yb)
{
    __shared__ float sh[2], sh2[2];
    const int r = blockIdx.x, t = threadIdx.x;
    const size_t base = (size_t)r * DIM;
    float v = y[base + t] + res[base + t];
    float s = v;
    for (int off = 32; off; off >>= 1) s += __shfl_down(s, off, 64);
    if ((t & 63) == 0) sh[t >> 6] = s;
    __syncthreads();
    const float mean = (sh[0] + sh[1]) * (1.f / 128.f);
    const float d = v - mean;
    float q = d * d;
    for (int off = 32; off; off >>= 1) q += __shfl_down(q, off, 64);
    if ((t & 63) == 0) sh2[t >> 6] = q;
    __syncthreads();
    const float var = (sh2[0] + sh2[1]) * (1.f / 128.f);
    float o = d * rsqrtf(var + 1e-5f) * g[t] + b[t];
    y[base + t] = o; yb[base + t] = f2b(o);
}

__global__ void pool_kernel(const float* __restrict__ y, const int* __restrict__ cnt,
                            float* __restrict__ pooled)
{
    const int g = blockIdx.x, c = threadIdx.x;
    const int L = cnt[g];
    float s = 0.f;
    for (int k = 0; k < L; k++) s += y[((size_t)g * L_MAX + k) * DIM + c];
    pooled[g * DIM + c] = s / (float)max(L, 1);
}

__global__ void build_fin(const float* __restrict__ acc, const float* __restrict__ pooled,
                          const int* __restrict__ midx, const int* __restrict__ genre,
                          ushort* __restrict__ A2)
{
    const int i = blockIdx.x, t = threadIdx.x;
    float v = (t < 128) ? acc[(size_t)midx[i] * DIM + t]
                        : pooled[genre[i] * DIM + (t - 128)];
    A2[(size_t)i * 256 + t] = f2b(v);
}

__global__ void scatter_movies(const float* __restrict__ fused, const int* __restrict__ midx,
                               float* __restrict__ out)
{
    const int i = blockIdx.x, c = threadIdx.x;
    out[(size_t)midx[i] * DIM + c] = fused[(size_t)i * DIM + c];
}

extern "C" void kernel_launch(void* const* d_in, const int* in_sizes, int n_in,
                              void* d_out, int out_size, void* d_ws, size_t ws_size,
                              hipStream_t stream)
{
    const float* x      = (const float*)d_in[0];
    const int* e[3]     = { (const int*)d_in[1], (const int*)d_in[2], (const int*)d_in[3] };
    const int* midx     = (const int*)d_in[4];
    const int* genre    = (const int*)d_in[5];
    const float* gatW   = (const float*)d_in[6];
    const float* attS   = (const float*)d_in[7];
    const float* attD   = (const float*)d_in[8];
    const float* gatB   = (const float*)d_in[9];
    const float* decW   = (const float*)d_in[10];
    const float* decB   = (const float*)d_in[11];
    const float* qkvW   = (const float*)d_in[12];
    const float* qkvB   = (const float*)d_in[13];
    const float* outW   = (const float*)d_in[14];
    const float* outB   = (const float*)d_in[15];
    const float* ln1g   = (const float*)d_in[16];
    const float* ln1b   = (const float*)d_in[17];
    const float* ln2g   = (const float*)d_in[18];
    const float* ln2b   = (const float*)d_in[19];
    const float* fw1    = (const float*)d_in[20];
    const float* fb1    = (const float*)d_in[21];
    const float* fw2    = (const float*)d_in[22];
    const float* fb2    = (const float*)d_in[23];
    const float* fusW   = (const float*)d_in[24];
    const float* fusB   = (const float*)d_in[25];
    float* out = (float*)d_out;

    // ---- workspace layout (float offsets); peak ~94 MB ----
    float* ws  = (float*)d_ws;
    float* acc = ws;                              // 6,400,000 f32
    float* R   = ws + 6400000;
    // stage A:
    float*  hbuf  = R;                            // 6,400,000 f32
    float*  gbuf  = R + 6400000;                  // 6,400,000 f32
    float*  als   = R + 12800000;                 // 200,000
    float*  ald   = R + 13000000;                 // 200,000
    float*  den   = R + 13200000;                 // 200,000
    ushort* xb    = (ushort*)(R + 13400000);      // 6,400,000 bf16
    ushort* gatWb = (ushort*)(R + 16600000);      // 49,152 bf16
    ushort* decWb = (ushort*)(R + 16624576);      // 49,152 bf16
    ushort* gbx   = (ushort*)hbuf;                // aliases hbuf (dead by gat_norm)
    // stage B (aliases stage A region):
    float*  ybuf  = R;                            // 2,611,200 f32
    float*  tmp   = R + 2611200;                  // 2,611,200 f32
    ushort* ybx   = (ushort*)(R + 5222400);       // 2,611,200 bf16
    ushort* attnb = (ushort*)(R + 6528000);       // 2,611,200 bf16
    ushort* qkvb  = (ushort*)(R + 7833600);       // 7,833,600 bf16
    ushort* midb  = (ushort*)(R + 11750400);      // 8,355,840 bf16 (FFN chunk)
    ushort* finb  = (ushort*)(R + 11750400);      // aliases midb (5,222,400 bf16)
    float*  pooled= R + 15928320;                 // 3,840
    int*    cntb  = (int*)(R + 15932160);         // 32
    int*    posb  = cntb + 32;                    // 20,400
    ushort* qkvWb = (ushort*)(R + 15952640);      // 196,608 bf16
    ushort* outWb = (ushort*)(R + 16051000 - 56); // = R+16050944: 65,536 bf16
    ushort* fw1b  = (ushort*)(R + 16083712);      // 1,048,576 bf16
    ushort* fw2b  = (ushort*)(R + 16608000);      // 1,048,576 bf16
    ushort* fusWb = (ushort*)(R + 17132288);      // 32,768 bf16

    const float decay[3] = { 1.0f, 0.90483741803595952f, 0.81873075307798182f };

    // ================= Stage A: 3-hop GAT =================
    hipMemsetAsync(acc, 0, (size_t)6400000 * 4, stream);
    cvt32<<<(6400000 / 8 + 255) / 256, 256, 0, stream>>>(x, xb, 6400000 / 8);
    cvt32<<<(49152 / 8 + 255) / 256, 256, 0, stream>>>(gatW, gatWb, 49152 / 8);
    cvt32<<<(49152 / 8 + 255) / 256, 256, 0, stream>>>(decW, decWb, 49152 / 8);
    for (int k = 0; k < 3; k++) {
        gemm_bt<0, 0, 0><<<dim3(782, 2), 256, 0, stream>>>(
            xb, gatWb + k * DIM * DIM, nullptr, hbuf, N_NODES, DIM, DIM, 1.f);
        gat_al<<<(N_NODES * 4 + 255) / 256, 256, 0, stream>>>(
            hbuf, attS + k * DIM, attD + k * DIM, als, ald, N_NODES);
        hipMemsetAsync(gbuf, 0, (size_t)6400000 * 4, stream);
        hipMemsetAsync(den, 0, (size_t)200000 * 4, stream);
        gat_edge<<<(N_EDGES + N_NODES) / 4, 256, 0, stream>>>(
            e[k], e[k] + N_EDGES, N_EDGES, N_NODES, hbuf, als, ald, gbuf, den);
        gat_norm<<<25000, 256, 0, stream>>>(gbuf, den, gatB + k * DIM, gbx);
        gemm_bt<1, 1, 0><<<dim3(782, 2), 256, 0, stream>>>(
            gbx, decWb + k * DIM * DIM, decB + k * DIM, acc, N_NODES, DIM, DIM, decay[k]);
    }

    // ================= Stage B: genre transformer =================
    cvt32<<<(196608 / 8 + 255) / 256, 256, 0, stream>>>(qkvW, qkvWb, 196608 / 8);
    cvt32<<<(65536 / 8 + 255) / 256, 256, 0, stream>>>(outW, outWb, 65536 / 8);
    cvt32<<<(1048576 / 8 + 255) / 256, 256, 0, stream>>>(fw1, fw1b, 1048576 / 8);
    cvt32<<<(1048576 / 8 + 255) / 256, 256, 0, stream>>>(fw2, fw2b, 1048576 / 8);
    cvt32<<<(32768 / 8 + 255) / 256, 256, 0, stream>>>(fusW, fusWb, 32768 / 8);

    hipMemsetAsync(cntb, 0, 32 * 4, stream);
    calc_pos<<<(N_MOVIE + 255) / 256, 256, 0, stream>>>(genre, posb, cntb, N_MOVIE);
    build_y<<<N_MOVIE, 128, 0, stream>>>(acc, midx, genre, posb, ybuf, ybx);

    const int CH_ROWS = 6 * L_MAX;   // 4080
    for (int l = 0; l < N_LAYERS; l++) {
        gemm_bt<0, 0, 1><<<dim3(319, 6), 256, 0, stream>>>(
            ybx, qkvWb + (size_t)l * 384 * DIM, qkvB + l * 384, qkvb, NROWS, 384, DIM, 1.f);
        flash_attn<<<dim3(6, 4, 30), 256, 0, stream>>>(qkvb, cntb, attnb);
        gemm_bt<0, 0, 0><<<dim3(319, 2), 256, 0, stream>>>(
            attnb, outWb + (size_t)l * DIM * DIM, outB + l * DIM, tmp, NROWS, DIM, DIM, 1.f);
        ln_res<<<NROWS, 128, 0, stream>>>(ybuf, tmp, ln1g + l * DIM, ln1b + l * DIM, ybx);
        for (int ch = 0; ch < 5; ch++) {
            const size_t ro = (size_t)ch * CH_ROWS * DIM;
            gemm_bt<2, 0, 1><<<dim3(64, 32), 256, 0, stream>>>(
                ybx + ro, fw1b + (size_t)l * FF * DIM, fb1 + l * FF,
                midb, CH_ROWS, FF, DIM, 1.f);
            gemm_bt<0, 0, 0><<<dim3(64, 2), 256, 0, stream>>>(
                midb, fw2b + (size_t)l * FF * DIM, fb2 + l * DIM,
                tmp + ro, CH_ROWS, DIM, FF, 1.f);
        }
        ln_res<<<NROWS, 128, 0, stream>>>(ybuf, tmp, ln2g + l * DIM, ln2b + l * DIM, ybx);
    }

    pool_kernel<<<N_GENRE, 128, 0, stream>>>(ybuf, cntb, pooled);
    build_fin<<<N_MOVIE, 256, 0, stream>>>(acc, pooled, midx, genre, finb);
    gemm_bt<1, 0, 0><<<dim3(319, 2), 256, 0, stream>>>(
        finb, fusWb, fusB, tmp, NROWS, DIM, 256, 1.f);

    hipMemcpyAsync(out, acc, (size_t)6400000 * 4, hipMemcpyDeviceToDevice, stream);
    scatter_movies<<<N_MOVIE, 128, 0, stream>>>(tmp, midx, out);
}

// Round 5
// 2236.327 us; speedup vs baseline: 4.8249x; 1.2886x over previous
//
#include <hip/hip_runtime.h>

#define N_NODES  50000
#define N_EDGES  400000
#define DIM      128
#define N_MOVIE  20400
#define N_GENRE  30
#define L_MAX    680
#define NROWS    (N_GENRE * L_MAX)   /* 20400 */
#define FF       2048
#define N_LAYERS 4

typedef __attribute__((ext_vector_type(8))) short bf16x8;
typedef __attribute__((ext_vector_type(4))) float f32x4;

#define MFMA16 __builtin_amdgcn_mfma_f32_16x16x32_bf16

__device__ __forceinline__ float b2f(ushort u) {
    union { unsigned i; float f; } c; c.i = ((unsigned)u) << 16; return c.f;
}
__device__ __forceinline__ ushort f2b(float f) {
    union { float f; unsigned i; } c; c.f = f;
    unsigned u = c.i;
    u += 0x7FFFu + ((u >> 16) & 1u);   // RNE
    return (ushort)(u >> 16);
}
__device__ __forceinline__ bf16x8 load8s(const ushort* p) {
    return *(const bf16x8*)p;
}
// async global->LDS, 16B per lane; LDS dest must be wave-uniform base + lane*16
__device__ __forceinline__ void async16(const ushort* g, ushort* l) {
    __builtin_amdgcn_global_load_lds(
        (const __attribute__((address_space(1))) void*)g,
        (__attribute__((address_space(3))) void*)l, 16, 0, 0);
}

// fp32 -> bf16, 8 elems/thread
__global__ void cvt32(const float* __restrict__ s, ushort* __restrict__ d, int n8)
{
    int i = blockIdx.x * blockDim.x + threadIdx.x;
    if (i >= n8) return;
    const float4* q = (const float4*)(s + (size_t)i * 8);
    float4 a = q[0], b = q[1];
    bf16x8 r;
    r[0] = (short)f2b(a.x); r[1] = (short)f2b(a.y);
    r[2] = (short)f2b(a.z); r[3] = (short)f2b(a.w);
    r[4] = (short)f2b(b.x); r[5] = (short)f2b(b.y);
    r[6] = (short)f2b(b.z); r[7] = (short)f2b(b.w);
    *(bf16x8*)(d + (size_t)i * 8) = r;
}

// ============ LDS-staged GEMM: C[M,N] = epi(A @ W^T + bias) ============
// BM x 128 tile, BK=32, 256 threads. BM in {128,64}. N must be multiple of 128.
// ACT: 0 none, 1 leaky(0.01), 2 relu.  EPI: 0 store, 1 C += scale*v.  OBF: bf16 out.
template<int BM, int ACT, int EPI, int OBF>
__global__ __launch_bounds__(256) void gemm_lds(
    const ushort* __restrict__ A, const ushort* __restrict__ W,
    const float* __restrict__ bias, void* __restrict__ Cv,
    int M, int N, int K, float scale)
{
    __shared__ ushort As[BM * 32];
    __shared__ ushort Ws[128 * 32];
    const int tid  = threadIdx.x;
    const int wave = tid >> 6, lane = tid & 63;
    const int quad = lane >> 4, l16 = lane & 15;
    const int m0 = blockIdx.x * BM;
    const int n0 = blockIdx.y * 128;

    constexpr int MT = BM / 32;              // 4 (BM=128) or 2 (BM=64)
    const int mbase = (wave & 1) * (BM / 2);
    const int nbase = (wave >> 1) * 64;

    // staging coords: thread covers LDS bytes wave*1024 + lane*16 (+ issue*4096)
    const int srow = wave * 16 + (lane >> 2);   // row within 64-row slab
    const int skof = (lane & 3) * 8;            // k offset in shorts

    f32x4 acc[MT][4] = {};
    for (int k0 = 0; k0 < K; k0 += 32) {
#pragma unroll
        for (int i = 0; i < BM / 64; i++) {
            int r = i * 64 + srow;
            int rg = min(m0 + r, M - 1);
            async16(A + (size_t)rg * K + k0 + skof, As + r * 32 + skof);
        }
#pragma unroll
        for (int i = 0; i < 2; i++) {
            int r = i * 64 + srow;
            async16(W + (size_t)(n0 + r) * K + k0 + skof, Ws + r * 32 + skof);
        }
        __syncthreads();

        bf16x8 a[MT], b[4];
#pragma unroll
        for (int mt = 0; mt < MT; mt++)
            a[mt] = load8s(As + (mbase + mt * 16 + l16) * 32 + quad * 8);
#pragma unroll
        for (int nt = 0; nt < 4; nt++)
            b[nt] = load8s(Ws + (nbase + nt * 16 + l16) * 32 + quad * 8);
#pragma unroll
        for (int mt = 0; mt < MT; mt++)
#pragma unroll
            for (int nt = 0; nt < 4; nt++)
                acc[mt][nt] = MFMA16(a[mt], b[nt], acc[mt][nt], 0, 0, 0);
        __syncthreads();
    }

#pragma unroll
    for (int nt = 0; nt < 4; nt++) {
        const int col = n0 + nbase + nt * 16 + l16;
        const float bv = bias ? bias[col] : 0.f;
#pragma unroll
        for (int mt = 0; mt < MT; mt++) {
#pragma unroll
            for (int r = 0; r < 4; r++) {
                const int row = m0 + mbase + mt * 16 + quad * 4 + r;
                if (row < M) {
                    float v = acc[mt][nt][r] + bv;
                    if (ACT == 1) v = (v >= 0.f) ? v : 0.01f * v;
                    if (ACT == 2) v = fmaxf(v, 0.f);
                    const size_t idx = (size_t)row * N + col;
                    if (OBF)           ((ushort*)Cv)[idx] = f2b(v);
                    else if (EPI == 1) ((float*)Cv)[idx] += scale * v;
                    else               ((float*)Cv)[idx] = v;
                }
            }
        }
    }
}

// per-(node,head) attention logit halves (h in bf16)
__global__ void gat_al(const ushort* __restrict__ h,
                       const float* __restrict__ asrc, const float* __restrict__ adst,
                       float* __restrict__ als, float* __restrict__ ald, int N)
{
    int idx = blockIdx.x * blockDim.x + threadIdx.x;
    if (idx >= N * 4) return;
    int n = idx >> 2, hh = idx & 3;
    const ushort* hp = h + (size_t)n * DIM + hh * 32;
    float s = 0.f, d = 0.f;
#pragma unroll 8
    for (int c = 0; c < 32; c++) {
        float v = b2f(hp[c]);
        s += v * asrc[hh * 32 + c];
        d += v * adst[hh * 32 + c];
    }
    als[idx] = s; ald[idx] = d;
}

// ---------------- CSR build ----------------
__global__ void csr_init(int* __restrict__ cnt) {
    int i = blockIdx.x * 256 + threadIdx.x;
    if (i < N_NODES) cnt[i] = 1;   // self-loop
}
__global__ void csr_deg(const int* __restrict__ dst, int* __restrict__ cnt) {
    int i = blockIdx.x * 256 + threadIdx.x;
    if (i < N_EDGES) atomicAdd(&cnt[dst[i]], 1);
}
__global__ __launch_bounds__(1024) void csr_scan(
    const int* __restrict__ cnt, int* __restrict__ off, int* __restrict__ cur)
{
    __shared__ int part[1024];
    const int t = threadIdx.x;
    const int base = t * 49;
    int s = 0;
    for (int i = 0; i < 49; i++) { int idx = base + i; if (idx < N_NODES) s += cnt[idx]; }
    part[t] = s;
    __syncthreads();
    for (int d = 1; d < 1024; d <<= 1) {
        int v = (t >= d) ? part[t - d] : 0;
        __syncthreads();
        part[t] += v;
        __syncthreads();
    }
    int run = t ? part[t - 1] : 0;
    for (int i = 0; i < 49; i++) {
        int idx = base + i;
        if (idx < N_NODES) { off[idx] = run; cur[idx] = run; run += cnt[idx]; }
    }
    if (t == 1023) off[N_NODES] = part[1023];
}
__global__ void csr_scat(const int* __restrict__ src, const int* __restrict__ dst,
                         int* __restrict__ cur, int* __restrict__ srcs)
{
    int i = blockIdx.x * 256 + threadIdx.x;
    if (i < N_EDGES) {
        int p = atomicAdd(&cur[dst[i]], 1);
        srcs[p] = src[i];
    } else if (i < N_EDGES + N_NODES) {
        int n = i - N_EDGES;
        int p = atomicAdd(&cur[n], 1);
        srcs[p] = n;   // self-loop
    }
}

// one wave per dst: registers accumulate sum(w*h[src]) & sum(w); fold norm+bias; bf16 out
__global__ __launch_bounds__(256) void gat_gather(
    const int* __restrict__ off, const int* __restrict__ srcs,
    const ushort* __restrict__ hb, const float* __restrict__ als,
    const float* __restrict__ ald, const float* __restrict__ bias,
    ushort* __restrict__ ob)
{
    int w = (blockIdx.x * 256 + threadIdx.x) >> 6;
    int lane = threadIdx.x & 63;
    if (w >= N_NODES) return;
    const int h0 = lane >> 5, h1 = 2 + h0;
    const float ad0 = ald[(size_t)w * 4 + h0], ad1 = ald[(size_t)w * 4 + h1];
    const int jb = off[w], je = off[w + 1];
    float acc0 = 0.f, acc1 = 0.f, ws0 = 0.f, ws1 = 0.f;
    for (int j = jb; j < je; j++) {
        int s = srcs[j];
        float e0 = als[(size_t)s * 4 + h0] + ad0; e0 = (e0 >= 0.f) ? e0 : 0.2f * e0;
        float e1 = als[(size_t)s * 4 + h1] + ad1; e1 = (e1 >= 0.f) ? e1 : 0.2f * e1;
        float w0 = __expf(e0), w1 = __expf(e1);
        ws0 += w0; ws1 += w1;
        acc0 += w0 * b2f(hb[(size_t)s * DIM + lane]);
        acc1 += w1 * b2f(hb[(size_t)s * DIM + 64 + lane]);
    }
    ob[(size_t)w * DIM + lane]      = f2b(acc0 / ws0 + bias[lane]);
    ob[(size_t)w * DIM + 64 + lane] = f2b(acc1 / ws1 + bias[64 + lane]);
}

__global__ void calc_pos(const int* __restrict__ genre, int* __restrict__ pos,
                         int* __restrict__ cnt, int NM)
{
    int i = blockIdx.x * blockDim.x + threadIdx.x;
    if (i < NM) pos[i] = atomicAdd(&cnt[genre[i]], 1);
}

__global__ void build_y(const float* __restrict__ acc, const int* __restrict__ midx,
                        const int* __restrict__ genre, const int* __restrict__ pos,
                        float* __restrict__ y, ushort* __restrict__ yb)
{
    int i = blockIdx.x, c = threadIdx.x;
    int g = genre[i], p = pos[i];
    float v = acc[(size_t)midx[i] * DIM + c];
    size_t o = ((size_t)g * L_MAX + p) * DIM + c;
    y[o] = v; yb[o] = f2b(v);
}

// ===================== MFMA flash attention (bf16 in/out) =====================
#define SV 712
#define SP 40

__global__ __launch_bounds__(256) void flash_attn(
    const ushort* __restrict__ qkv, const int* __restrict__ cnt,
    ushort* __restrict__ o)
{
    __shared__ ushort vT[32 * SV];
    __shared__ ushort Pb[4][32 * SP];

    const int qt = blockIdx.x, hh = blockIdx.y, g = blockIdx.z;
    const int t = threadIdx.x, wave = t >> 6, lane = t & 63;
    const int quad = lane >> 4, l16 = lane & 15;
    const int L = cnt[g];
    const float scale = 0.17677669529663687f;
    const ushort* base = qkv + (size_t)g * L_MAX * 384;

    for (int i = t; i < L_MAX * 32; i += 256) {
        int k = i >> 5, d = i & 31;
        vT[d * SV + k] = (k < L) ? base[(size_t)k * 384 + 256 + hh * 32 + d] : (ushort)0;
    }
    for (int i = t; i < 32 * 32; i += 256) {
        int k = L_MAX + (i & 31), d = i >> 5;
        if (k < 704) vT[d * SV + k] = 0;
    }
    __syncthreads();

    const int q0 = qt * 128 + wave * 32;
    const int rq0 = min(q0 + l16, L_MAX - 1);
    const int rq1 = min(q0 + 16 + l16, L_MAX - 1);
    bf16x8 a0 = load8s(base + (size_t)rq0 * 384 + hh * 32 + quad * 8);
    bf16x8 a1 = load8s(base + (size_t)rq1 * 384 + hh * 32 + quad * 8);

    f32x4 oacc[2][2] = {};
    float rsum[2][4] = {};
    ushort* P = Pb[wave];

    for (int kt = 0; kt < 704; kt += 32) {
        const int rk0 = min(kt + l16, L_MAX - 1);
        const int rk1 = min(kt + 16 + l16, L_MAX - 1);
        bf16x8 b0 = load8s(base + (size_t)rk0 * 384 + 128 + hh * 32 + quad * 8);
        bf16x8 b1 = load8s(base + (size_t)rk1 * 384 + 128 + hh * 32 + quad * 8);
        f32x4 z = {};
        f32x4 s[2][2];
        s[0][0] = MFMA16(a0, b0, z, 0, 0, 0);
        s[0][1] = MFMA16(a0, b1, z, 0, 0, 0);
        s[1][0] = MFMA16(a1, b0, z, 0, 0, 0);
        s[1][1] = MFMA16(a1, b1, z, 0, 0, 0);

#pragma unroll
        for (int mi = 0; mi < 2; mi++)
#pragma unroll
            for (int j = 0; j < 2; j++) {
                const int kc = kt + j * 16 + l16;
                const bool ok = kc < L;
#pragma unroll
                for (int r = 0; r < 4; r++) {
                    float w = ok ? __expf(s[mi][j][r] * scale) : 0.f;
                    rsum[mi][r] += w;
                    P[(mi * 16 + quad * 4 + r) * SP + j * 16 + l16] = f2b(w);
                }
            }
        __syncthreads();

        bf16x8 p0 = load8s(P + (size_t)l16 * SP + quad * 8);
        bf16x8 p1 = load8s(P + (size_t)(16 + l16) * SP + quad * 8);
        bf16x8 v0 = load8s(vT + (size_t)l16 * SV + kt + quad * 8);
        bf16x8 v1 = load8s(vT + (size_t)(16 + l16) * SV + kt + quad * 8);
        oacc[0][0] = MFMA16(p0, v0, oacc[0][0], 0, 0, 0);
        oacc[0][1] = MFMA16(p0, v1, oacc[0][1], 0, 0, 0);
        oacc[1][0] = MFMA16(p1, v0, oacc[1][0], 0, 0, 0);
        oacc[1][1] = MFMA16(p1, v1, oacc[1][1], 0, 0, 0);
        __syncthreads();
    }

#pragma unroll
    for (int mi = 0; mi < 2; mi++)
#pragma unroll
        for (int r = 0; r < 4; r++) {
            float s = rsum[mi][r];
            s += __shfl_xor(s, 1, 64);
            s += __shfl_xor(s, 2, 64);
            s += __shfl_xor(s, 4, 64);
            s += __shfl_xor(s, 8, 64);
            rsum[mi][r] = s;
        }

#pragma unroll
    for (int mi = 0; mi < 2; mi++)
#pragma unroll
        for (int j = 0; j < 2; j++)
#pragma unroll
            for (int r = 0; r < 4; r++) {
                const int q = q0 + mi * 16 + quad * 4 + r;
                if (q < L_MAX)
                    o[((size_t)(g * L_MAX + q)) * DIM + hh * 32 + j * 16 + l16] =
                        f2b(oacc[mi][j][r] / rsum[mi][r]);
            }
}

// y = LN(y + res) * g + b; writes fp32 y and bf16 yb
__global__ __launch_bounds__(128) void ln_res(
    float* __restrict__ y, const float* __restrict__ res,
    const float* __restrict__ g, const float* __restrict__ b,
    ushort* __restrict__ yb)
{
    __shared__ float sh[2], sh2[2];
    const int r = blockIdx.x, t = threadIdx.x;
    const size_t base = (size_t)r * DIM;
    float v = y[base + t] + res[base + t];
    float s = v;
    for (int off = 32; off; off >>= 1) s += __shfl_down(s, off, 64);
    if ((t & 63) == 0) sh[t >> 6] = s;
    __syncthreads();
    const float mean = (sh[0] + sh[1]) * (1.f / 128.f);
    const float d = v - mean;
    float q = d * d;
    for (int off = 32; off; off >>= 1) q += __shfl_down(q, off, 64);
    if ((t & 63) == 0) sh2[t >> 6] = q;
    __syncthreads();
    const float var = (sh2[0] + sh2[1]) * (1.f / 128.f);
    float o = d * rsqrtf(var + 1e-5f) * g[t] + b[t];
    y[base + t] = o; yb[base + t] = f2b(o);
}

__global__ __launch_bounds__(256) void pool_kernel(
    const float* __restrict__ y, const int* __restrict__ cnt, float* __restrict__ pooled)
{
    __shared__ float sh[128];
    const int g = blockIdx.x, t = threadIdx.x;
    const int c = t & 127, h = t >> 7;
    const int L = cnt[g];
    float s = 0.f;
    for (int k = h; k < L; k += 2) s += y[((size_t)g * L_MAX + k) * DIM + c];
    if (h) sh[c] = s;
    __syncthreads();
    if (!h) pooled[g * DIM + c] = (s + sh[c]) / (float)max(L, 1);
}

__global__ void build_fin(const float* __restrict__ acc, const float* __restrict__ pooled,
                          const int* __restrict__ midx, const int* __restrict__ genre,
                          ushort* __restrict__ A2)
{
    const int i = blockIdx.x, t = threadIdx.x;
    float v = (t < 128) ? acc[(size_t)midx[i] * DIM + t]
                        : pooled[genre[i] * DIM + (t - 128)];
    A2[(size_t)i * 256 + t] = f2b(v);
}

__global__ void scatter_movies(const float* __restrict__ fused, const int* __restrict__ midx,
                               float* __restrict__ out)
{
    const int i = blockIdx.x, c = threadIdx.x;
    out[(size_t)midx[i] * DIM + c] = fused[(size_t)i * DIM + c];
}

extern "C" void kernel_launch(void* const* d_in, const int* in_sizes, int n_in,
                              void* d_out, int out_size, void* d_ws, size_t ws_size,
                              hipStream_t stream)
{
    const float* x      = (const float*)d_in[0];
    const int* e[3]     = { (const int*)d_in[1], (const int*)d_in[2], (const int*)d_in[3] };
    const int* midx     = (const int*)d_in[4];
    const int* genre    = (const int*)d_in[5];
    const float* gatW   = (const float*)d_in[6];
    const float* attS   = (const float*)d_in[7];
    const float* attD   = (const float*)d_in[8];
    const float* gatB   = (const float*)d_in[9];
    const float* decW   = (const float*)d_in[10];
    const float* decB   = (const float*)d_in[11];
    const float* qkvW   = (const float*)d_in[12];
    const float* qkvB   = (const float*)d_in[13];
    const float* outW   = (const float*)d_in[14];
    const float* outB   = (const float*)d_in[15];
    const float* ln1g   = (const float*)d_in[16];
    const float* ln1b   = (const float*)d_in[17];
    const float* ln2g   = (const float*)d_in[18];
    const float* ln2b   = (const float*)d_in[19];
    const float* fw1    = (const float*)d_in[20];
    const float* fb1    = (const float*)d_in[21];
    const float* fw2    = (const float*)d_in[22];
    const float* fb2    = (const float*)d_in[23];
    const float* fusW   = (const float*)d_in[24];
    const float* fusB   = (const float*)d_in[25];
    float* out = (float*)d_out;

    // ---- workspace layout (float offsets from R); peak ~119 MB ----
    float* ws  = (float*)d_ws;
    float* acc = ws;                              // 6,400,000 f32
    float* R   = ws + 6400000;
    // stage A:
    ushort* xb   = (ushort*)(R);                  // 6.4M shorts
    ushort* hb   = (ushort*)(R + 3200000);        // 6.4M shorts
    ushort* gbx  = (ushort*)(R + 6400000);        // 6.4M shorts
    float*  als  = R + 9600000;                   // 200,000
    float*  ald  = R + 9800000;                   // 200,000
    int*   cntA  = (int*)(R + 10000000);          // 50,000
    int*   offA  = (int*)(R + 10050000);          // 50,001
    int*   curA  = (int*)(R + 10100004);          // 50,000
    int*   srcsA = (int*)(R + 10150004);          // 450,000
    ushort* gatWb= (ushort*)(R + 10600004);       // 49,152 shorts
    ushort* decWb= (ushort*)(R + 10624580);       // 49,152 shorts
    // stage B (aliases stage A):
    float*  ybuf  = R;                            // 2,611,200
    float*  tmp   = R + 2611200;                  // 2,611,200
    ushort* ybx   = (ushort*)(R + 5222400);       // 2,611,200 shorts
    ushort* attnb = (ushort*)(R + 6528000);       // 2,611,200 shorts
    ushort* qkvb  = (ushort*)(R + 7833600);       // 7,833,600 shorts
    ushort* midb  = (ushort*)(R + 11750400);      // 20,889,600 shorts (10200x2048)
    ushort* finb  = midb;                         // 5,222,400 shorts
    float*  pooled= R + 22195200;                 // 3,840
    int*    cntb  = (int*)(R + 22199040);         // 32
    int*    posb  = cntb + 32;                    // 20,400
    ushort* qkvWb = (ushort*)(R + 22220000);      // 196,608 shorts
    ushort* outWb = (ushort*)(R + 22318304);      // 65,536 shorts
    ushort* fw1b  = (ushort*)(R + 22351072);      // 1,048,576 shorts
    ushort* fw2b  = (ushort*)(R + 22875360);      // 1,048,576 shorts
    ushort* fusWb = (ushort*)(R + 23399648);      // 32,768 shorts

    const float decay[3] = { 1.0f, 0.90483741803595952f, 0.81873075307798182f };

    // ================= Stage A: 3-hop GAT =================
    cvt32<<<(6400000 / 8 + 255) / 256, 256, 0, stream>>>(x, xb, 6400000 / 8);
    cvt32<<<(49152 / 8 + 255) / 256, 256, 0, stream>>>(gatW, gatWb, 49152 / 8);
    cvt32<<<(49152 / 8 + 255) / 256, 256, 0, stream>>>(decW, decWb, 49152 / 8);
    for (int k = 0; k < 3; k++) {
        gemm_lds<128, 0, 0, 1><<<dim3(391, 1), 256, 0, stream>>>(
            xb, gatWb + k * DIM * DIM, nullptr, hb, N_NODES, DIM, DIM, 1.f);
        gat_al<<<(N_NODES * 4 + 255) / 256, 256, 0, stream>>>(
            hb, attS + k * DIM, attD + k * DIM, als, ald, N_NODES);
        // CSR build
        csr_init<<<(N_NODES + 255) / 256, 256, 0, stream>>>(cntA);
        csr_deg<<<(N_EDGES + 255) / 256, 256, 0, stream>>>(e[k] + N_EDGES, cntA);
        csr_scan<<<1, 1024, 0, stream>>>(cntA, offA, curA);
        csr_scat<<<(N_EDGES + N_NODES + 255) / 256, 256, 0, stream>>>(
            e[k], e[k] + N_EDGES, curA, srcsA);
        gat_gather<<<(N_NODES * 64 + 255) / 256, 256, 0, stream>>>(
            offA, srcsA, hb, als, ald, gatB + k * DIM, gbx);
        if (k == 0)
            gemm_lds<128, 1, 0, 0><<<dim3(391, 1), 256, 0, stream>>>(
                gbx, decWb, decB, acc, N_NODES, DIM, DIM, 1.f);
        else
            gemm_lds<128, 1, 1, 0><<<dim3(391, 1), 256, 0, stream>>>(
                gbx, decWb + k * DIM * DIM, decB + k * DIM, acc, N_NODES, DIM, DIM, decay[k]);
    }

    // ================= Stage B: genre transformer =================
    cvt32<<<(196608 / 8 + 255) / 256, 256, 0, stream>>>(qkvW, qkvWb, 196608 / 8);
    cvt32<<<(65536 / 8 + 255) / 256, 256, 0, stream>>>(outW, outWb, 65536 / 8);
    cvt32<<<(1048576 / 8 + 255) / 256, 256, 0, stream>>>(fw1, fw1b, 1048576 / 8);
    cvt32<<<(1048576 / 8 + 255) / 256, 256, 0, stream>>>(fw2, fw2b, 1048576 / 8);
    cvt32<<<(32768 / 8 + 255) / 256, 256, 0, stream>>>(fusW, fusWb, 32768 / 8);

    hipMemsetAsync(cntb, 0, 32 * 4, stream);
    calc_pos<<<(N_MOVIE + 255) / 256, 256, 0, stream>>>(genre, posb, cntb, N_MOVIE);
    build_y<<<N_MOVIE, 128, 0, stream>>>(acc, midx, genre, posb, ybuf, ybx);

    const int CH_ROWS = 10200;   // 2 FFN chunks
    for (int l = 0; l < N_LAYERS; l++) {
        gemm_lds<128, 0, 0, 1><<<dim3(160, 3), 256, 0, stream>>>(
            ybx, qkvWb + (size_t)l * 384 * DIM, qkvB + l * 384, qkvb, NROWS, 384, DIM, 1.f);
        flash_attn<<<dim3(6, 4, 30), 256, 0, stream>>>(qkvb, cntb, attnb);
        gemm_lds<64, 0, 0, 0><<<dim3(319, 1), 256, 0, stream>>>(
            attnb, outWb + (size_t)l * DIM * DIM, outB + l * DIM, tmp, NROWS, DIM, DIM, 1.f);
        ln_res<<<NROWS, 128, 0, stream>>>(ybuf, tmp, ln1g + l * DIM, ln1b + l * DIM, ybx);
        for (int ch = 0; ch < 2; ch++) {
            const size_t ro = (size_t)ch * CH_ROWS * DIM;
            gemm_lds<128, 2, 0, 1><<<dim3(80, 16), 256, 0, stream>>>(
                ybx + ro, fw1b + (size_t)l * FF * DIM, fb1 + l * FF,
                midb, CH_ROWS, FF, DIM, 1.f);
            gemm_lds<64, 0, 0, 0><<<dim3(160, 1), 256, 0, stream>>>(
                midb, fw2b + (size_t)l * FF * DIM, fb2 + l * DIM,
                tmp + ro, CH_ROWS, DIM, FF, 1.f);
        }
        ln_res<<<NROWS, 128, 0, stream>>>(ybuf, tmp, ln2g + l * DIM, ln2b + l * DIM, ybx);
    }

    pool_kernel<<<N_GENRE, 256, 0, stream>>>(ybuf, cntb, pooled);
    build_fin<<<N_MOVIE, 256, 0, stream>>>(acc, pooled, midx, genre, finb);
    gemm_lds<64, 1, 0, 0><<<dim3(319, 1), 256, 0, stream>>>(
        finb, fusWb, fusB, tmp, NROWS, DIM, 256, 1.f);

    hipMemcpyAsync(out, acc, (size_t)6400000 * 4, hipMemcpyDeviceToDevice, stream);
    scatter_movies<<<N_MOVIE, 128, 0, stream>>>(tmp, midx, out);
}

// Round 6
// 1906.744 us; speedup vs baseline: 5.6588x; 1.1729x over previous
//
#include <hip/hip_runtime.h>

#define N_NODES  50000
#define N_EDGES  400000
#define DIM      128
#define N_MOVIE  20400
#define N_GENRE  30
#define L_MAX    680
#define NROWS    (N_GENRE * L_MAX)   /* 20400 */
#define FF       2048
#define N_LAYERS 4
#define SCAN_NBLK 196               /* ceil(50000/256) */

typedef __attribute__((ext_vector_type(8))) short bf16x8;
typedef __attribute__((ext_vector_type(4))) float f32x4;

#define MFMA16 __builtin_amdgcn_mfma_f32_16x16x32_bf16

__device__ __forceinline__ float b2f(ushort u) {
    union { unsigned i; float f; } c; c.i = ((unsigned)u) << 16; return c.f;
}
__device__ __forceinline__ ushort f2b(float f) {
    union { float f; unsigned i; } c; c.f = f;
    unsigned u = c.i;
    u += 0x7FFFu + ((u >> 16) & 1u);   // RNE
    return (ushort)(u >> 16);
}
__device__ __forceinline__ bf16x8 load8s(const ushort* p) {
    return *(const bf16x8*)p;
}
// async global->LDS, 16B per lane; LDS dest must be wave-uniform base + lane*16
__device__ __forceinline__ void async16(const ushort* g, ushort* l) {
    __builtin_amdgcn_global_load_lds(
        (const __attribute__((address_space(1))) void*)g,
        (__attribute__((address_space(3))) void*)l, 16, 0, 0);
}

// fp32 -> bf16, 8 elems/thread
__global__ void cvt32(const float* __restrict__ s, ushort* __restrict__ d, int n8)
{
    int i = blockIdx.x * blockDim.x + threadIdx.x;
    if (i >= n8) return;
    const float4* q = (const float4*)(s + (size_t)i * 8);
    float4 a = q[0], b = q[1];
    bf16x8 r;
    r[0] = (short)f2b(a.x); r[1] = (short)f2b(a.y);
    r[2] = (short)f2b(a.z); r[3] = (short)f2b(a.w);
    r[4] = (short)f2b(b.x); r[5] = (short)f2b(b.y);
    r[6] = (short)f2b(b.z); r[7] = (short)f2b(b.w);
    *(bf16x8*)(d + (size_t)i * 8) = r;
}

// ============ LDS-staged GEMM: C[M,N] = epi(A @ W^T + bias) ============
template<int BM, int ACT, int EPI, int OBF>
__global__ __launch_bounds__(256) void gemm_lds(
    const ushort* __restrict__ A, const ushort* __restrict__ W,
    const float* __restrict__ bias, void* __restrict__ Cv,
    int M, int N, int K, float scale)
{
    __shared__ ushort As[BM * 32];
    __shared__ ushort Ws[128 * 32];
    const int tid  = threadIdx.x;
    const int wave = tid >> 6, lane = tid & 63;
    const int quad = lane >> 4, l16 = lane & 15;
    const int m0 = blockIdx.x * BM;
    const int n0 = blockIdx.y * 128;

    constexpr int MT = BM / 32;
    const int mbase = (wave & 1) * (BM / 2);
    const int nbase = (wave >> 1) * 64;

    const int srow = wave * 16 + (lane >> 2);
    const int skof = (lane & 3) * 8;

    f32x4 acc[MT][4] = {};
    for (int k0 = 0; k0 < K; k0 += 32) {
#pragma unroll
        for (int i = 0; i < BM / 64; i++) {
            int r = i * 64 + srow;
            int rg = min(m0 + r, M - 1);
            async16(A + (size_t)rg * K + k0 + skof, As + r * 32 + skof);
        }
#pragma unroll
        for (int i = 0; i < 2; i++) {
            int r = i * 64 + srow;
            async16(W + (size_t)(n0 + r) * K + k0 + skof, Ws + r * 32 + skof);
        }
        __syncthreads();

        bf16x8 a[MT], b[4];
#pragma unroll
        for (int mt = 0; mt < MT; mt++)
            a[mt] = load8s(As + (mbase + mt * 16 + l16) * 32 + quad * 8);
#pragma unroll
        for (int nt = 0; nt < 4; nt++)
            b[nt] = load8s(Ws + (nbase + nt * 16 + l16) * 32 + quad * 8);
#pragma unroll
        for (int mt = 0; mt < MT; mt++)
#pragma unroll
            for (int nt = 0; nt < 4; nt++)
                acc[mt][nt] = MFMA16(a[mt], b[nt], acc[mt][nt], 0, 0, 0);
        __syncthreads();
    }

#pragma unroll
    for (int nt = 0; nt < 4; nt++) {
        const int col = n0 + nbase + nt * 16 + l16;
        const float bv = bias ? bias[col] : 0.f;
#pragma unroll
        for (int mt = 0; mt < MT; mt++) {
#pragma unroll
            for (int r = 0; r < 4; r++) {
                const int row = m0 + mbase + mt * 16 + quad * 4 + r;
                if (row < M) {
                    float v = acc[mt][nt][r] + bv;
                    if (ACT == 1) v = (v >= 0.f) ? v : 0.01f * v;
                    if (ACT == 2) v = fmaxf(v, 0.f);
                    const size_t idx = (size_t)row * N + col;
                    if (OBF)           ((ushort*)Cv)[idx] = f2b(v);
                    else if (EPI == 1) ((float*)Cv)[idx] += scale * v;
                    else               ((float*)Cv)[idx] = v;
                }
            }
        }
    }
}

// per-(node,head) attention logit halves (h in bf16)
__global__ void gat_al(const ushort* __restrict__ h,
                       const float* __restrict__ asrc, const float* __restrict__ adst,
                       float* __restrict__ als, float* __restrict__ ald, int N)
{
    int idx = blockIdx.x * blockDim.x + threadIdx.x;
    if (idx >= N * 4) return;
    int n = idx >> 2, hh = idx & 3;
    const ushort* hp = h + (size_t)n * DIM + hh * 32;
    float s = 0.f, d = 0.f;
#pragma unroll 8
    for (int c = 0; c < 32; c++) {
        float v = b2f(hp[c]);
        s += v * asrc[hh * 32 + c];
        d += v * adst[hh * 32 + c];
    }
    als[idx] = s; ald[idx] = d;
}

// ---------------- CSR build ----------------
__global__ void csr_deg(const int* __restrict__ dst, int* __restrict__ cnt) {
    int i = blockIdx.x * 256 + threadIdx.x;
    if (i < N_EDGES) atomicAdd(&cnt[dst[i]], 1);
}

// phase 1: per-block exclusive scan (+1 folds self-loop into count)
__global__ __launch_bounds__(256) void scan_blk(
    const int* __restrict__ cnt, int* __restrict__ off, int* __restrict__ bsum)
{
    __shared__ int sh[256];
    const int t = threadIdx.x;
    const int i = blockIdx.x * 256 + t;
    int v = (i < N_NODES) ? cnt[i] + 1 : 0;
    sh[t] = v;
    __syncthreads();
    for (int d = 1; d < 256; d <<= 1) {
        int x = (t >= d) ? sh[t - d] : 0;
        __syncthreads();
        sh[t] += x;
        __syncthreads();
    }
    if (i < N_NODES) off[i] = sh[t] - v;
    if (t == 255) bsum[blockIdx.x] = sh[255];
}
// phase 2: exclusive scan of block sums (196 <= 256), in-place
__global__ __launch_bounds__(256) void scan_top(int* __restrict__ bsum)
{
    __shared__ int sh[256];
    const int t = threadIdx.x;
    int v = (t < SCAN_NBLK) ? bsum[t] : 0;
    sh[t] = v;
    __syncthreads();
    for (int d = 1; d < 256; d <<= 1) {
        int x = (t >= d) ? sh[t - d] : 0;
        __syncthreads();
        sh[t] += x;
        __syncthreads();
    }
    if (t < SCAN_NBLK) bsum[t] = sh[t] - v;
}
// phase 3: add block prefix; init cur; off[N] = fixed total
__global__ __launch_bounds__(256) void scan_add(
    int* __restrict__ off, const int* __restrict__ bsum, int* __restrict__ cur)
{
    const int i = blockIdx.x * 256 + threadIdx.x;
    if (i < N_NODES) {
        int o = off[i] + bsum[blockIdx.x];
        off[i] = o; cur[i] = o;
    }
    if (i == 0) off[N_NODES] = N_EDGES + N_NODES;
}

__global__ void csr_scat(const int* __restrict__ src, const int* __restrict__ dst,
                         int* __restrict__ cur, int* __restrict__ srcs)
{
    int i = blockIdx.x * 256 + threadIdx.x;
    if (i < N_EDGES) {
        int p = atomicAdd(&cur[dst[i]], 1);
        srcs[p] = src[i];
    } else if (i < N_EDGES + N_NODES) {
        int n = i - N_EDGES;
        int p = atomicAdd(&cur[n], 1);
        srcs[p] = n;   // self-loop
    }
}

// one wave per dst: registers accumulate sum(w*h[src]) & sum(w); fold norm+bias; bf16 out
__global__ __launch_bounds__(256) void gat_gather(
    const int* __restrict__ off, const int* __restrict__ srcs,
    const ushort* __restrict__ hb, const float* __restrict__ als,
    const float* __restrict__ ald, const float* __restrict__ bias,
    ushort* __restrict__ ob)
{
    int w = (blockIdx.x * 256 + threadIdx.x) >> 6;
    int lane = threadIdx.x & 63;
    if (w >= N_NODES) return;
    const int h0 = lane >> 5, h1 = 2 + h0;
    const float ad0 = ald[(size_t)w * 4 + h0], ad1 = ald[(size_t)w * 4 + h1];
    const int jb = off[w], je = off[w + 1];
    float acc0 = 0.f, acc1 = 0.f, ws0 = 0.f, ws1 = 0.f;
    for (int j = jb; j < je; j++) {
        int s = srcs[j];
        float e0 = als[(size_t)s * 4 + h0] + ad0; e0 = (e0 >= 0.f) ? e0 : 0.2f * e0;
        float e1 = als[(size_t)s * 4 + h1] + ad1; e1 = (e1 >= 0.f) ? e1 : 0.2f * e1;
        float w0 = __expf(e0), w1 = __expf(e1);
        ws0 += w0; ws1 += w1;
        acc0 += w0 * b2f(hb[(size_t)s * DIM + lane]);
        acc1 += w1 * b2f(hb[(size_t)s * DIM + 64 + lane]);
    }
    ob[(size_t)w * DIM + lane]      = f2b(acc0 / ws0 + bias[lane]);
    ob[(size_t)w * DIM + 64 + lane] = f2b(acc1 / ws1 + bias[64 + lane]);
}

__global__ void calc_pos(const int* __restrict__ genre, int* __restrict__ pos,
                         int* __restrict__ cnt, int NM)
{
    int i = blockIdx.x * blockDim.x + threadIdx.x;
    if (i < NM) pos[i] = atomicAdd(&cnt[genre[i]], 1);
}

__global__ void build_y(const float* __restrict__ acc, const int* __restrict__ midx,
                        const int* __restrict__ genre, const int* __restrict__ pos,
                        float* __restrict__ y, ushort* __restrict__ yb)
{
    int i = blockIdx.x, c = threadIdx.x;
    int g = genre[i], p = pos[i];
    float v = acc[(size_t)midx[i] * DIM + c];
    size_t o = ((size_t)g * L_MAX + p) * DIM + c;
    y[o] = v; yb[o] = f2b(v);
}

// ===================== MFMA flash attention (bf16 in/out) =====================
#define SV 712
#define SP 40

__global__ __launch_bounds__(256) void flash_attn(
    const ushort* __restrict__ qkv, const int* __restrict__ cnt,
    ushort* __restrict__ o)
{
    __shared__ ushort vT[32 * SV];
    __shared__ ushort Pb[4][32 * SP];

    const int qt = blockIdx.x, hh = blockIdx.y, g = blockIdx.z;
    const int t = threadIdx.x, wave = t >> 6, lane = t & 63;
    const int quad = lane >> 4, l16 = lane & 15;
    const int L = cnt[g];
    const float scale = 0.17677669529663687f;
    const ushort* base = qkv + (size_t)g * L_MAX * 384;

    for (int i = t; i < L_MAX * 32; i += 256) {
        int k = i >> 5, d = i & 31;
        vT[d * SV + k] = (k < L) ? base[(size_t)k * 384 + 256 + hh * 32 + d] : (ushort)0;
    }
    for (int i = t; i < 32 * 32; i += 256) {
        int k = L_MAX + (i & 31), d = i >> 5;
        if (k < 704) vT[d * SV + k] = 0;
    }
    __syncthreads();

    const int q0 = qt * 128 + wave * 32;
    const int rq0 = min(q0 + l16, L_MAX - 1);
    const int rq1 = min(q0 + 16 + l16, L_MAX - 1);
    bf16x8 a0 = load8s(base + (size_t)rq0 * 384 + hh * 32 + quad * 8);
    bf16x8 a1 = load8s(base + (size_t)rq1 * 384 + hh * 32 + quad * 8);

    f32x4 oacc[2][2] = {};
    float rsum[2][4] = {};
    ushort* P = Pb[wave];

    for (int kt = 0; kt < 704; kt += 32) {
        const int rk0 = min(kt + l16, L_MAX - 1);
        const int rk1 = min(kt + 16 + l16, L_MAX - 1);
        bf16x8 b0 = load8s(base + (size_t)rk0 * 384 + 128 + hh * 32 + quad * 8);
        bf16x8 b1 = load8s(base + (size_t)rk1 * 384 + 128 + hh * 32 + quad * 8);
        f32x4 z = {};
        f32x4 s[2][2];
        s[0][0] = MFMA16(a0, b0, z, 0, 0, 0);
        s[0][1] = MFMA16(a0, b1, z, 0, 0, 0);
        s[1][0] = MFMA16(a1, b0, z, 0, 0, 0);
        s[1][1] = MFMA16(a1, b1, z, 0, 0, 0);

#pragma unroll
        for (int mi = 0; mi < 2; mi++)
#pragma unroll
            for (int j = 0; j < 2; j++) {
                const int kc = kt + j * 16 + l16;
                const bool ok = kc < L;
#pragma unroll
                for (int r = 0; r < 4; r++) {
                    float w = ok ? __expf(s[mi][j][r] * scale) : 0.f;
                    rsum[mi][r] += w;
                    P[(mi * 16 + quad * 4 + r) * SP + j * 16 + l16] = f2b(w);
                }
            }
        __syncthreads();

        bf16x8 p0 = load8s(P + (size_t)l16 * SP + quad * 8);
        bf16x8 p1 = load8s(P + (size_t)(16 + l16) * SP + quad * 8);
        bf16x8 v0 = load8s(vT + (size_t)l16 * SV + kt + quad * 8);
        bf16x8 v1 = load8s(vT + (size_t)(16 + l16) * SV + kt + quad * 8);
        oacc[0][0] = MFMA16(p0, v0, oacc[0][0], 0, 0, 0);
        oacc[0][1] = MFMA16(p0, v1, oacc[0][1], 0, 0, 0);
        oacc[1][0] = MFMA16(p1, v0, oacc[1][0], 0, 0, 0);
        oacc[1][1] = MFMA16(p1, v1, oacc[1][1], 0, 0, 0);
        __syncthreads();
    }

#pragma unroll
    for (int mi = 0; mi < 2; mi++)
#pragma unroll
        for (int r = 0; r < 4; r++) {
            float s = rsum[mi][r];
            s += __shfl_xor(s, 1, 64);
            s += __shfl_xor(s, 2, 64);
            s += __shfl_xor(s, 4, 64);
            s += __shfl_xor(s, 8, 64);
            rsum[mi][r] = s;
        }

#pragma unroll
    for (int mi = 0; mi < 2; mi++)
#pragma unroll
        for (int j = 0; j < 2; j++)
#pragma unroll
            for (int r = 0; r < 4; r++) {
                const int q = q0 + mi * 16 + quad * 4 + r;
                if (q < L_MAX)
                    o[((size_t)(g * L_MAX + q)) * DIM + hh * 32 + j * 16 + l16] =
                        f2b(oacc[mi][j][r] / rsum[mi][r]);
            }
}

// y = LN(y + res) * g + b; writes fp32 y and bf16 yb
__global__ __launch_bounds__(128) void ln_res(
    float* __restrict__ y, const float* __restrict__ res,
    const float* __restrict__ g, const float* __restrict__ b,
    ushort* __restrict__ yb)
{
    __shared__ float sh[2], sh2[2];
    const int r = blockIdx.x, t = threadIdx.x;
    const size_t base = (size_t)r * DIM;
    float v = y[base + t] + res[base + t];
    float s = v;
    for (int off = 32; off; off >>= 1) s += __shfl_down(s, off, 64);
    if ((t & 63) == 0) sh[t >> 6] = s;
    __syncthreads();
    const float mean = (sh[0] + sh[1]) * (1.f / 128.f);
    const float d = v - mean;
    float q = d * d;
    for (int off = 32; off; off >>= 1) q += __shfl_down(q, off, 64);
    if ((t & 63) == 0) sh2[t >> 6] = q;
    __syncthreads();
    const float var = (sh2[0] + sh2[1]) * (1.f / 128.f);
    float o = d * rsqrtf(var + 1e-5f) * g[t] + b[t];
    y[base + t] = o; yb[base + t] = f2b(o);
}

__global__ __launch_bounds__(256) void pool_kernel(
    const float* __restrict__ y, const int* __restrict__ cnt, float* __restrict__ pooled)
{
    __shared__ float sh[128];
    const int g = blockIdx.x, t = threadIdx.x;
    const int c = t & 127, h = t >> 7;
    const int L = cnt[g];
    float s = 0.f;
    for (int k = h; k < L; k += 2) s += y[((size_t)g * L_MAX + k) * DIM + c];
    if (h) sh[c] = s;
    __syncthreads();
    if (!h) pooled[g * DIM + c] = (s + sh[c]) / (float)max(L, 1);
}

__global__ void build_fin(const float* __restrict__ acc, const float* __restrict__ pooled,
                          const int* __restrict__ midx, const int* __restrict__ genre,
                          ushort* __restrict__ A2)
{
    const int i = blockIdx.x, t = threadIdx.x;
    float v = (t < 128) ? acc[(size_t)midx[i] * DIM + t]
                        : pooled[genre[i] * DIM + (t - 128)];
    A2[(size_t)i * 256 + t] = f2b(v);
}

__global__ void scatter_movies(const float* __restrict__ fused, const int* __restrict__ midx,
                               float* __restrict__ out)
{
    const int i = blockIdx.x, c = threadIdx.x;
    out[(size_t)midx[i] * DIM + c] = fused[(size_t)i * DIM + c];
}

extern "C" void kernel_launch(void* const* d_in, const int* in_sizes, int n_in,
                              void* d_out, int out_size, void* d_ws, size_t ws_size,
                              hipStream_t stream)
{
    const float* x      = (const float*)d_in[0];
    const int* e[3]     = { (const int*)d_in[1], (const int*)d_in[2], (const int*)d_in[3] };
    const int* midx     = (const int*)d_in[4];
    const int* genre    = (const int*)d_in[5];
    const float* gatW   = (const float*)d_in[6];
    const float* attS   = (const float*)d_in[7];
    const float* attD   = (const float*)d_in[8];
    const float* gatB   = (const float*)d_in[9];
    const float* decW   = (const float*)d_in[10];
    const float* decB   = (const float*)d_in[11];
    const float* qkvW   = (const float*)d_in[12];
    const float* qkvB   = (const float*)d_in[13];
    const float* outW   = (const float*)d_in[14];
    const float* outB   = (const float*)d_in[15];
    const float* ln1g   = (const float*)d_in[16];
    const float* ln1b   = (const float*)d_in[17];
    const float* ln2g   = (const float*)d_in[18];
    const float* ln2b   = (const float*)d_in[19];
    const float* fw1    = (const float*)d_in[20];
    const float* fb1    = (const float*)d_in[21];
    const float* fw2    = (const float*)d_in[22];
    const float* fb2    = (const float*)d_in[23];
    const float* fusW   = (const float*)d_in[24];
    const float* fusB   = (const float*)d_in[25];
    float* out = (float*)d_out;

    // ---- workspace layout (float offsets from R); peak ~119 MB ----
    float* ws  = (float*)d_ws;
    float* acc = ws;                              // 6,400,000 f32
    float* R   = ws + 6400000;
    // stage A:
    ushort* xb   = (ushort*)(R);                  // 6.4M shorts
    ushort* hb   = (ushort*)(R + 3200000);        // 6.4M shorts
    ushort* gbx  = (ushort*)(R + 6400000);        // 6.4M shorts
    float*  als  = R + 9600000;                   // 200,000
    float*  ald  = R + 9800000;                   // 200,000
    int*   cntA  = (int*)(R + 10000000);          // 50,000
    int*   offA  = (int*)(R + 10050000);          // 50,001
    int*   curA  = (int*)(R + 10100004);          // 50,000
    int*   srcsA = (int*)(R + 10150004);          // 450,000
    ushort* gatWb= (ushort*)(R + 10600004);       // 49,152 shorts
    ushort* decWb= (ushort*)(R + 10624580);       // 49,152 shorts
    int*    bsum = (int*)(R + 10649156);          // 256
    // stage B (aliases stage A):
    float*  ybuf  = R;                            // 2,611,200
    float*  tmp   = R + 2611200;                  // 2,611,200
    ushort* ybx   = (ushort*)(R + 5222400);       // 2,611,200 shorts
    ushort* attnb = (ushort*)(R + 6528000);       // 2,611,200 shorts
    ushort* qkvb  = (ushort*)(R + 7833600);       // 7,833,600 shorts
    ushort* midb  = (ushort*)(R + 11750400);      // 20,889,600 shorts
    ushort* finb  = midb;                         // 5,222,400 shorts
    float*  pooled= R + 22195200;                 // 3,840
    int*    cntb  = (int*)(R + 22199040);         // 32
    int*    posb  = cntb + 32;                    // 20,400
    ushort* qkvWb = (ushort*)(R + 22220000);      // 196,608 shorts
    ushort* outWb = (ushort*)(R + 22318304);      // 65,536 shorts
    ushort* fw1b  = (ushort*)(R + 22351072);      // 1,048,576 shorts
    ushort* fw2b  = (ushort*)(R + 22875360);      // 1,048,576 shorts
    ushort* fusWb = (ushort*)(R + 23399648);      // 32,768 shorts

    const float decay[3] = { 1.0f, 0.90483741803595952f, 0.81873075307798182f };

    // ================= Stage A: 3-hop GAT =================
    cvt32<<<(6400000 / 8 + 255) / 256, 256, 0, stream>>>(x, xb, 6400000 / 8);
    cvt32<<<(49152 / 8 + 255) / 256, 256, 0, stream>>>(gatW, gatWb, 49152 / 8);
    cvt32<<<(49152 / 8 + 255) / 256, 256, 0, stream>>>(decW, decWb, 49152 / 8);
    for (int k = 0; k < 3; k++) {
        gemm_lds<128, 0, 0, 1><<<dim3(391, 1), 256, 0, stream>>>(
            xb, gatWb + k * DIM * DIM, nullptr, hb, N_NODES, DIM, DIM, 1.f);
        gat_al<<<(N_NODES * 4 + 255) / 256, 256, 0, stream>>>(
            hb, attS + k * DIM, attD + k * DIM, als, ald, N_NODES);
        // CSR build (multi-block scan)
        hipMemsetAsync(cntA, 0, N_NODES * 4, stream);
        csr_deg<<<(N_EDGES + 255) / 256, 256, 0, stream>>>(e[k] + N_EDGES, cntA);
        scan_blk<<<SCAN_NBLK, 256, 0, stream>>>(cntA, offA, bsum);
        scan_top<<<1, 256, 0, stream>>>(bsum);
        scan_add<<<SCAN_NBLK, 256, 0, stream>>>(offA, bsum, curA);
        csr_scat<<<(N_EDGES + N_NODES + 255) / 256, 256, 0, stream>>>(
            e[k], e[k] + N_EDGES, curA, srcsA);
        gat_gather<<<(N_NODES * 64 + 255) / 256, 256, 0, stream>>>(
            offA, srcsA, hb, als, ald, gatB + k * DIM, gbx);
        if (k == 0)
            gemm_lds<128, 1, 0, 0><<<dim3(391, 1), 256, 0, stream>>>(
                gbx, decWb, decB, acc, N_NODES, DIM, DIM, 1.f);
        else
            gemm_lds<128, 1, 1, 0><<<dim3(391, 1), 256, 0, stream>>>(
                gbx, decWb + k * DIM * DIM, decB + k * DIM, acc, N_NODES, DIM, DIM, decay[k]);
    }

    // ================= Stage B: genre transformer =================
    cvt32<<<(196608 / 8 + 255) / 256, 256, 0, stream>>>(qkvW, qkvWb, 196608 / 8);
    cvt32<<<(65536 / 8 + 255) / 256, 256, 0, stream>>>(outW, outWb, 65536 / 8);
    cvt32<<<(1048576 / 8 + 255) / 256, 256, 0, stream>>>(fw1, fw1b, 1048576 / 8);
    cvt32<<<(1048576 / 8 + 255) / 256, 256, 0, stream>>>(fw2, fw2b, 1048576 / 8);
    cvt32<<<(32768 / 8 + 255) / 256, 256, 0, stream>>>(fusW, fusWb, 32768 / 8);

    hipMemsetAsync(cntb, 0, 32 * 4, stream);
    calc_pos<<<(N_MOVIE + 255) / 256, 256, 0, stream>>>(genre, posb, cntb, N_MOVIE);
    build_y<<<N_MOVIE, 128, 0, stream>>>(acc, midx, genre, posb, ybuf, ybx);

    const int CH_ROWS = 10200;   // 2 FFN chunks
    for (int l = 0; l < N_LAYERS; l++) {
        gemm_lds<128, 0, 0, 1><<<dim3(160, 3), 256, 0, stream>>>(
            ybx, qkvWb + (size_t)l * 384 * DIM, qkvB + l * 384, qkvb, NROWS, 384, DIM, 1.f);
        flash_attn<<<dim3(6, 4, 30), 256, 0, stream>>>(qkvb, cntb, attnb);
        gemm_lds<64, 0, 0, 0><<<dim3(319, 1), 256, 0, stream>>>(
            attnb, outWb + (size_t)l * DIM * DIM, outB + l * DIM, tmp, NROWS, DIM, DIM, 1.f);
        ln_res<<<NROWS, 128, 0, stream>>>(ybuf, tmp, ln1g + l * DIM, ln1b + l * DIM, ybx);
        for (int ch = 0; ch < 2; ch++) {
            const size_t ro = (size_t)ch * CH_ROWS * DIM;
            gemm_lds<128, 2, 0, 1><<<dim3(80, 16), 256, 0, stream>>>(
                ybx + ro, fw1b + (size_t)l * FF * DIM, fb1 + l * FF,
                midb, CH_ROWS, FF, DIM, 1.f);
            gemm_lds<64, 0, 0, 0><<<dim3(160, 1), 256, 0, stream>>>(
                midb, fw2b + (size_t)l * FF * DIM, fb2 + l * DIM,
                tmp + ro, CH_ROWS, DIM, FF, 1.f);
        }
        ln_res<<<NROWS, 128, 0, stream>>>(ybuf, tmp, ln2g + l * DIM, ln2b + l * DIM, ybx);
    }

    pool_kernel<<<N_GENRE, 256, 0, stream>>>(ybuf, cntb, pooled);
    build_fin<<<N_MOVIE, 256, 0, stream>>>(acc, pooled, midx, genre, finb);
    gemm_lds<64, 1, 0, 0><<<dim3(319, 1), 256, 0, stream>>>(
        finb, fusWb, fusB, tmp, NROWS, DIM, 256, 1.f);

    hipMemcpyAsync(out, acc, (size_t)6400000 * 4, hipMemcpyDeviceToDevice, stream);
    scatter_movies<<<N_MOVIE, 128, 0, stream>>>(tmp, midx, out);
}

// Round 7
// 1839.993 us; speedup vs baseline: 5.8641x; 1.0363x over previous
//
#include <hip/hip_runtime.h>

#define N_NODES  50000
#define N_EDGES  400000
#define DIM      128
#define N_MOVIE  20400
#define N_GENRE  30
#define L_MAX    680
#define NROWS    (N_GENRE * L_MAX)   /* 20400 */
#define FF       2048
#define N_LAYERS 4
#define SCAN_NBLK 196               /* ceil(50000/256) */

typedef __attribute__((ext_vector_type(8))) short bf16x8;
typedef __attribute__((ext_vector_type(4))) float f32x4;

#define MFMA16 __builtin_amdgcn_mfma_f32_16x16x32_bf16

__device__ __forceinline__ float b2f(ushort u) {
    union { unsigned i; float f; } c; c.i = ((unsigned)u) << 16; return c.f;
}
__device__ __forceinline__ ushort f2b(float f) {
    union { float f; unsigned i; } c; c.f = f;
    unsigned u = c.i;
    u += 0x7FFFu + ((u >> 16) & 1u);   // RNE
    return (ushort)(u >> 16);
}
__device__ __forceinline__ bf16x8 load8s(const ushort* p) {
    return *(const bf16x8*)p;
}
// async global->LDS, 16B per lane; LDS dest must be wave-uniform base + lane*16
__device__ __forceinline__ void async16(const ushort* g, ushort* l) {
    __builtin_amdgcn_global_load_lds(
        (const __attribute__((address_space(1))) void*)g,
        (__attribute__((address_space(3))) void*)l, 16, 0, 0);
}

// fp32 -> bf16, 8 elems/thread
__global__ void cvt32(const float* __restrict__ s, ushort* __restrict__ d, int n8)
{
    int i = blockIdx.x * blockDim.x + threadIdx.x;
    if (i >= n8) return;
    const float4* q = (const float4*)(s + (size_t)i * 8);
    float4 a = q[0], b = q[1];
    bf16x8 r;
    r[0] = (short)f2b(a.x); r[1] = (short)f2b(a.y);
    r[2] = (short)f2b(a.z); r[3] = (short)f2b(a.w);
    r[4] = (short)f2b(b.x); r[5] = (short)f2b(b.y);
    r[6] = (short)f2b(b.z); r[7] = (short)f2b(b.w);
    *(bf16x8*)(d + (size_t)i * 8) = r;
}

// ============ LDS-staged GEMM: C[M,N] = epi(A @ W^T + bias) ============
template<int BM, int ACT, int EPI, int OBF>
__global__ __launch_bounds__(256) void gemm_lds(
    const ushort* __restrict__ A, const ushort* __restrict__ W,
    const float* __restrict__ bias, void* __restrict__ Cv,
    int M, int N, int K, float scale)
{
    __shared__ ushort As[BM * 32];
    __shared__ ushort Ws[128 * 32];
    const int tid  = threadIdx.x;
    const int wave = tid >> 6, lane = tid & 63;
    const int quad = lane >> 4, l16 = lane & 15;
    const int m0 = blockIdx.x * BM;
    const int n0 = blockIdx.y * 128;

    constexpr int MT = BM / 32;
    const int mbase = (wave & 1) * (BM / 2);
    const int nbase = (wave >> 1) * 64;

    const int srow = wave * 16 + (lane >> 2);
    const int skof = (lane & 3) * 8;

    f32x4 acc[MT][4] = {};
    for (int k0 = 0; k0 < K; k0 += 32) {
#pragma unroll
        for (int i = 0; i < BM / 64; i++) {
            int r = i * 64 + srow;
            int rg = min(m0 + r, M - 1);
            async16(A + (size_t)rg * K + k0 + skof, As + r * 32 + skof);
        }
#pragma unroll
        for (int i = 0; i < 2; i++) {
            int r = i * 64 + srow;
            async16(W + (size_t)(n0 + r) * K + k0 + skof, Ws + r * 32 + skof);
        }
        __syncthreads();

        bf16x8 a[MT], b[4];
#pragma unroll
        for (int mt = 0; mt < MT; mt++)
            a[mt] = load8s(As + (mbase + mt * 16 + l16) * 32 + quad * 8);
#pragma unroll
        for (int nt = 0; nt < 4; nt++)
            b[nt] = load8s(Ws + (nbase + nt * 16 + l16) * 32 + quad * 8);
#pragma unroll
        for (int mt = 0; mt < MT; mt++)
#pragma unroll
            for (int nt = 0; nt < 4; nt++)
                acc[mt][nt] = MFMA16(a[mt], b[nt], acc[mt][nt], 0, 0, 0);
        __syncthreads();
    }

#pragma unroll
    for (int nt = 0; nt < 4; nt++) {
        const int col = n0 + nbase + nt * 16 + l16;
        const float bv = bias ? bias[col] : 0.f;
#pragma unroll
        for (int mt = 0; mt < MT; mt++) {
#pragma unroll
            for (int r = 0; r < 4; r++) {
                const int row = m0 + mbase + mt * 16 + quad * 4 + r;
                if (row < M) {
                    float v = acc[mt][nt][r] + bv;
                    if (ACT == 1) v = (v >= 0.f) ? v : 0.01f * v;
                    if (ACT == 2) v = fmaxf(v, 0.f);
                    const size_t idx = (size_t)row * N + col;
                    if (OBF)           ((ushort*)Cv)[idx] = f2b(v);
                    else if (EPI == 1) ((float*)Cv)[idx] += scale * v;
                    else               ((float*)Cv)[idx] = v;
                }
            }
        }
    }
}

// per-(node,head) attention logit halves (h in bf16)
__global__ void gat_al(const ushort* __restrict__ h,
                       const float* __restrict__ asrc, const float* __restrict__ adst,
                       float* __restrict__ als, float* __restrict__ ald, int N)
{
    int idx = blockIdx.x * blockDim.x + threadIdx.x;
    if (idx >= N * 4) return;
    int n = idx >> 2, hh = idx & 3;
    const ushort* hp = h + (size_t)n * DIM + hh * 32;
    float s = 0.f, d = 0.f;
#pragma unroll 8
    for (int c = 0; c < 32; c++) {
        float v = b2f(hp[c]);
        s += v * asrc[hh * 32 + c];
        d += v * adst[hh * 32 + c];
    }
    als[idx] = s; ald[idx] = d;
}

// ---------------- CSR build ----------------
__global__ void csr_deg(const int* __restrict__ dst, int* __restrict__ cnt) {
    int i = blockIdx.x * 256 + threadIdx.x;
    if (i < N_EDGES) atomicAdd(&cnt[dst[i]], 1);
}

__global__ __launch_bounds__(256) void scan_blk(
    const int* __restrict__ cnt, int* __restrict__ off, int* __restrict__ bsum)
{
    __shared__ int sh[256];
    const int t = threadIdx.x;
    const int i = blockIdx.x * 256 + t;
    int v = (i < N_NODES) ? cnt[i] + 1 : 0;
    sh[t] = v;
    __syncthreads();
    for (int d = 1; d < 256; d <<= 1) {
        int x = (t >= d) ? sh[t - d] : 0;
        __syncthreads();
        sh[t] += x;
        __syncthreads();
    }
    if (i < N_NODES) off[i] = sh[t] - v;
    if (t == 255) bsum[blockIdx.x] = sh[255];
}
__global__ __launch_bounds__(256) void scan_top(int* __restrict__ bsum)
{
    __shared__ int sh[256];
    const int t = threadIdx.x;
    int v = (t < SCAN_NBLK) ? bsum[t] : 0;
    sh[t] = v;
    __syncthreads();
    for (int d = 1; d < 256; d <<= 1) {
        int x = (t >= d) ? sh[t - d] : 0;
        __syncthreads();
        sh[t] += x;
        __syncthreads();
    }
    if (t < SCAN_NBLK) bsum[t] = sh[t] - v;
}
__global__ __launch_bounds__(256) void scan_add(
    int* __restrict__ off, const int* __restrict__ bsum, int* __restrict__ cur)
{
    const int i = blockIdx.x * 256 + threadIdx.x;
    if (i < N_NODES) {
        int o = off[i] + bsum[blockIdx.x];
        off[i] = o; cur[i] = o;
    }
    if (i == 0) off[N_NODES] = N_EDGES + N_NODES;
}

__global__ void csr_scat(const int* __restrict__ src, const int* __restrict__ dst,
                         int* __restrict__ cur, int* __restrict__ srcs)
{
    int i = blockIdx.x * 256 + threadIdx.x;
    if (i < N_EDGES) {
        int p = atomicAdd(&cur[dst[i]], 1);
        srcs[p] = src[i];
    } else if (i < N_EDGES + N_NODES) {
        int n = i - N_EDGES;
        int p = atomicAdd(&cur[n], 1);
        srcs[p] = n;   // self-loop
    }
}

// one wave per dst: registers accumulate sum(w*h[src]) & sum(w); fold norm+bias; bf16 out
__global__ __launch_bounds__(256) void gat_gather(
    const int* __restrict__ off, const int* __restrict__ srcs,
    const ushort* __restrict__ hb, const float* __restrict__ als,
    const float* __restrict__ ald, const float* __restrict__ bias,
    ushort* __restrict__ ob)
{
    int w = (blockIdx.x * 256 + threadIdx.x) >> 6;
    int lane = threadIdx.x & 63;
    if (w >= N_NODES) return;
    const int h0 = lane >> 5, h1 = 2 + h0;
    const float ad0 = ald[(size_t)w * 4 + h0], ad1 = ald[(size_t)w * 4 + h1];
    const int jb = off[w], je = off[w + 1];
    float acc0 = 0.f, acc1 = 0.f, ws0 = 0.f, ws1 = 0.f;
    for (int j = jb; j < je; j++) {
        int s = srcs[j];
        float e0 = als[(size_t)s * 4 + h0] + ad0; e0 = (e0 >= 0.f) ? e0 : 0.2f * e0;
        float e1 = als[(size_t)s * 4 + h1] + ad1; e1 = (e1 >= 0.f) ? e1 : 0.2f * e1;
        float w0 = __expf(e0), w1 = __expf(e1);
        ws0 += w0; ws1 += w1;
        acc0 += w0 * b2f(hb[(size_t)s * DIM + lane]);
        acc1 += w1 * b2f(hb[(size_t)s * DIM + 64 + lane]);
    }
    ob[(size_t)w * DIM + lane]      = f2b(acc0 / ws0 + bias[lane]);
    ob[(size_t)w * DIM + 64 + lane] = f2b(acc1 / ws1 + bias[64 + lane]);
}

__global__ void calc_pos(const int* __restrict__ genre, int* __restrict__ pos,
                         int* __restrict__ cnt, int NM)
{
    int i = blockIdx.x * blockDim.x + threadIdx.x;
    if (i < NM) pos[i] = atomicAdd(&cnt[genre[i]], 1);
}

__global__ void build_y(const float* __restrict__ acc, const int* __restrict__ midx,
                        const int* __restrict__ genre, const int* __restrict__ pos,
                        float* __restrict__ y, ushort* __restrict__ yb)
{
    int i = blockIdx.x, c = threadIdx.x;
    int g = genre[i], p = pos[i];
    float v = acc[(size_t)midx[i] * DIM + c];
    size_t o = ((size_t)g * L_MAX + p) * DIM + c;
    y[o] = v; yb[o] = f2b(v);
}

// ============ barrier-free MFMA flash attention (S^T formulation) ============
// grid (qt=6, head=4, genre=30); 4 waves, each 32 q-rows.
// S^T = MFMA(K_frag, Q_frag): lane holds col=q (l16), row=k-col (quad*4+r).
// P^T written as packed b64 rows P[q][kcol]; PV via O^T = MFMA(V^T_frag, P^T_frag).
#define SV 712   /* vT row stride in shorts (1424 B, 16B-aligned, 2-way-conflict reads) */
#define SP 40    /* P row stride in shorts (80 B, 16B-aligned, <=2-way) */

__global__ __launch_bounds__(256) void flash_attn(
    const ushort* __restrict__ qkv, const int* __restrict__ cnt,
    ushort* __restrict__ o)
{
    __shared__ ushort vT[32 * SV];        // 45568 B, read-only after stage
    __shared__ ushort Pb[4][32 * SP];     // 10240 B, wave-private tiles

    const int qt = blockIdx.x, hh = blockIdx.y, g = blockIdx.z;
    const int t = threadIdx.x, wave = t >> 6, lane = t & 63;
    const int quad = lane >> 4, l16 = lane & 15;
    const int L = cnt[g];
    const float scale = 0.17677669529663687f;   // 1/sqrt(32)
    const ushort* base = qkv + (size_t)g * L_MAX * 384;

    // stage V^T (coalesced global read, strided LDS write), pad k=680..703 with 0
    for (int i = t; i < L_MAX * 32; i += 256) {
        int k = i >> 5, d = i & 31;
        vT[d * SV + k] = (k < L) ? base[(size_t)k * 384 + 256 + hh * 32 + d] : (ushort)0;
    }
    for (int i = t; i < 32 * 24; i += 256) {
        int k = L_MAX + (i % 24), d = i / 24;
        vT[d * SV + k] = 0;
    }
    __syncthreads();   // vT visible to all waves; last barrier in the kernel

    const int q0 = qt * 128 + wave * 32;
    bf16x8 a0 = load8s(base + (size_t)min(q0 + l16,      L_MAX - 1) * 384 + hh * 32 + quad * 8);
    bf16x8 a1 = load8s(base + (size_t)min(q0 + 16 + l16, L_MAX - 1) * 384 + hh * 32 + quad * 8);

    f32x4 oacc[2][2] = {};        // [dhalf][qhalf], O^T layout
    float rsum[2] = {0.f, 0.f};   // per qhalf, quad-partial (q = l16)
    ushort* P = Pb[wave];

    for (int kt = 0; kt < 704; kt += 32) {
        bf16x8 b0 = load8s(base + (size_t)min(kt + l16,      L_MAX - 1) * 384 + 128 + hh * 32 + quad * 8);
        bf16x8 b1 = load8s(base + (size_t)min(kt + 16 + l16, L_MAX - 1) * 384 + 128 + hh * 32 + quad * 8);
        f32x4 z = {};
        f32x4 st00 = MFMA16(b0, a0, z, 0, 0, 0);   // S^T[k 0..15][q 0..15]
        f32x4 st01 = MFMA16(b0, a1, z, 0, 0, 0);   // S^T[k 0..15][q 16..31]
        f32x4 st10 = MFMA16(b1, a0, z, 0, 0, 0);   // S^T[k 16..31][q 0..15]
        f32x4 st11 = MFMA16(b1, a1, z, 0, 0, 0);

        const int kc0 = kt + quad * 4, kc1 = kt + 16 + quad * 4;
#pragma unroll
        for (int qh = 0; qh < 2; qh++) {
            const f32x4 sA = qh ? st01 : st00;
            const f32x4 sB = qh ? st11 : st10;
            float w[8];
#pragma unroll
            for (int r = 0; r < 4; r++) {
                w[r]     = (kc0 + r < L) ? __expf(sA[r] * scale) : 0.f;
                w[4 + r] = (kc1 + r < L) ? __expf(sB[r] * scale) : 0.f;
                rsum[qh] += w[r] + w[4 + r];
            }
            ushort4 pk0, pk1;
            pk0.x = f2b(w[0]); pk0.y = f2b(w[1]); pk0.z = f2b(w[2]); pk0.w = f2b(w[3]);
            pk1.x = f2b(w[4]); pk1.y = f2b(w[5]); pk1.z = f2b(w[6]); pk1.w = f2b(w[7]);
            *(ushort4*)(P + (qh * 16 + l16) * SP + quad * 4)      = pk0;   // kcols kt+quad*4..+3
            *(ushort4*)(P + (qh * 16 + l16) * SP + 16 + quad * 4) = pk1;   // kcols kt+16+quad*4..+3
        }
        // wave-private P: in-wave lgkmcnt ordering suffices, no barrier
        bf16x8 p0 = load8s(P + (size_t)l16 * SP + quad * 8);         // P^T B-frag, q 0..15
        bf16x8 p1 = load8s(P + (size_t)(16 + l16) * SP + quad * 8);  // q 16..31
        bf16x8 v0 = load8s(vT + (size_t)l16 * SV + kt + quad * 8);   // V^T A-frag, d 0..15
        bf16x8 v1 = load8s(vT + (size_t)(16 + l16) * SV + kt + quad * 8);
        oacc[0][0] = MFMA16(v0, p0, oacc[0][0], 0, 0, 0);
        oacc[0][1] = MFMA16(v0, p1, oacc[0][1], 0, 0, 0);
        oacc[1][0] = MFMA16(v1, p0, oacc[1][0], 0, 0, 0);
        oacc[1][1] = MFMA16(v1, p1, oacc[1][1], 0, 0, 0);
    }

#pragma unroll
    for (int qh = 0; qh < 2; qh++) {
        float s = rsum[qh];
        s += __shfl_xor(s, 16, 64);
        s += __shfl_xor(s, 32, 64);
        const int q = q0 + qh * 16 + l16;
        if (q < L_MAX) {
            const float inv = 1.f / s;
#pragma unroll
            for (int dh = 0; dh < 2; dh++) {
                ushort4 pk;
                pk.x = f2b(oacc[dh][qh][0] * inv);
                pk.y = f2b(oacc[dh][qh][1] * inv);
                pk.z = f2b(oacc[dh][qh][2] * inv);
                pk.w = f2b(oacc[dh][qh][3] * inv);
                *(ushort4*)(o + ((size_t)(g * L_MAX + q)) * DIM + hh * 32 + dh * 16 + quad * 4) = pk;
            }
        }
    }
}

// y = LN(y + res) * g + b; writes fp32 y and bf16 yb
__global__ __launch_bounds__(128) void ln_res(
    float* __restrict__ y, const float* __restrict__ res,
    const float* __restrict__ g, const float* __restrict__ b,
    ushort* __restrict__ yb)
{
    __shared__ float sh[2], sh2[2];
    const int r = blockIdx.x, t = threadIdx.x;
    const size_t base = (size_t)r * DIM;
    float v = y[base + t] + res[base + t];
    float s = v;
    for (int off = 32; off; off >>= 1) s += __shfl_down(s, off, 64);
    if ((t & 63) == 0) sh[t >> 6] = s;
    __syncthreads();
    const float mean = (sh[0] + sh[1]) * (1.f / 128.f);
    const float d = v - mean;
    float q = d * d;
    for (int off = 32; off; off >>= 1) q += __shfl_down(q, off, 64);
    if ((t & 63) == 0) sh2[t >> 6] = q;
    __syncthreads();
    const float var = (sh2[0] + sh2[1]) * (1.f / 128.f);
    float o = d * rsqrtf(var + 1e-5f) * g[t] + b[t];
    y[base + t] = o; yb[base + t] = f2b(o);
}

__global__ __launch_bounds__(256) void pool_kernel(
    const float* __restrict__ y, const int* __restrict__ cnt, float* __restrict__ pooled)
{
    __shared__ float sh[128];
    const int g = blockIdx.x, t = threadIdx.x;
    const int c = t & 127, h = t >> 7;
    const int L = cnt[g];
    float s = 0.f;
    for (int k = h; k < L; k += 2) s += y[((size_t)g * L_MAX + k) * DIM + c];
    if (h) sh[c] = s;
    __syncthreads();
    if (!h) pooled[g * DIM + c] = (s + sh[c]) / (float)max(L, 1);
}

__global__ void build_fin(const float* __restrict__ acc, const float* __restrict__ pooled,
                          const int* __restrict__ midx, const int* __restrict__ genre,
                          ushort* __restrict__ A2)
{
    const int i = blockIdx.x, t = threadIdx.x;
    float v = (t < 128) ? acc[(size_t)midx[i] * DIM + t]
                        : pooled[genre[i] * DIM + (t - 128)];
    A2[(size_t)i * 256 + t] = f2b(v);
}

__global__ void scatter_movies(const float* __restrict__ fused, const int* __restrict__ midx,
                               float* __restrict__ out)
{
    const int i = blockIdx.x, c = threadIdx.x;
    out[(size_t)midx[i] * DIM + c] = fused[(size_t)i * DIM + c];
}

extern "C" void kernel_launch(void* const* d_in, const int* in_sizes, int n_in,
                              void* d_out, int out_size, void* d_ws, size_t ws_size,
                              hipStream_t stream)
{
    const float* x      = (const float*)d_in[0];
    const int* e[3]     = { (const int*)d_in[1], (const int*)d_in[2], (const int*)d_in[3] };
    const int* midx     = (const int*)d_in[4];
    const int* genre    = (const int*)d_in[5];
    const float* gatW   = (const float*)d_in[6];
    const float* attS   = (const float*)d_in[7];
    const float* attD   = (const float*)d_in[8];
    const float* gatB   = (const float*)d_in[9];
    const float* decW   = (const float*)d_in[10];
    const float* decB   = (const float*)d_in[11];
    const float* qkvW   = (const float*)d_in[12];
    const float* qkvB   = (const float*)d_in[13];
    const float* outW   = (const float*)d_in[14];
    const float* outB   = (const float*)d_in[15];
    const float* ln1g   = (const float*)d_in[16];
    const float* ln1b   = (const float*)d_in[17];
    const float* ln2g   = (const float*)d_in[18];
    const float* ln2b   = (const float*)d_in[19];
    const float* fw1    = (const float*)d_in[20];
    const float* fb1    = (const float*)d_in[21];
    const float* fw2    = (const float*)d_in[22];
    const float* fb2    = (const float*)d_in[23];
    const float* fusW   = (const float*)d_in[24];
    const float* fusB   = (const float*)d_in[25];
    float* out = (float*)d_out;

    // ---- workspace layout (float offsets from R); peak ~119 MB ----
    float* ws  = (float*)d_ws;
    float* acc = ws;                              // 6,400,000 f32
    float* R   = ws + 6400000;
    // stage A:
    ushort* xb   = (ushort*)(R);                  // 6.4M shorts
    ushort* hb   = (ushort*)(R + 3200000);        // 6.4M shorts
    ushort* gbx  = (ushort*)(R + 6400000);        // 6.4M shorts
    float*  als  = R + 9600000;                   // 200,000
    float*  ald  = R + 9800000;                   // 200,000
    int*   cntA  = (int*)(R + 10000000);          // 50,000
    int*   offA  = (int*)(R + 10050000);          // 50,001
    int*   curA  = (int*)(R + 10100004);          // 50,000
    int*   srcsA = (int*)(R + 10150004);          // 450,000
    ushort* gatWb= (ushort*)(R + 10600004);       // 49,152 shorts
    ushort* decWb= (ushort*)(R + 10624580);       // 49,152 shorts
    int*    bsum = (int*)(R + 10649156);          // 256
    // stage B (aliases stage A):
    float*  ybuf  = R;                            // 2,611,200
    float*  tmp   = R + 2611200;                  // 2,611,200
    ushort* ybx   = (ushort*)(R + 5222400);       // 2,611,200 shorts
    ushort* attnb = (ushort*)(R + 6528000);       // 2,611,200 shorts
    ushort* qkvb  = (ushort*)(R + 7833600);       // 7,833,600 shorts
    ushort* midb  = (ushort*)(R + 11750400);      // 20,889,600 shorts
    ushort* finb  = midb;                         // 5,222,400 shorts
    float*  pooled= R + 22195200;                 // 3,840
    int*    cntb  = (int*)(R + 22199040);         // 32
    int*    posb  = cntb + 32;                    // 20,400
    ushort* qkvWb = (ushort*)(R + 22220000);      // 196,608 shorts
    ushort* outWb = (ushort*)(R + 22318304);      // 65,536 shorts
    ushort* fw1b  = (ushort*)(R + 22351072);      // 1,048,576 shorts
    ushort* fw2b  = (ushort*)(R + 22875360);      // 1,048,576 shorts
    ushort* fusWb = (ushort*)(R + 23399648);      // 32,768 shorts

    const float decay[3] = { 1.0f, 0.90483741803595952f, 0.81873075307798182f };

    // ================= Stage A: 3-hop GAT =================
    cvt32<<<(6400000 / 8 + 255) / 256, 256, 0, stream>>>(x, xb, 6400000 / 8);
    cvt32<<<(49152 / 8 + 255) / 256, 256, 0, stream>>>(gatW, gatWb, 49152 / 8);
    cvt32<<<(49152 / 8 + 255) / 256, 256, 0, stream>>>(decW, decWb, 49152 / 8);
    for (int k = 0; k < 3; k++) {
        gemm_lds<128, 0, 0, 1><<<dim3(391, 1), 256, 0, stream>>>(
            xb, gatWb + k * DIM * DIM, nullptr, hb, N_NODES, DIM, DIM, 1.f);
        gat_al<<<(N_NODES * 4 + 255) / 256, 256, 0, stream>>>(
            hb, attS + k * DIM, attD + k * DIM, als, ald, N_NODES);
        hipMemsetAsync(cntA, 0, N_NODES * 4, stream);
        csr_deg<<<(N_EDGES + 255) / 256, 256, 0, stream>>>(e[k] + N_EDGES, cntA);
        scan_blk<<<SCAN_NBLK, 256, 0, stream>>>(cntA, offA, bsum);
        scan_top<<<1, 256, 0, stream>>>(bsum);
        scan_add<<<SCAN_NBLK, 256, 0, stream>>>(offA, bsum, curA);
        csr_scat<<<(N_EDGES + N_NODES + 255) / 256, 256, 0, stream>>>(
            e[k], e[k] + N_EDGES, curA, srcsA);
        gat_gather<<<(N_NODES * 64 + 255) / 256, 256, 0, stream>>>(
            offA, srcsA, hb, als, ald, gatB + k * DIM, gbx);
        if (k == 0)
            gemm_lds<128, 1, 0, 0><<<dim3(391, 1), 256, 0, stream>>>(
                gbx, decWb, decB, acc, N_NODES, DIM, DIM, 1.f);
        else
            gemm_lds<128, 1, 1, 0><<<dim3(391, 1), 256, 0, stream>>>(
                gbx, decWb + k * DIM * DIM, decB + k * DIM, acc, N_NODES, DIM, DIM, decay[k]);
    }

    // ================= Stage B: genre transformer =================
    cvt32<<<(196608 / 8 + 255) / 256, 256, 0, stream>>>(qkvW, qkvWb, 196608 / 8);
    cvt32<<<(65536 / 8 + 255) / 256, 256, 0, stream>>>(outW, outWb, 65536 / 8);
    cvt32<<<(1048576 / 8 + 255) / 256, 256, 0, stream>>>(fw1, fw1b, 1048576 / 8);
    cvt32<<<(1048576 / 8 + 255) / 256, 256, 0, stream>>>(fw2, fw2b, 1048576 / 8);
    cvt32<<<(32768 / 8 + 255) / 256, 256, 0, stream>>>(fusW, fusWb, 32768 / 8);

    hipMemsetAsync(cntb, 0, 32 * 4, stream);
    calc_pos<<<(N_MOVIE + 255) / 256, 256, 0, stream>>>(genre, posb, cntb, N_MOVIE);
    build_y<<<N_MOVIE, 128, 0, stream>>>(acc, midx, genre, posb, ybuf, ybx);

    const int CH_ROWS = 10200;   // 2 FFN chunks
    for (int l = 0; l < N_LAYERS; l++) {
        gemm_lds<128, 0, 0, 1><<<dim3(160, 3), 256, 0, stream>>>(
            ybx, qkvWb + (size_t)l * 384 * DIM, qkvB + l * 384, qkvb, NROWS, 384, DIM, 1.f);
        flash_attn<<<dim3(6, 4, 30), 256, 0, stream>>>(qkvb, cntb, attnb);
        gemm_lds<64, 0, 0, 0><<<dim3(319, 1), 256, 0, stream>>>(
            attnb, outWb + (size_t)l * DIM * DIM, outB + l * DIM, tmp, NROWS, DIM, DIM, 1.f);
        ln_res<<<NROWS, 128, 0, stream>>>(ybuf, tmp, ln1g + l * DIM, ln1b + l * DIM, ybx);
        for (int ch = 0; ch < 2; ch++) {
            const size_t ro = (size_t)ch * CH_ROWS * DIM;
            gemm_lds<128, 2, 0, 1><<<dim3(80, 16), 256, 0, stream>>>(
                ybx + ro, fw1b + (size_t)l * FF * DIM, fb1 + l * FF,
                midb, CH_ROWS, FF, DIM, 1.f);
            gemm_lds<64, 0, 0, 0><<<dim3(160, 1), 256, 0, stream>>>(
                midb, fw2b + (size_t)l * FF * DIM, fb2 + l * DIM,
                tmp + ro, CH_ROWS, DIM, FF, 1.f);
        }
        ln_res<<<NROWS, 128, 0, stream>>>(ybuf, tmp, ln2g + l * DIM, ln2b + l * DIM, ybx);
    }

    pool_kernel<<<N_GENRE, 256, 0, stream>>>(ybuf, cntb, pooled);
    build_fin<<<N_MOVIE, 256, 0, stream>>>(acc, pooled, midx, genre, finb);
    gemm_lds<64, 1, 0, 0><<<dim3(319, 1), 256, 0, stream>>>(
        finb, fusWb, fusB, tmp, NROWS, DIM, 256, 1.f);

    hipMemcpyAsync(out, acc, (size_t)6400000 * 4, hipMemcpyDeviceToDevice, stream);
    scatter_movies<<<N_MOVIE, 128, 0, stream>>>(tmp, midx, out);
}

// Round 8
// 1646.735 us; speedup vs baseline: 6.5523x; 1.1174x over previous
//
#include <hip/hip_runtime.h>

#define N_NODES  50000
#define N_EDGES  400000
#define DIM      128
#define N_MOVIE  20400
#define N_GENRE  30
#define L_MAX    680
#define NROWS    (N_GENRE * L_MAX)   /* 20400 */
#define FF       2048
#define N_LAYERS 4
#define SCAN_NBLK 196               /* ceil(50000/256) */

typedef __attribute__((ext_vector_type(8))) short bf16x8;
typedef __attribute__((ext_vector_type(4))) float f32x4;

#define MFMA16 __builtin_amdgcn_mfma_f32_16x16x32_bf16

__device__ __forceinline__ float b2f(ushort u) {
    union { unsigned i; float f; } c; c.i = ((unsigned)u) << 16; return c.f;
}
__device__ __forceinline__ ushort f2b(float f) {
    union { float f; unsigned i; } c; c.f = f;
    unsigned u = c.i;
    u += 0x7FFFu + ((u >> 16) & 1u);   // RNE
    return (ushort)(u >> 16);
}
__device__ __forceinline__ bf16x8 load8s(const ushort* p) {
    return *(const bf16x8*)p;
}
// async global->LDS, 16B per lane; LDS dest must be wave-uniform base + lane*16
__device__ __forceinline__ void async16(const ushort* g, ushort* l) {
    __builtin_amdgcn_global_load_lds(
        (const __attribute__((address_space(1))) void*)g,
        (__attribute__((address_space(3))) void*)l, 16, 0, 0);
}

// fp32 -> bf16, 8 elems/thread
__global__ void cvt32(const float* __restrict__ s, ushort* __restrict__ d, int n8)
{
    int i = blockIdx.x * blockDim.x + threadIdx.x;
    if (i >= n8) return;
    const float4* q = (const float4*)(s + (size_t)i * 8);
    float4 a = q[0], b = q[1];
    bf16x8 r;
    r[0] = (short)f2b(a.x); r[1] = (short)f2b(a.y);
    r[2] = (short)f2b(a.z); r[3] = (short)f2b(a.w);
    r[4] = (short)f2b(b.x); r[5] = (short)f2b(b.y);
    r[6] = (short)f2b(b.z); r[7] = (short)f2b(b.w);
    *(bf16x8*)(d + (size_t)i * 8) = r;
}

// ============ LDS-staged GEMM: C[M,N] = epi(A @ W^T + bias) ============
// OBF: 0 = f32 out, 1 = bf16 out, 2 = bf16 TRANSPOSED out (Cv[col*M + row],
//      packed ushort4 over 4 consecutive rows — feeds flash_attn V^T).
template<int BM, int ACT, int EPI, int OBF>
__global__ __launch_bounds__(256) void gemm_lds(
    const ushort* __restrict__ A, const ushort* __restrict__ W,
    const float* __restrict__ bias, void* __restrict__ Cv,
    int M, int N, int K, float scale)
{
    __shared__ ushort As[BM * 32];
    __shared__ ushort Ws[128 * 32];
    const int tid  = threadIdx.x;
    const int wave = tid >> 6, lane = tid & 63;
    const int quad = lane >> 4, l16 = lane & 15;
    const int m0 = blockIdx.x * BM;
    const int n0 = blockIdx.y * 128;

    constexpr int MT = BM / 32;
    const int mbase = (wave & 1) * (BM / 2);
    const int nbase = (wave >> 1) * 64;

    const int srow = wave * 16 + (lane >> 2);
    const int skof = (lane & 3) * 8;

    f32x4 acc[MT][4] = {};
    for (int k0 = 0; k0 < K; k0 += 32) {
#pragma unroll
        for (int i = 0; i < BM / 64; i++) {
            int r = i * 64 + srow;
            int rg = min(m0 + r, M - 1);
            async16(A + (size_t)rg * K + k0 + skof, As + r * 32 + skof);
        }
#pragma unroll
        for (int i = 0; i < 2; i++) {
            int r = i * 64 + srow;
            async16(W + (size_t)(n0 + r) * K + k0 + skof, Ws + r * 32 + skof);
        }
        __syncthreads();

        bf16x8 a[MT], b[4];
#pragma unroll
        for (int mt = 0; mt < MT; mt++)
            a[mt] = load8s(As + (mbase + mt * 16 + l16) * 32 + quad * 8);
#pragma unroll
        for (int nt = 0; nt < 4; nt++)
            b[nt] = load8s(Ws + (nbase + nt * 16 + l16) * 32 + quad * 8);
#pragma unroll
        for (int mt = 0; mt < MT; mt++)
#pragma unroll
            for (int nt = 0; nt < 4; nt++)
                acc[mt][nt] = MFMA16(a[mt], b[nt], acc[mt][nt], 0, 0, 0);
        __syncthreads();
    }

#pragma unroll
    for (int nt = 0; nt < 4; nt++) {
        const int col = n0 + nbase + nt * 16 + l16;
        const float bv = bias ? bias[col] : 0.f;
#pragma unroll
        for (int mt = 0; mt < MT; mt++) {
            if (OBF == 2) {
                const int row0 = m0 + mbase + mt * 16 + quad * 4;
                if (row0 < M) {          // M % 4 == 0: all-or-nothing
                    ushort4 pk;
                    pk.x = f2b(acc[mt][nt][0] + bv);
                    pk.y = f2b(acc[mt][nt][1] + bv);
                    pk.z = f2b(acc[mt][nt][2] + bv);
                    pk.w = f2b(acc[mt][nt][3] + bv);
                    *(ushort4*)((ushort*)Cv + (size_t)col * M + row0) = pk;
                }
            } else {
#pragma unroll
                for (int r = 0; r < 4; r++) {
                    const int row = m0 + mbase + mt * 16 + quad * 4 + r;
                    if (row < M) {
                        float v = acc[mt][nt][r] + bv;
                        if (ACT == 1) v = (v >= 0.f) ? v : 0.01f * v;
                        if (ACT == 2) v = fmaxf(v, 0.f);
                        const size_t idx = (size_t)row * N + col;
                        if (OBF == 1)      ((ushort*)Cv)[idx] = f2b(v);
                        else if (EPI == 1) ((float*)Cv)[idx] += scale * v;
                        else               ((float*)Cv)[idx] = v;
                    }
                }
            }
        }
    }
}

// per-(node,head) attention logit halves (h in bf16)
__global__ void gat_al(const ushort* __restrict__ h,
                       const float* __restrict__ asrc, const float* __restrict__ adst,
                       float* __restrict__ als, float* __restrict__ ald, int N)
{
    int idx = blockIdx.x * blockDim.x + threadIdx.x;
    if (idx >= N * 4) return;
    int n = idx >> 2, hh = idx & 3;
    const ushort* hp = h + (size_t)n * DIM + hh * 32;
    float s = 0.f, d = 0.f;
#pragma unroll 8
    for (int c = 0; c < 32; c++) {
        float v = b2f(hp[c]);
        s += v * asrc[hh * 32 + c];
        d += v * adst[hh * 32 + c];
    }
    als[idx] = s; ald[idx] = d;
}

// ---------------- CSR build ----------------
__global__ void csr_deg(const int* __restrict__ dst, int* __restrict__ cnt) {
    int i = blockIdx.x * 256 + threadIdx.x;
    if (i < N_EDGES) atomicAdd(&cnt[dst[i]], 1);
}

__global__ __launch_bounds__(256) void scan_blk(
    const int* __restrict__ cnt, int* __restrict__ off, int* __restrict__ bsum)
{
    __shared__ int sh[256];
    const int t = threadIdx.x;
    const int i = blockIdx.x * 256 + t;
    int v = (i < N_NODES) ? cnt[i] + 1 : 0;
    sh[t] = v;
    __syncthreads();
    for (int d = 1; d < 256; d <<= 1) {
        int x = (t >= d) ? sh[t - d] : 0;
        __syncthreads();
        sh[t] += x;
        __syncthreads();
    }
    if (i < N_NODES) off[i] = sh[t] - v;
    if (t == 255) bsum[blockIdx.x] = sh[255];
}
__global__ __launch_bounds__(256) void scan_top(int* __restrict__ bsum)
{
    __shared__ int sh[256];
    const int t = threadIdx.x;
    int v = (t < SCAN_NBLK) ? bsum[t] : 0;
    sh[t] = v;
    __syncthreads();
    for (int d = 1; d < 256; d <<= 1) {
        int x = (t >= d) ? sh[t - d] : 0;
        __syncthreads();
        sh[t] += x;
        __syncthreads();
    }
    if (t < SCAN_NBLK) bsum[t] = sh[t] - v;
}
__global__ __launch_bounds__(256) void scan_add(
    int* __restrict__ off, const int* __restrict__ bsum, int* __restrict__ cur)
{
    const int i = blockIdx.x * 256 + threadIdx.x;
    if (i < N_NODES) {
        int o = off[i] + bsum[blockIdx.x];
        off[i] = o; cur[i] = o;
    }
    if (i == 0) off[N_NODES] = N_EDGES + N_NODES;
}

__global__ void csr_scat(const int* __restrict__ src, const int* __restrict__ dst,
                         int* __restrict__ cur, int* __restrict__ srcs)
{
    int i = blockIdx.x * 256 + threadIdx.x;
    if (i < N_EDGES) {
        int p = atomicAdd(&cur[dst[i]], 1);
        srcs[p] = src[i];
    } else if (i < N_EDGES + N_NODES) {
        int n = i - N_EDGES;
        int p = atomicAdd(&cur[n], 1);
        srcs[p] = n;   // self-loop
    }
}

// one wave per dst: registers accumulate sum(w*h[src]) & sum(w); fold norm+bias; bf16 out
__global__ __launch_bounds__(256) void gat_gather(
    const int* __restrict__ off, const int* __restrict__ srcs,
    const ushort* __restrict__ hb, const float* __restrict__ als,
    const float* __restrict__ ald, const float* __restrict__ bias,
    ushort* __restrict__ ob)
{
    int w = (blockIdx.x * 256 + threadIdx.x) >> 6;
    int lane = threadIdx.x & 63;
    if (w >= N_NODES) return;
    const int h0 = lane >> 5, h1 = 2 + h0;
    const float ad0 = ald[(size_t)w * 4 + h0], ad1 = ald[(size_t)w * 4 + h1];
    const int jb = off[w], je = off[w + 1];
    float acc0 = 0.f, acc1 = 0.f, ws0 = 0.f, ws1 = 0.f;
    for (int j = jb; j < je; j++) {
        int s = srcs[j];
        float e0 = als[(size_t)s * 4 + h0] + ad0; e0 = (e0 >= 0.f) ? e0 : 0.2f * e0;
        float e1 = als[(size_t)s * 4 + h1] + ad1; e1 = (e1 >= 0.f) ? e1 : 0.2f * e1;
        float w0 = __expf(e0), w1 = __expf(e1);
        ws0 += w0; ws1 += w1;
        acc0 += w0 * b2f(hb[(size_t)s * DIM + lane]);
        acc1 += w1 * b2f(hb[(size_t)s * DIM + 64 + lane]);
    }
    ob[(size_t)w * DIM + lane]      = f2b(acc0 / ws0 + bias[lane]);
    ob[(size_t)w * DIM + 64 + lane] = f2b(acc1 / ws1 + bias[64 + lane]);
}

__global__ void calc_pos(const int* __restrict__ genre, int* __restrict__ pos,
                         int* __restrict__ cnt, int NM)
{
    int i = blockIdx.x * blockDim.x + threadIdx.x;
    if (i < NM) pos[i] = atomicAdd(&cnt[genre[i]], 1);
}

__global__ void build_y(const float* __restrict__ acc, const int* __restrict__ midx,
                        const int* __restrict__ genre, const int* __restrict__ pos,
                        float* __restrict__ y, ushort* __restrict__ yb)
{
    int i = blockIdx.x, c = threadIdx.x;
    int g = genre[i], p = pos[i];
    float v = acc[(size_t)midx[i] * DIM + c];
    size_t o = ((size_t)g * L_MAX + p) * DIM + c;
    y[o] = v; yb[o] = f2b(v);
}

// ======== barrier-free flash attention: V^T pre-transposed in global ========
// qk: [g*680 + l][256] (Q 0..127, K 128..255); vtg: [d 0..127][Lglobal 20400]
// grid (qt=6, head=4, genre=30); 4 waves, each 32 q-rows; LDS = P tiles only.
#define SP 40    /* P row stride in shorts (80 B, 16B-aligned) */

__global__ __launch_bounds__(256) void flash_attn(
    const ushort* __restrict__ qk, const ushort* __restrict__ vtg,
    const int* __restrict__ cnt, ushort* __restrict__ o)
{
    __shared__ ushort Pb[4][32 * SP];     // 10240 B, wave-private tiles

    const int qt = blockIdx.x, hh = blockIdx.y, g = blockIdx.z;
    const int t = threadIdx.x, wave = t >> 6, lane = t & 63;
    const int quad = lane >> 4, l16 = lane & 15;
    const int L = cnt[g];
    const float scale = 0.17677669529663687f;   // 1/sqrt(32)
    const ushort* base = qk + (size_t)g * L_MAX * 256;
    const ushort* vb0 = vtg + (size_t)(hh * 32 + l16) * NROWS + g * L_MAX;
    const ushort* vb1 = vb0 + (size_t)16 * NROWS;

    const int q0 = qt * 128 + wave * 32;
    bf16x8 a0 = load8s(base + (size_t)min(q0 + l16,      L_MAX - 1) * 256 + hh * 32 + quad * 8);
    bf16x8 a1 = load8s(base + (size_t)min(q0 + 16 + l16, L_MAX - 1) * 256 + hh * 32 + quad * 8);

    f32x4 oacc[2][2] = {};        // [dhalf][qhalf], O^T layout
    float rsum[2] = {0.f, 0.f};   // per qhalf (q = l16), quad-partial
    ushort* P = Pb[wave];

    for (int kt = 0; kt < 704; kt += 32) {
        bf16x8 b0 = load8s(base + (size_t)min(kt + l16,      L_MAX - 1) * 256 + 128 + hh * 32 + quad * 8);
        bf16x8 b1 = load8s(base + (size_t)min(kt + 16 + l16, L_MAX - 1) * 256 + 128 + hh * 32 + quad * 8);
        f32x4 z = {};
        f32x4 st00 = MFMA16(b0, a0, z, 0, 0, 0);   // S^T[k][q]
        f32x4 st01 = MFMA16(b0, a1, z, 0, 0, 0);
        f32x4 st10 = MFMA16(b1, a0, z, 0, 0, 0);
        f32x4 st11 = MFMA16(b1, a1, z, 0, 0, 0);

        const int kc0 = kt + quad * 4, kc1 = kt + 16 + quad * 4;
#pragma unroll
        for (int qh = 0; qh < 2; qh++) {
            const f32x4 sA = qh ? st01 : st00;
            const f32x4 sB = qh ? st11 : st10;
            float w[8];
#pragma unroll
            for (int r = 0; r < 4; r++) {
                w[r]     = (kc0 + r < L) ? __expf(sA[r] * scale) : 0.f;
                w[4 + r] = (kc1 + r < L) ? __expf(sB[r] * scale) : 0.f;
                rsum[qh] += w[r] + w[4 + r];
            }
            ushort4 pk0, pk1;
            pk0.x = f2b(w[0]); pk0.y = f2b(w[1]); pk0.z = f2b(w[2]); pk0.w = f2b(w[3]);
            pk1.x = f2b(w[4]); pk1.y = f2b(w[5]); pk1.z = f2b(w[6]); pk1.w = f2b(w[7]);
            *(ushort4*)(P + (qh * 16 + l16) * SP + quad * 4)      = pk0;
            *(ushort4*)(P + (qh * 16 + l16) * SP + 16 + quad * 4) = pk1;
        }
        // wave-private P: in-wave lgkmcnt ordering suffices, no barrier
        bf16x8 p0 = load8s(P + (size_t)l16 * SP + quad * 8);
        bf16x8 p1 = load8s(P + (size_t)(16 + l16) * SP + quad * 8);
        bf16x8 v0 = load8s(vb0 + kt + quad * 8);   // V^T direct from global
        bf16x8 v1 = load8s(vb1 + kt + quad * 8);
        oacc[0][0] = MFMA16(v0, p0, oacc[0][0], 0, 0, 0);
        oacc[0][1] = MFMA16(v0, p1, oacc[0][1], 0, 0, 0);
        oacc[1][0] = MFMA16(v1, p0, oacc[1][0], 0, 0, 0);
        oacc[1][1] = MFMA16(v1, p1, oacc[1][1], 0, 0, 0);
    }

#pragma unroll
    for (int qh = 0; qh < 2; qh++) {
        float s = rsum[qh];
        s += __shfl_xor(s, 16, 64);
        s += __shfl_xor(s, 32, 64);
        const int q = q0 + qh * 16 + l16;
        if (q < L_MAX) {
            const float inv = 1.f / s;
#pragma unroll
            for (int dh = 0; dh < 2; dh++) {
                ushort4 pk;
                pk.x = f2b(oacc[dh][qh][0] * inv);
                pk.y = f2b(oacc[dh][qh][1] * inv);
                pk.z = f2b(oacc[dh][qh][2] * inv);
                pk.w = f2b(oacc[dh][qh][3] * inv);
                *(ushort4*)(o + ((size_t)(g * L_MAX + q)) * DIM + hh * 32 + dh * 16 + quad * 4) = pk;
            }
        }
    }
}

// y = LN(y + res) * g + b; writes fp32 y and bf16 yb
__global__ __launch_bounds__(128) void ln_res(
    float* __restrict__ y, const float* __restrict__ res,
    const float* __restrict__ g, const float* __restrict__ b,
    ushort* __restrict__ yb)
{
    __shared__ float sh[2], sh2[2];
    const int r = blockIdx.x, t = threadIdx.x;
    const size_t base = (size_t)r * DIM;
    float v = y[base + t] + res[base + t];
    float s = v;
    for (int off = 32; off; off >>= 1) s += __shfl_down(s, off, 64);
    if ((t & 63) == 0) sh[t >> 6] = s;
    __syncthreads();
    const float mean = (sh[0] + sh[1]) * (1.f / 128.f);
    const float d = v - mean;
    float q = d * d;
    for (int off = 32; off; off >>= 1) q += __shfl_down(q, off, 64);
    if ((t & 63) == 0) sh2[t >> 6] = q;
    __syncthreads();
    const float var = (sh2[0] + sh2[1]) * (1.f / 128.f);
    float o = d * rsqrtf(var + 1e-5f) * g[t] + b[t];
    y[base + t] = o; yb[base + t] = f2b(o);
}

__global__ __launch_bounds__(256) void pool_kernel(
    const float* __restrict__ y, const int* __restrict__ cnt, float* __restrict__ pooled)
{
    __shared__ float sh[128];
    const int g = blockIdx.x, t = threadIdx.x;
    const int c = t & 127, h = t >> 7;
    const int L = cnt[g];
    float s = 0.f;
    for (int k = h; k < L; k += 2) s += y[((size_t)g * L_MAX + k) * DIM + c];
    if (h) sh[c] = s;
    __syncthreads();
    if (!h) pooled[g * DIM + c] = (s + sh[c]) / (float)max(L, 1);
}

__global__ void build_fin(const float* __restrict__ acc, const float* __restrict__ pooled,
                          const int* __restrict__ midx, const int* __restrict__ genre,
                          ushort* __restrict__ A2)
{
    const int i = blockIdx.x, t = threadIdx.x;
    float v = (t < 128) ? acc[(size_t)midx[i] * DIM + t]
                        : pooled[genre[i] * DIM + (t - 128)];
    A2[(size_t)i * 256 + t] = f2b(v);
}

__global__ void scatter_movies(const float* __restrict__ fused, const int* __restrict__ midx,
                               float* __restrict__ out)
{
    const int i = blockIdx.x, c = threadIdx.x;
    out[(size_t)midx[i] * DIM + c] = fused[(size_t)i * DIM + c];
}

extern "C" void kernel_launch(void* const* d_in, const int* in_sizes, int n_in,
                              void* d_out, int out_size, void* d_ws, size_t ws_size,
                              hipStream_t stream)
{
    const float* x      = (const float*)d_in[0];
    const int* e[3]     = { (const int*)d_in[1], (const int*)d_in[2], (const int*)d_in[3] };
    const int* midx     = (const int*)d_in[4];
    const int* genre    = (const int*)d_in[5];
    const float* gatW   = (const float*)d_in[6];
    const float* attS   = (const float*)d_in[7];
    const float* attD   = (const float*)d_in[8];
    const float* gatB   = (const float*)d_in[9];
    const float* decW   = (const float*)d_in[10];
    const float* decB   = (const float*)d_in[11];
    const float* qkvW   = (const float*)d_in[12];
    const float* qkvB   = (const float*)d_in[13];
    const float* outW   = (const float*)d_in[14];
    const float* outB   = (const float*)d_in[15];
    const float* ln1g   = (const float*)d_in[16];
    const float* ln1b   = (const float*)d_in[17];
    const float* ln2g   = (const float*)d_in[18];
    const float* ln2b   = (const float*)d_in[19];
    const float* fw1    = (const float*)d_in[20];
    const float* fb1    = (const float*)d_in[21];
    const float* fw2    = (const float*)d_in[22];
    const float* fb2    = (const float*)d_in[23];
    const float* fusW   = (const float*)d_in[24];
    const float* fusB   = (const float*)d_in[25];
    float* out = (float*)d_out;

    // ---- workspace layout (float offsets from R); peak ~119 MB ----
    float* ws  = (float*)d_ws;
    float* acc = ws;                              // 6,400,000 f32
    float* R   = ws + 6400000;
    // stage A:
    ushort* xb   = (ushort*)(R);                  // 6.4M shorts
    ushort* hb   = (ushort*)(R + 3200000);        // 6.4M shorts
    ushort* gbx  = (ushort*)(R + 6400000);        // 6.4M shorts
    float*  als  = R + 9600000;                   // 200,000
    float*  ald  = R + 9800000;                   // 200,000
    int*   cntA  = (int*)(R + 10000000);          // 50,000
    int*   offA  = (int*)(R + 10050000);          // 50,001
    int*   curA  = (int*)(R + 10100004);          // 50,000
    int*   srcsA = (int*)(R + 10150004);          // 450,000
    ushort* gatWb= (ushort*)(R + 10600004);       // 49,152 shorts
    ushort* decWb= (ushort*)(R + 10624580);       // 49,152 shorts
    int*    bsum = (int*)(R + 10649156);          // 256
    // stage B (aliases stage A):
    float*  ybuf  = R;                            // 2,611,200
    float*  tmp   = R + 2611200;                  // 2,611,200
    ushort* ybx   = (ushort*)(R + 5222400);       // 2,611,200 shorts
    ushort* attnb = (ushort*)(R + 6528000);       // 2,611,200 shorts
    ushort* qkvb  = (ushort*)(R + 7833600);       // 5,222,400 shorts (Q,K stride 256)
    ushort* vtg   = (ushort*)(R + 10444800);      // 2,611,200 shorts (V^T [128][20400];
                                                  //  ≤64-short tail reads spill into midb — P=0 there)
    ushort* midb  = (ushort*)(R + 11750400);      // 20,889,600 shorts
    ushort* finb  = midb;                         // 5,222,400 shorts
    float*  pooled= R + 22195200;                 // 3,840
    int*    cntb  = (int*)(R + 22199040);         // 32
    int*    posb  = cntb + 32;                    // 20,400
    ushort* qkvWb = (ushort*)(R + 22220000);      // 196,608 shorts
    ushort* outWb = (ushort*)(R + 22318304);      // 65,536 shorts
    ushort* fw1b  = (ushort*)(R + 22351072);      // 1,048,576 shorts
    ushort* fw2b  = (ushort*)(R + 22875360);      // 1,048,576 shorts
    ushort* fusWb = (ushort*)(R + 23399648);      // 32,768 shorts

    const float decay[3] = { 1.0f, 0.90483741803595952f, 0.81873075307798182f };

    // ================= Stage A: 3-hop GAT =================
    cvt32<<<(6400000 / 8 + 255) / 256, 256, 0, stream>>>(x, xb, 6400000 / 8);
    cvt32<<<(49152 / 8 + 255) / 256, 256, 0, stream>>>(gatW, gatWb, 49152 / 8);
    cvt32<<<(49152 / 8 + 255) / 256, 256, 0, stream>>>(decW, decWb, 49152 / 8);
    for (int k = 0; k < 3; k++) {
        gemm_lds<128, 0, 0, 1><<<dim3(391, 1), 256, 0, stream>>>(
            xb, gatWb + k * DIM * DIM, nullptr, hb, N_NODES, DIM, DIM, 1.f);
        gat_al<<<(N_NODES * 4 + 255) / 256, 256, 0, stream>>>(
            hb, attS + k * DIM, attD + k * DIM, als, ald, N_NODES);
        hipMemsetAsync(cntA, 0, N_NODES * 4, stream);
        csr_deg<<<(N_EDGES + 255) / 256, 256, 0, stream>>>(e[k] + N_EDGES, cntA);
        scan_blk<<<SCAN_NBLK, 256, 0, stream>>>(cntA, offA, bsum);
        scan_top<<<1, 256, 0, stream>>>(bsum);
        scan_add<<<SCAN_NBLK, 256, 0, stream>>>(offA, bsum, curA);
        csr_scat<<<(N_EDGES + N_NODES + 255) / 256, 256, 0, stream>>>(
            e[k], e[k] + N_EDGES, curA, srcsA);
        gat_gather<<<(N_NODES * 64 + 255) / 256, 256, 0, stream>>>(
            offA, srcsA, hb, als, ald, gatB + k * DIM, gbx);
        if (k == 0)
            gemm_lds<128, 1, 0, 0><<<dim3(391, 1), 256, 0, stream>>>(
                gbx, decWb, decB, acc, N_NODES, DIM, DIM, 1.f);
        else
            gemm_lds<128, 1, 1, 0><<<dim3(391, 1), 256, 0, stream>>>(
                gbx, decWb + k * DIM * DIM, decB + k * DIM, acc, N_NODES, DIM, DIM, decay[k]);
    }

    // ================= Stage B: genre transformer =================
    cvt32<<<(196608 / 8 + 255) / 256, 256, 0, stream>>>(qkvW, qkvWb, 196608 / 8);
    cvt32<<<(65536 / 8 + 255) / 256, 256, 0, stream>>>(outW, outWb, 65536 / 8);
    cvt32<<<(1048576 / 8 + 255) / 256, 256, 0, stream>>>(fw1, fw1b, 1048576 / 8);
    cvt32<<<(1048576 / 8 + 255) / 256, 256, 0, stream>>>(fw2, fw2b, 1048576 / 8);
    cvt32<<<(32768 / 8 + 255) / 256, 256, 0, stream>>>(fusW, fusWb, 32768 / 8);

    hipMemsetAsync(cntb, 0, 32 * 4, stream);
    calc_pos<<<(N_MOVIE + 255) / 256, 256, 0, stream>>>(genre, posb, cntb, N_MOVIE);
    build_y<<<N_MOVIE, 128, 0, stream>>>(acc, midx, genre, posb, ybuf, ybx);

    const int CH_ROWS = 10200;   // 2 FFN chunks
    for (int l = 0; l < N_LAYERS; l++) {
        // Q,K projection -> qkvb [row][256]
        gemm_lds<128, 0, 0, 1><<<dim3(160, 2), 256, 0, stream>>>(
            ybx, qkvWb + (size_t)l * 384 * DIM, qkvB + l * 384, qkvb, NROWS, 256, DIM, 1.f);
        // V projection, transposed store -> vtg [d][20400]
        gemm_lds<128, 0, 0, 2><<<dim3(160, 1), 256, 0, stream>>>(
            ybx, qkvWb + (size_t)l * 384 * DIM + 256 * DIM, qkvB + l * 384 + 256,
            vtg, NROWS, DIM, DIM, 1.f);
        flash_attn<<<dim3(6, 4, 30), 256, 0, stream>>>(qkvb, vtg, cntb, attnb);
        gemm_lds<64, 0, 0, 0><<<dim3(319, 1), 256, 0, stream>>>(
            attnb, outWb + (size_t)l * DIM * DIM, outB + l * DIM, tmp, NROWS, DIM, DIM, 1.f);
        ln_res<<<NROWS, 128, 0, stream>>>(ybuf, tmp, ln1g + l * DIM, ln1b + l * DIM, ybx);
        for (int ch = 0; ch < 2; ch++) {
            const size_t ro = (size_t)ch * CH_ROWS * DIM;
            gemm_lds<128, 2, 0, 1><<<dim3(80, 16), 256, 0, stream>>>(
                ybx + ro, fw1b + (size_t)l * FF * DIM, fb1 + l * FF,
                midb, CH_ROWS, FF, DIM, 1.f);
            gemm_lds<64, 0, 0, 0><<<dim3(160, 1), 256, 0, stream>>>(
                midb, fw2b + (size_t)l * FF * DIM, fb2 + l * DIM,
                tmp + ro, CH_ROWS, DIM, FF, 1.f);
        }
        ln_res<<<NROWS, 128, 0, stream>>>(ybuf, tmp, ln2g + l * DIM, ln2b + l * DIM, ybx);
    }

    pool_kernel<<<N_GENRE, 256, 0, stream>>>(ybuf, cntb, pooled);
    build_fin<<<N_MOVIE, 256, 0, stream>>>(acc, pooled, midx, genre, finb);
    gemm_lds<64, 1, 0, 0><<<dim3(319, 1), 256, 0, stream>>>(
        finb, fusWb, fusB, tmp, NROWS, DIM, 256, 1.f);

    hipMemcpyAsync(out, acc, (size_t)6400000 * 4, hipMemcpyDeviceToDevice, stream);
    scatter_movies<<<N_MOVIE, 128, 0, stream>>>(tmp, midx, out);
}

// Round 9
// 1558.942 us; speedup vs baseline: 6.9213x; 1.0563x over previous
//
#include <hip/hip_runtime.h>

#define N_NODES  50000
#define N_EDGES  400000
#define DIM      128
#define N_MOVIE  20400
#define N_GENRE  30
#define L_MAX    680
#define NROWS    (N_GENRE * L_MAX)   /* 20400 */
#define FF       2048
#define N_LAYERS 4
#define SCAN_NBLK 196               /* ceil(50000/256) */
#define OFFS     (N_NODES + 1)
#define EPG      (N_EDGES + N_NODES) /* 450000 entries per graph */

typedef __attribute__((ext_vector_type(8))) short bf16x8;
typedef __attribute__((ext_vector_type(4))) float f32x4;

#define MFMA16 __builtin_amdgcn_mfma_f32_16x16x32_bf16

__device__ __forceinline__ float b2f(ushort u) {
    union { unsigned i; float f; } c; c.i = ((unsigned)u) << 16; return c.f;
}
__device__ __forceinline__ ushort f2b(float f) {
    union { float f; unsigned i; } c; c.f = f;
    unsigned u = c.i;
    u += 0x7FFFu + ((u >> 16) & 1u);   // RNE
    return (ushort)(u >> 16);
}
__device__ __forceinline__ bf16x8 load8s(const ushort* p) {
    return *(const bf16x8*)p;
}
__device__ __forceinline__ void async16(const ushort* g, ushort* l) {
    __builtin_amdgcn_global_load_lds(
        (const __attribute__((address_space(1))) void*)g,
        (__attribute__((address_space(3))) void*)l, 16, 0, 0);
}

// fp32 -> bf16, 8 elems/thread
__global__ void cvt32(const float* __restrict__ s, ushort* __restrict__ d, int n8)
{
    int i = blockIdx.x * blockDim.x + threadIdx.x;
    if (i >= n8) return;
    const float4* q = (const float4*)(s + (size_t)i * 8);
    float4 a = q[0], b = q[1];
    bf16x8 r;
    r[0] = (short)f2b(a.x); r[1] = (short)f2b(a.y);
    r[2] = (short)f2b(a.z); r[3] = (short)f2b(a.w);
    r[4] = (short)f2b(b.x); r[5] = (short)f2b(b.y);
    r[6] = (short)f2b(b.z); r[7] = (short)f2b(b.w);
    *(bf16x8*)(d + (size_t)i * 8) = r;
}

// ============ LDS-staged GEMM: C[M,N] = epi(A @ W^T + bias) ============
// OBF: 0 = f32 out, 1 = bf16 out, 2 = bf16 TRANSPOSED out (Cv[col*M + row]).
template<int BM, int ACT, int EPI, int OBF>
__global__ __launch_bounds__(256) void gemm_lds(
    const ushort* __restrict__ A, const ushort* __restrict__ W,
    const float* __restrict__ bias, void* __restrict__ Cv,
    int M, int N, int K, float scale)
{
    __shared__ ushort As[BM * 32];
    __shared__ ushort Ws[128 * 32];
    const int tid  = threadIdx.x;
    const int wave = tid >> 6, lane = tid & 63;
    const int quad = lane >> 4, l16 = lane & 15;
    const int m0 = blockIdx.x * BM;
    const int n0 = blockIdx.y * 128;

    constexpr int MT = BM / 32;
    const int mbase = (wave & 1) * (BM / 2);
    const int nbase = (wave >> 1) * 64;

    const int srow = wave * 16 + (lane >> 2);
    const int skof = (lane & 3) * 8;

    f32x4 acc[MT][4] = {};
    for (int k0 = 0; k0 < K; k0 += 32) {
#pragma unroll
        for (int i = 0; i < BM / 64; i++) {
            int r = i * 64 + srow;
            int rg = min(m0 + r, M - 1);
            async16(A + (size_t)rg * K + k0 + skof, As + r * 32 + skof);
        }
#pragma unroll
        for (int i = 0; i < 2; i++) {
            int r = i * 64 + srow;
            async16(W + (size_t)(n0 + r) * K + k0 + skof, Ws + r * 32 + skof);
        }
        __syncthreads();

        bf16x8 a[MT], b[4];
#pragma unroll
        for (int mt = 0; mt < MT; mt++)
            a[mt] = load8s(As + (mbase + mt * 16 + l16) * 32 + quad * 8);
#pragma unroll
        for (int nt = 0; nt < 4; nt++)
            b[nt] = load8s(Ws + (nbase + nt * 16 + l16) * 32 + quad * 8);
#pragma unroll
        for (int mt = 0; mt < MT; mt++)
#pragma unroll
            for (int nt = 0; nt < 4; nt++)
                acc[mt][nt] = MFMA16(a[mt], b[nt], acc[mt][nt], 0, 0, 0);
        __syncthreads();
    }

#pragma unroll
    for (int nt = 0; nt < 4; nt++) {
        const int col = n0 + nbase + nt * 16 + l16;
        const float bv = bias ? bias[col] : 0.f;
#pragma unroll
        for (int mt = 0; mt < MT; mt++) {
            if (OBF == 2) {
                const int row0 = m0 + mbase + mt * 16 + quad * 4;
                if (row0 < M) {
                    ushort4 pk;
                    pk.x = f2b(acc[mt][nt][0] + bv);
                    pk.y = f2b(acc[mt][nt][1] + bv);
                    pk.z = f2b(acc[mt][nt][2] + bv);
                    pk.w = f2b(acc[mt][nt][3] + bv);
                    *(ushort4*)((ushort*)Cv + (size_t)col * M + row0) = pk;
                }
            } else {
#pragma unroll
                for (int r = 0; r < 4; r++) {
                    const int row = m0 + mbase + mt * 16 + quad * 4 + r;
                    if (row < M) {
                        float v = acc[mt][nt][r] + bv;
                        if (ACT == 1) v = (v >= 0.f) ? v : 0.01f * v;
                        if (ACT == 2) v = fmaxf(v, 0.f);
                        const size_t idx = (size_t)row * N + col;
                        if (OBF == 1)      ((ushort*)Cv)[idx] = f2b(v);
                        else if (EPI == 1) ((float*)Cv)[idx] += scale * v;
                        else               ((float*)Cv)[idx] = v;
                    }
                }
            }
        }
    }
}

// per-(node,head) attention logit halves (h in bf16)
__global__ void gat_al(const ushort* __restrict__ h,
                       const float* __restrict__ asrc, const float* __restrict__ adst,
                       float* __restrict__ als, float* __restrict__ ald, int N)
{
    int idx = blockIdx.x * blockDim.x + threadIdx.x;
    if (idx >= N * 4) return;
    int n = idx >> 2, hh = idx & 3;
    const ushort* hp = h + (size_t)n * DIM + hh * 32;
    float s = 0.f, d = 0.f;
#pragma unroll 8
    for (int c = 0; c < 32; c++) {
        float v = b2f(hp[c]);
        s += v * asrc[hh * 32 + c];
        d += v * adst[hh * 32 + c];
    }
    als[idx] = s; ald[idx] = d;
}

// ---------------- batched CSR build (3 graphs in one pass) ----------------
__global__ void csr_deg3(const int* __restrict__ d0, const int* __restrict__ d1,
                         const int* __restrict__ d2, int* __restrict__ cnt)
{
    int i = blockIdx.x * 256 + threadIdx.x;
    int g = blockIdx.y;
    const int* d = (g == 0) ? d0 : (g == 1) ? d1 : d2;
    if (i < N_EDGES) atomicAdd(&cnt[(size_t)g * N_NODES + d[i]], 1);
}

__global__ __launch_bounds__(256) void scan_blk3(
    const int* __restrict__ cnt, int* __restrict__ off, int* __restrict__ bsum)
{
    __shared__ int sh[256];
    const int g = blockIdx.y, t = threadIdx.x;
    const int i = blockIdx.x * 256 + t;
    int v = (i < N_NODES) ? cnt[(size_t)g * N_NODES + i] + 1 : 0;   // +1 self-loop
    sh[t] = v;
    __syncthreads();
    for (int d = 1; d < 256; d <<= 1) {
        int x = (t >= d) ? sh[t - d] : 0;
        __syncthreads();
        sh[t] += x;
        __syncthreads();
    }
    if (i < N_NODES) off[(size_t)g * OFFS + i] = sh[t] - v;
    if (t == 255) bsum[g * 256 + blockIdx.x] = sh[255];
}
__global__ __launch_bounds__(256) void scan_top3(int* __restrict__ bsum)
{
    __shared__ int sh[256];
    const int g = blockIdx.x, t = threadIdx.x;
    int v = (t < SCAN_NBLK) ? bsum[g * 256 + t] : 0;
    sh[t] = v;
    __syncthreads();
    for (int d = 1; d < 256; d <<= 1) {
        int x = (t >= d) ? sh[t - d] : 0;
        __syncthreads();
        sh[t] += x;
        __syncthreads();
    }
    if (t < SCAN_NBLK) bsum[g * 256 + t] = sh[t] - v;
}
__global__ __launch_bounds__(256) void scan_add3(
    int* __restrict__ off, const int* __restrict__ bsum, int* __restrict__ cur)
{
    const int g = blockIdx.y;
    const int i = blockIdx.x * 256 + threadIdx.x;
    if (i < N_NODES) {
        int o = off[(size_t)g * OFFS + i] + bsum[g * 256 + blockIdx.x];
        off[(size_t)g * OFFS + i] = o;
        cur[(size_t)g * N_NODES + i] = o;
    }
    if (i == 0) off[(size_t)g * OFFS + N_NODES] = EPG;
}
__global__ void csr_scat3(const int* __restrict__ e0, const int* __restrict__ e1,
                          const int* __restrict__ e2, int* __restrict__ cur,
                          int* __restrict__ srcs)
{
    int i = blockIdx.x * 256 + threadIdx.x;
    int g = blockIdx.y;
    const int* e = (g == 0) ? e0 : (g == 1) ? e1 : e2;
    int* curg = cur + (size_t)g * N_NODES;
    int* srcg = srcs + (size_t)g * EPG;
    if (i < N_EDGES) {
        int p = atomicAdd(&curg[e[N_EDGES + i]], 1);
        srcg[p] = e[i];
    } else if (i < EPG) {
        int n = i - N_EDGES;
        int p = atomicAdd(&curg[n], 1);
        srcg[p] = n;   // self-loop
    }
}

// one wave per dst: registers accumulate sum(w*h[src]) & sum(w); fold norm+bias; bf16 out
__global__ __launch_bounds__(256) void gat_gather(
    const int* __restrict__ off, const int* __restrict__ srcs,
    const ushort* __restrict__ hb, const float* __restrict__ als,
    const float* __restrict__ ald, const float* __restrict__ bias,
    ushort* __restrict__ ob)
{
    int w = (blockIdx.x * 256 + threadIdx.x) >> 6;
    int lane = threadIdx.x & 63;
    if (w >= N_NODES) return;
    const int h0 = lane >> 5, h1 = 2 + h0;
    const float ad0 = ald[(size_t)w * 4 + h0], ad1 = ald[(size_t)w * 4 + h1];
    const int jb = off[w], je = off[w + 1];
    float acc0 = 0.f, acc1 = 0.f, ws0 = 0.f, ws1 = 0.f;
    for (int j = jb; j < je; j++) {
        int s = srcs[j];
        float e0 = als[(size_t)s * 4 + h0] + ad0; e0 = (e0 >= 0.f) ? e0 : 0.2f * e0;
        float e1 = als[(size_t)s * 4 + h1] + ad1; e1 = (e1 >= 0.f) ? e1 : 0.2f * e1;
        float w0 = __expf(e0), w1 = __expf(e1);
        ws0 += w0; ws1 += w1;
        acc0 += w0 * b2f(hb[(size_t)s * DIM + lane]);
        acc1 += w1 * b2f(hb[(size_t)s * DIM + 64 + lane]);
    }
    ob[(size_t)w * DIM + lane]      = f2b(acc0 / ws0 + bias[lane]);
    ob[(size_t)w * DIM + 64 + lane] = f2b(acc1 / ws1 + bias[64 + lane]);
}

__global__ void calc_pos(const int* __restrict__ genre, int* __restrict__ pos,
                         int* __restrict__ cnt, int NM)
{
    int i = blockIdx.x * blockDim.x + threadIdx.x;
    if (i < NM) pos[i] = atomicAdd(&cnt[genre[i]], 1);
}

__global__ void build_y(const float* __restrict__ acc, const int* __restrict__ midx,
                        const int* __restrict__ genre, const int* __restrict__ pos,
                        float* __restrict__ y, ushort* __restrict__ yb)
{
    int i = blockIdx.x, c = threadIdx.x;
    int g = genre[i], p = pos[i];
    float v = acc[(size_t)midx[i] * DIM + c];
    size_t o = ((size_t)g * L_MAX + p) * DIM + c;
    y[o] = v; yb[o] = f2b(v);
}

// ======== barrier-free flash attention: V^T pre-transposed in global ========
#define SP 40    /* P row stride in shorts (80 B, 16B-aligned) */

__global__ __launch_bounds__(256) void flash_attn(
    const ushort* __restrict__ qk, const ushort* __restrict__ vtg,
    const int* __restrict__ cnt, ushort* __restrict__ o)
{
    __shared__ ushort Pb[4][32 * SP];     // 10240 B, wave-private tiles

    const int qt = blockIdx.x, hh = blockIdx.y, g = blockIdx.z;
    const int t = threadIdx.x, wave = t >> 6, lane = t & 63;
    const int quad = lane >> 4, l16 = lane & 15;
    const int L = cnt[g];
    const float scale = 0.17677669529663687f;   // 1/sqrt(32)
    const ushort* base = qk + (size_t)g * L_MAX * 256;
    const ushort* vb0 = vtg + (size_t)(hh * 32 + l16) * NROWS + g * L_MAX;
    const ushort* vb1 = vb0 + (size_t)16 * NROWS;

    const int q0 = qt * 128 + wave * 32;
    bf16x8 a0 = load8s(base + (size_t)min(q0 + l16,      L_MAX - 1) * 256 + hh * 32 + quad * 8);
    bf16x8 a1 = load8s(base + (size_t)min(q0 + 16 + l16, L_MAX - 1) * 256 + hh * 32 + quad * 8);

    f32x4 oacc[2][2] = {};        // [dhalf][qhalf], O^T layout
    float rsum[2] = {0.f, 0.f};   // per qhalf (q = l16), quad-partial
    ushort* P = Pb[wave];

    for (int kt = 0; kt < 704; kt += 32) {
        bf16x8 b0 = load8s(base + (size_t)min(kt + l16,      L_MAX - 1) * 256 + 128 + hh * 32 + quad * 8);
        bf16x8 b1 = load8s(base + (size_t)min(kt + 16 + l16, L_MAX - 1) * 256 + 128 + hh * 32 + quad * 8);
        f32x4 z = {};
        f32x4 st00 = MFMA16(b0, a0, z, 0, 0, 0);   // S^T[k][q]
        f32x4 st01 = MFMA16(b0, a1, z, 0, 0, 0);
        f32x4 st10 = MFMA16(b1, a0, z, 0, 0, 0);
        f32x4 st11 = MFMA16(b1, a1, z, 0, 0, 0);

        const int kc0 = kt + quad * 4, kc1 = kt + 16 + quad * 4;
#pragma unroll
        for (int qh = 0; qh < 2; qh++) {
            const f32x4 sA = qh ? st01 : st00;
            const f32x4 sB = qh ? st11 : st10;
            float w[8];
#pragma unroll
            for (int r = 0; r < 4; r++) {
                w[r]     = (kc0 + r < L) ? __expf(sA[r] * scale) : 0.f;
                w[4 + r] = (kc1 + r < L) ? __expf(sB[r] * scale) : 0.f;
                rsum[qh] += w[r] + w[4 + r];
            }
            ushort4 pk0, pk1;
            pk0.x = f2b(w[0]); pk0.y = f2b(w[1]); pk0.z = f2b(w[2]); pk0.w = f2b(w[3]);
            pk1.x = f2b(w[4]); pk1.y = f2b(w[5]); pk1.z = f2b(w[6]); pk1.w = f2b(w[7]);
            *(ushort4*)(P + (qh * 16 + l16) * SP + quad * 4)      = pk0;
            *(ushort4*)(P + (qh * 16 + l16) * SP + 16 + quad * 4) = pk1;
        }
        // wave-private P: in-wave lgkmcnt ordering suffices, no barrier
        bf16x8 p0 = load8s(P + (size_t)l16 * SP + quad * 8);
        bf16x8 p1 = load8s(P + (size_t)(16 + l16) * SP + quad * 8);
        bf16x8 v0 = load8s(vb0 + kt + quad * 8);   // V^T direct from global
        bf16x8 v1 = load8s(vb1 + kt + quad * 8);
        oacc[0][0] = MFMA16(v0, p0, oacc[0][0], 0, 0, 0);
        oacc[0][1] = MFMA16(v0, p1, oacc[0][1], 0, 0, 0);
        oacc[1][0] = MFMA16(v1, p0, oacc[1][0], 0, 0, 0);
        oacc[1][1] = MFMA16(v1, p1, oacc[1][1], 0, 0, 0);
    }

#pragma unroll
    for (int qh = 0; qh < 2; qh++) {
        float s = rsum[qh];
        s += __shfl_xor(s, 16, 64);
        s += __shfl_xor(s, 32, 64);
        const int q = q0 + qh * 16 + l16;
        if (q < L_MAX) {
            const float inv = 1.f / s;
#pragma unroll
            for (int dh = 0; dh < 2; dh++) {
                ushort4 pk;
                pk.x = f2b(oacc[dh][qh][0] * inv);
                pk.y = f2b(oacc[dh][qh][1] * inv);
                pk.z = f2b(oacc[dh][qh][2] * inv);
                pk.w = f2b(oacc[dh][qh][3] * inv);
                *(ushort4*)(o + ((size_t)(g * L_MAX + q)) * DIM + hh * 32 + dh * 16 + quad * 4) = pk;
            }
        }
    }
}

// y = LN(y + res) * g + b; writes fp32 y and bf16 yb
__global__ __launch_bounds__(128) void ln_res(
    float* __restrict__ y, const float* __restrict__ res,
    const float* __restrict__ g, const float* __restrict__ b,
    ushort* __restrict__ yb)
{
    __shared__ float sh[2], sh2[2];
    const int r = blockIdx.x, t = threadIdx.x;
    const size_t base = (size_t)r * DIM;
    float v = y[base + t] + res[base + t];
    float s = v;
    for (int off = 32; off; off >>= 1) s += __shfl_down(s, off, 64);
    if ((t & 63) == 0) sh[t >> 6] = s;
    __syncthreads();
    const float mean = (sh[0] + sh[1]) * (1.f / 128.f);
    const float d = v - mean;
    float q = d * d;
    for (int off = 32; off; off >>= 1) q += __shfl_down(q, off, 64);
    if ((t & 63) == 0) sh2[t >> 6] = q;
    __syncthreads();
    const float var = (sh2[0] + sh2[1]) * (1.f / 128.f);
    float o = d * rsqrtf(var + 1e-5f) * g[t] + b[t];
    y[base + t] = o; yb[base + t] = f2b(o);
}

// parallel mean-pool: grid (genre, 17 segments of 40 rows); atomicAdd partial/L
__global__ __launch_bounds__(256) void pool_partial(
    const float* __restrict__ y, const int* __restrict__ cnt, float* __restrict__ pooled)
{
    __shared__ float sh[128];
    const int g = blockIdx.x, seg = blockIdx.y, t = threadIdx.x;
    const int c = t & 127, h = t >> 7;
    const int L = cnt[g];
    const int k0 = seg * 40, k1 = min(k0 + 40, L);
    float s = 0.f;
    for (int k = k0 + h; k < k1; k += 2) s += y[((size_t)g * L_MAX + k) * DIM + c];
    if (h) sh[c] = s;
    __syncthreads();
    if (!h) {
        float tot = s + sh[c];
        if (k0 < L) atomicAdd(&pooled[g * DIM + c], tot / (float)max(L, 1));
    }
}

__global__ void build_fin(const float* __restrict__ acc, const float* __restrict__ pooled,
                          const int* __restrict__ midx, const int* __restrict__ genre,
                          ushort* __restrict__ A2)
{
    const int i = blockIdx.x, t = threadIdx.x;
    float v = (t < 128) ? acc[(size_t)midx[i] * DIM + t]
                        : pooled[genre[i] * DIM + (t - 128)];
    A2[(size_t)i * 256 + t] = f2b(v);
}

__global__ void scatter_movies(const float* __restrict__ fused, const int* __restrict__ midx,
                               float* __restrict__ out)
{
    const int i = blockIdx.x, c = threadIdx.x;
    out[(size_t)midx[i] * DIM + c] = fused[(size_t)i * DIM + c];
}

extern "C" void kernel_launch(void* const* d_in, const int* in_sizes, int n_in,
                              void* d_out, int out_size, void* d_ws, size_t ws_size,
                              hipStream_t stream)
{
    const float* x      = (const float*)d_in[0];
    const int* e[3]     = { (const int*)d_in[1], (const int*)d_in[2], (const int*)d_in[3] };
    const int* midx     = (const int*)d_in[4];
    const int* genre    = (const int*)d_in[5];
    const float* gatW   = (const float*)d_in[6];
    const float* attS   = (const float*)d_in[7];
    const float* attD   = (const float*)d_in[8];
    const float* gatB   = (const float*)d_in[9];
    const float* decW   = (const float*)d_in[10];
    const float* decB   = (const float*)d_in[11];
    const float* qkvW   = (const float*)d_in[12];
    const float* qkvB   = (const float*)d_in[13];
    const float* outW   = (const float*)d_in[14];
    const float* outB   = (const float*)d_in[15];
    const float* ln1g   = (const float*)d_in[16];
    const float* ln1b   = (const float*)d_in[17];
    const float* ln2g   = (const float*)d_in[18];
    const float* ln2b   = (const float*)d_in[19];
    const float* fw1    = (const float*)d_in[20];
    const float* fb1    = (const float*)d_in[21];
    const float* fw2    = (const float*)d_in[22];
    const float* fb2    = (const float*)d_in[23];
    const float* fusW   = (const float*)d_in[24];
    const float* fusB   = (const float*)d_in[25];
    float* out = (float*)d_out;

    // ---- workspace layout (float offsets from R); peak ~119 MB ----
    float* ws  = (float*)d_ws;
    float* acc = ws;                              // 6,400,000 f32
    float* R   = ws + 6400000;
    // stage A:
    ushort* xb   = (ushort*)(R);                  // 6.4M shorts
    ushort* hb   = (ushort*)(R + 3200000);        // 6.4M shorts
    ushort* gbx  = (ushort*)(R + 6400000);        // 6.4M shorts
    float*  als  = R + 9600000;                   // 200,000
    float*  ald  = R + 9800000;                   // 200,000
    int*   cnt3  = (int*)(R + 10000000);          // 150,000
    int*   off3  = (int*)(R + 10150000);          // 150,003
    int*   cur3  = (int*)(R + 10300004);          // 150,000
    int*   srcs3 = (int*)(R + 10450004);          // 1,350,000
    ushort* gatWb= (ushort*)(R + 11800004);       // 49,152 shorts
    ushort* decWb= (ushort*)(R + 11824580);       // 49,152 shorts
    int*    bsum3= (int*)(R + 11849156);          // 768
    // stage B (aliases stage A):
    float*  ybuf  = R;                            // 2,611,200
    float*  tmp   = R + 2611200;                  // 2,611,200
    ushort* ybx   = (ushort*)(R + 5222400);       // 2,611,200 shorts
    ushort* attnb = (ushort*)(R + 6528000);       // 2,611,200 shorts
    ushort* qkvb  = (ushort*)(R + 7833600);       // 5,222,400 shorts (Q,K stride 256)
    ushort* vtg   = (ushort*)(R + 10444800);      // 2,611,200 shorts (V^T [128][20400])
    ushort* midb  = (ushort*)(R + 11750400);      // 20,889,600 shorts
    ushort* finb  = midb;                         // 5,222,400 shorts
    float*  pooled= R + 22195200;                 // 3,840
    int*    cntb  = (int*)(R + 22199040);         // 32
    int*    posb  = cntb + 32;                    // 20,400
    ushort* qkvWb = (ushort*)(R + 22220000);      // 196,608 shorts
    ushort* outWb = (ushort*)(R + 22318304);      // 65,536 shorts
    ushort* fw1b  = (ushort*)(R + 22351072);      // 1,048,576 shorts
    ushort* fw2b  = (ushort*)(R + 22875360);      // 1,048,576 shorts
    ushort* fusWb = (ushort*)(R + 23399648);      // 32,768 shorts

    const float decay[3] = { 1.0f, 0.90483741803595952f, 0.81873075307798182f };

    // ================= Stage A: 3-hop GAT =================
    cvt32<<<(6400000 / 8 + 255) / 256, 256, 0, stream>>>(x, xb, 6400000 / 8);
    cvt32<<<(49152 / 8 + 255) / 256, 256, 0, stream>>>(gatW, gatWb, 49152 / 8);
    cvt32<<<(49152 / 8 + 255) / 256, 256, 0, stream>>>(decW, decWb, 49152 / 8);

    // batched CSR build for all 3 hops (independent of GEMMs)
    hipMemsetAsync(cnt3, 0, (size_t)150000 * 4, stream);
    csr_deg3<<<dim3((N_EDGES + 255) / 256, 3), 256, 0, stream>>>(
        e[0] + N_EDGES, e[1] + N_EDGES, e[2] + N_EDGES, cnt3);
    scan_blk3<<<dim3(SCAN_NBLK, 3), 256, 0, stream>>>(cnt3, off3, bsum3);
    scan_top3<<<3, 256, 0, stream>>>(bsum3);
    scan_add3<<<dim3(SCAN_NBLK, 3), 256, 0, stream>>>(off3, bsum3, cur3);
    csr_scat3<<<dim3((EPG + 255) / 256, 3), 256, 0, stream>>>(
        e[0], e[1], e[2], cur3, srcs3);

    for (int k = 0; k < 3; k++) {
        gemm_lds<128, 0, 0, 1><<<dim3(391, 1), 256, 0, stream>>>(
            xb, gatWb + k * DIM * DIM, nullptr, hb, N_NODES, DIM, DIM, 1.f);
        gat_al<<<(N_NODES * 4 + 255) / 256, 256, 0, stream>>>(
            hb, attS + k * DIM, attD + k * DIM, als, ald, N_NODES);
        gat_gather<<<(N_NODES * 64 + 255) / 256, 256, 0, stream>>>(
            off3 + (size_t)k * OFFS, srcs3 + (size_t)k * EPG,
            hb, als, ald, gatB + k * DIM, gbx);
        if (k == 0)
            gemm_lds<128, 1, 0, 0><<<dim3(391, 1), 256, 0, stream>>>(
                gbx, decWb, decB, acc, N_NODES, DIM, DIM, 1.f);
        else
            gemm_lds<128, 1, 1, 0><<<dim3(391, 1), 256, 0, stream>>>(
                gbx, decWb + k * DIM * DIM, decB + k * DIM, acc, N_NODES, DIM, DIM, decay[k]);
    }

    // ================= Stage B: genre transformer =================
    cvt32<<<(196608 / 8 + 255) / 256, 256, 0, stream>>>(qkvW, qkvWb, 196608 / 8);
    cvt32<<<(65536 / 8 + 255) / 256, 256, 0, stream>>>(outW, outWb, 65536 / 8);
    cvt32<<<(1048576 / 8 + 255) / 256, 256, 0, stream>>>(fw1, fw1b, 1048576 / 8);
    cvt32<<<(1048576 / 8 + 255) / 256, 256, 0, stream>>>(fw2, fw2b, 1048576 / 8);
    cvt32<<<(32768 / 8 + 255) / 256, 256, 0, stream>>>(fusW, fusWb, 32768 / 8);

    hipMemsetAsync(cntb, 0, 32 * 4, stream);
    calc_pos<<<(N_MOVIE + 255) / 256, 256, 0, stream>>>(genre, posb, cntb, N_MOVIE);
    build_y<<<N_MOVIE, 128, 0, stream>>>(acc, midx, genre, posb, ybuf, ybx);

    const int CH_ROWS = 10200;   // 2 FFN chunks
    for (int l = 0; l < N_LAYERS; l++) {
        gemm_lds<128, 0, 0, 1><<<dim3(160, 2), 256, 0, stream>>>(
            ybx, qkvWb + (size_t)l * 384 * DIM, qkvB + l * 384, qkvb, NROWS, 256, DIM, 1.f);
        gemm_lds<128, 0, 0, 2><<<dim3(160, 1), 256, 0, stream>>>(
            ybx, qkvWb + (size_t)l * 384 * DIM + 256 * DIM, qkvB + l * 384 + 256,
            vtg, NROWS, DIM, DIM, 1.f);
        flash_attn<<<dim3(6, 4, 30), 256, 0, stream>>>(qkvb, vtg, cntb, attnb);
        gemm_lds<64, 0, 0, 0><<<dim3(319, 1), 256, 0, stream>>>(
            attnb, outWb + (size_t)l * DIM * DIM, outB + l * DIM, tmp, NROWS, DIM, DIM, 1.f);
        ln_res<<<NROWS, 128, 0, stream>>>(ybuf, tmp, ln1g + l * DIM, ln1b + l * DIM, ybx);
        for (int ch = 0; ch < 2; ch++) {
            const size_t ro = (size_t)ch * CH_ROWS * DIM;
            gemm_lds<128, 2, 0, 1><<<dim3(80, 16), 256, 0, stream>>>(
                ybx + ro, fw1b + (size_t)l * FF * DIM, fb1 + l * FF,
                midb, CH_ROWS, FF, DIM, 1.f);
            gemm_lds<64, 0, 0, 0><<<dim3(160, 1), 256, 0, stream>>>(
                midb, fw2b + (size_t)l * FF * DIM, fb2 + l * DIM,
                tmp + ro, CH_ROWS, DIM, FF, 1.f);
        }
        ln_res<<<NROWS, 128, 0, stream>>>(ybuf, tmp, ln2g + l * DIM, ln2b + l * DIM, ybx);
    }

    hipMemsetAsync(pooled, 0, 3840 * 4, stream);
    pool_partial<<<dim3(N_GENRE, 17), 256, 0, stream>>>(ybuf, cntb, pooled);
    build_fin<<<N_MOVIE, 256, 0, stream>>>(acc, pooled, midx, genre, finb);
    gemm_lds<64, 1, 0, 0><<<dim3(319, 1), 256, 0, stream>>>(
        finb, fusWb, fusB, tmp, NROWS, DIM, 256, 1.f);

    hipMemcpyAsync(out, acc, (size_t)6400000 * 4, hipMemcpyDeviceToDevice, stream);
    scatter_movies<<<N_MOVIE, 128, 0, stream>>>(tmp, midx, out);
}

// Round 10
// 1453.093 us; speedup vs baseline: 7.4255x; 1.0728x over previous
//
#include <hip/hip_runtime.h>

#define N_NODES  50000
#define N_EDGES  400000
#define DIM      128
#define N_MOVIE  20400
#define N_GENRE  30
#define L_MAX    680
#define NROWS    (N_GENRE * L_MAX)   /* 20400 */
#define FF       2048
#define N_LAYERS 4

// bucketed CSR build
#define NBKT 98          /* bucket = dst >> 9 (512 nodes per bucket) */
#define NPB  512
#define ECAP 4608        /* edges per bucket capacity (mean 4096 + 8 sigma) */
#define SCAP 5120        /* CSR per bucket capacity (edges + selfs) */
#define EPGB (NBKT * ECAP)
#define SPGB (NBKT * SCAP)

typedef __attribute__((ext_vector_type(8))) short bf16x8;
typedef __attribute__((ext_vector_type(4))) float f32x4;

#define MFMA16 __builtin_amdgcn_mfma_f32_16x16x32_bf16

__device__ __forceinline__ float b2f(ushort u) {
    union { unsigned i; float f; } c; c.i = ((unsigned)u) << 16; return c.f;
}
__device__ __forceinline__ ushort f2b(float f) {
    union { float f; unsigned i; } c; c.f = f;
    unsigned u = c.i;
    u += 0x7FFFu + ((u >> 16) & 1u);   // RNE
    return (ushort)(u >> 16);
}
__device__ __forceinline__ bf16x8 load8s(const ushort* p) {
    return *(const bf16x8*)p;
}
__device__ __forceinline__ void async16(const ushort* g, ushort* l) {
    __builtin_amdgcn_global_load_lds(
        (const __attribute__((address_space(1))) void*)g,
        (__attribute__((address_space(3))) void*)l, 16, 0, 0);
}

__device__ __forceinline__ void cvt8(const float* s, ushort* d, int i) {
    const float4* q = (const float4*)(s + (size_t)i * 8);
    float4 a = q[0], b = q[1];
    bf16x8 r;
    r[0] = (short)f2b(a.x); r[1] = (short)f2b(a.y);
    r[2] = (short)f2b(a.z); r[3] = (short)f2b(a.w);
    r[4] = (short)f2b(b.x); r[5] = (short)f2b(b.y);
    r[6] = (short)f2b(b.z); r[7] = (short)f2b(b.w);
    *(bf16x8*)(d + (size_t)i * 8) = r;
}

// fp32 -> bf16, 8 elems/thread
__global__ void cvt32(const float* __restrict__ s, ushort* __restrict__ d, int n8)
{
    int i = blockIdx.x * blockDim.x + threadIdx.x;
    if (i < n8) cvt8(s, d, i);
}

// all 7 weight tensors in one launch (blockIdx.y selects tensor)
__global__ void cvt_w(const float* gatW, const float* decW, const float* qkvW,
                      const float* outW, const float* fw1, const float* fw2,
                      const float* fusW,
                      ushort* gatWb, ushort* decWb, ushort* qkvWb,
                      ushort* outWb, ushort* fw1b, ushort* fw2b, ushort* fusWb)
{
    const float* s; ushort* d; int n8;
    switch (blockIdx.y) {
        case 0: s = gatW; d = gatWb; n8 = 49152 / 8; break;
        case 1: s = decW; d = decWb; n8 = 49152 / 8; break;
        case 2: s = qkvW; d = qkvWb; n8 = 196608 / 8; break;
        case 3: s = outW; d = outWb; n8 = 65536 / 8; break;
        case 4: s = fw1;  d = fw1b;  n8 = 1048576 / 8; break;
        case 5: s = fw2;  d = fw2b;  n8 = 1048576 / 8; break;
        default: s = fusW; d = fusWb; n8 = 32768 / 8; break;
    }
    int i = blockIdx.x * 256 + threadIdx.x;
    if (i < n8) cvt8(s, d, i);
}

// ============ LDS-staged GEMM: C[M,N] = epi(A @ W^T + bias) ============
// OBF: 0 = f32 out, 1 = bf16 out, 2 = bf16 TRANSPOSED out (Cv[col*M + row]).
template<int BM, int ACT, int EPI, int OBF>
__global__ __launch_bounds__(256) void gemm_lds(
    const ushort* __restrict__ A, const ushort* __restrict__ W,
    const float* __restrict__ bias, void* __restrict__ Cv,
    int M, int N, int K, float scale)
{
    __shared__ ushort As[BM * 32];
    __shared__ ushort Ws[128 * 32];
    const int tid  = threadIdx.x;
    const int wave = tid >> 6, lane = tid & 63;
    const int quad = lane >> 4, l16 = lane & 15;
    const int m0 = blockIdx.x * BM;
    const int n0 = blockIdx.y * 128;

    constexpr int MT = BM / 32;
    const int mbase = (wave & 1) * (BM / 2);
    const int nbase = (wave >> 1) * 64;

    const int srow = wave * 16 + (lane >> 2);
    const int skof = (lane & 3) * 8;

    f32x4 acc[MT][4] = {};
    for (int k0 = 0; k0 < K; k0 += 32) {
#pragma unroll
        for (int i = 0; i < BM / 64; i++) {
            int r = i * 64 + srow;
            int rg = min(m0 + r, M - 1);
            async16(A + (size_t)rg * K + k0 + skof, As + r * 32 + skof);
        }
#pragma unroll
        for (int i = 0; i < 2; i++) {
            int r = i * 64 + srow;
            async16(W + (size_t)(n0 + r) * K + k0 + skof, Ws + r * 32 + skof);
        }
        __syncthreads();

        bf16x8 a[MT], b[4];
#pragma unroll
        for (int mt = 0; mt < MT; mt++)
            a[mt] = load8s(As + (mbase + mt * 16 + l16) * 32 + quad * 8);
#pragma unroll
        for (int nt = 0; nt < 4; nt++)
            b[nt] = load8s(Ws + (nbase + nt * 16 + l16) * 32 + quad * 8);
#pragma unroll
        for (int mt = 0; mt < MT; mt++)
#pragma unroll
            for (int nt = 0; nt < 4; nt++)
                acc[mt][nt] = MFMA16(a[mt], b[nt], acc[mt][nt], 0, 0, 0);
        __syncthreads();
    }

#pragma unroll
    for (int nt = 0; nt < 4; nt++) {
        const int col = n0 + nbase + nt * 16 + l16;
        const float bv = bias ? bias[col] : 0.f;
#pragma unroll
        for (int mt = 0; mt < MT; mt++) {
            if (OBF == 2) {
                const int row0 = m0 + mbase + mt * 16 + quad * 4;
                if (row0 < M) {
                    ushort4 pk;
                    pk.x = f2b(acc[mt][nt][0] + bv);
                    pk.y = f2b(acc[mt][nt][1] + bv);
                    pk.z = f2b(acc[mt][nt][2] + bv);
                    pk.w = f2b(acc[mt][nt][3] + bv);
                    *(ushort4*)((ushort*)Cv + (size_t)col * M + row0) = pk;
                }
            } else {
#pragma unroll
                for (int r = 0; r < 4; r++) {
                    const int row = m0 + mbase + mt * 16 + quad * 4 + r;
                    if (row < M) {
                        float v = acc[mt][nt][r] + bv;
                        if (ACT == 1) v = (v >= 0.f) ? v : 0.01f * v;
                        if (ACT == 2) v = fmaxf(v, 0.f);
                        const size_t idx = (size_t)row * N + col;
                        if (OBF == 1)      ((ushort*)Cv)[idx] = f2b(v);
                        else if (EPI == 1) ((float*)Cv)[idx] += scale * v;
                        else               ((float*)Cv)[idx] = v;
                    }
                }
            }
        }
    }
}

// per-(node,head) attention logit halves (h in bf16)
__global__ void gat_al(const ushort* __restrict__ h,
                       const float* __restrict__ asrc, const float* __restrict__ adst,
                       float* __restrict__ als, float* __restrict__ ald, int N)
{
    int idx = blockIdx.x * blockDim.x + threadIdx.x;
    if (idx >= N * 4) return;
    int n = idx >> 2, hh = idx & 3;
    const ushort* hp = h + (size_t)n * DIM + hh * 32;
    float s = 0.f, d = 0.f;
#pragma unroll 8
    for (int c = 0; c < 32; c++) {
        float v = b2f(hp[c]);
        s += v * asrc[hh * 32 + c];
        d += v * adst[hh * 32 + c];
    }
    als[idx] = s; ald[idx] = d;
}

// ---------------- bucketed CSR build ----------------
// bcur: [3*NBKT] counters, one per 16-int line; init to b*ECAP
__global__ void csr_initb(int* __restrict__ bcur)
{
    int i = blockIdx.x * 256 + threadIdx.x;
    if (i < 3 * NBKT) bcur[i * 16] = (i % NBKT) * ECAP;
}

// route edges into per-bucket regions; block-local LDS hist -> one atomic/bucket
__global__ __launch_bounds__(256) void csr_route(
    const int* __restrict__ e0, const int* __restrict__ e1, const int* __restrict__ e2,
    int* __restrict__ bcur, int* __restrict__ ebuf)
{
    __shared__ int hist[NBKT], base[NBKT], cur[NBKT];
    const int g = blockIdx.y, t = threadIdx.x;
    const int* e = (g == 0) ? e0 : (g == 1) ? e1 : e2;
    const int i0 = blockIdx.x * 4096;
    for (int j = t; j < NBKT; j += 256) { hist[j] = 0; cur[j] = 0; }
    __syncthreads();
    unsigned pk[16]; int bk[16];
#pragma unroll
    for (int j = 0; j < 16; j++) {
        int i = i0 + j * 256 + t;
        if (i < N_EDGES) {
            int s = e[i], d = e[N_EDGES + i];
            bk[j] = d >> 9;
            pk[j] = (unsigned)s | ((unsigned)(d & 511) << 16);
            atomicAdd(&hist[bk[j]], 1);
        } else bk[j] = -1;
    }
    __syncthreads();
    for (int j = t; j < NBKT; j += 256)
        if (hist[j]) base[j] = atomicAdd(&bcur[(g * NBKT + j) * 16], hist[j]);
    __syncthreads();
#pragma unroll
    for (int j = 0; j < 16; j++)
        if (bk[j] >= 0) {
            int p = base[bk[j]] + atomicAdd(&cur[bk[j]], 1);
            ebuf[(size_t)g * EPGB + p] = (int)pk[j];
        }
}

// per-bucket: LDS hist (+self) -> scan -> off/deg -> scatter srcs (block-local writes)
__global__ __launch_bounds__(256) void csr_build(
    const int* __restrict__ bcur, const int* __restrict__ ebuf,
    int* __restrict__ off, int* __restrict__ deg, int* __restrict__ srcs)
{
    __shared__ int hist[NPB];
    __shared__ int part[256];
    const int g = blockIdx.y, b = blockIdx.x, t = threadIdx.x;
    const int nb0 = b * NPB;
    const int nn = min(NPB, N_NODES - nb0);
    const int cnt = bcur[(g * NBKT + b) * 16] - b * ECAP;
    const int* eb = ebuf + (size_t)g * EPGB + b * ECAP;

    for (int j = t; j < NPB; j += 256) hist[j] = (j < nn) ? 1 : 0;   // self-loop
    __syncthreads();
    for (int i = t; i < cnt; i += 256)
        atomicAdd(&hist[(eb[i] >> 16) & 511], 1);
    __syncthreads();

    // exclusive scan over NPB=512 (2 elems/thread)
    int a0 = hist[t * 2], a1 = hist[t * 2 + 1];
    int sum = a0 + a1;
    part[t] = sum;
    __syncthreads();
    for (int d = 1; d < 256; d <<= 1) {
        int x = (t >= d) ? part[t - d] : 0;
        __syncthreads();
        part[t] += x;
        __syncthreads();
    }
    const int excl = part[t] - sum;
    __syncthreads();
    const int sb = b * SCAP;
    hist[t * 2]     = excl;
    hist[t * 2 + 1] = excl + a0;
    if (t * 2 < nn) {
        off[(size_t)g * N_NODES + nb0 + t * 2] = sb + excl;
        deg[(size_t)g * N_NODES + nb0 + t * 2] = a0;
    }
    if (t * 2 + 1 < nn) {
        off[(size_t)g * N_NODES + nb0 + t * 2 + 1] = sb + excl + a0;
        deg[(size_t)g * N_NODES + nb0 + t * 2 + 1] = a1;
    }
    __syncthreads();

    int* sg = srcs + (size_t)g * SPGB + sb;
    for (int i = t; i < cnt; i += 256) {
        int v = eb[i];
        int p = atomicAdd(&hist[(v >> 16) & 511], 1);
        sg[p] = v & 0xFFFF;
    }
    for (int j = t; j < nn; j += 256) {
        int p = atomicAdd(&hist[j], 1);
        sg[p] = nb0 + j;
    }
}

// one wave per dst: accumulate sum(w*h[src]) & sum(w); fold norm+bias; bf16 out
__global__ __launch_bounds__(256) void gat_gather(
    const int* __restrict__ off, const int* __restrict__ deg, const int* __restrict__ srcs,
    const ushort* __restrict__ hb, const float* __restrict__ als,
    const float* __restrict__ ald, const float* __restrict__ bias,
    ushort* __restrict__ ob)
{
    int w = (blockIdx.x * 256 + threadIdx.x) >> 6;
    int lane = threadIdx.x & 63;
    if (w >= N_NODES) return;
    const int h0 = lane >> 5, h1 = 2 + h0;
    const float ad0 = ald[(size_t)w * 4 + h0], ad1 = ald[(size_t)w * 4 + h1];
    const int jb = off[w], je = jb + deg[w];
    float acc0 = 0.f, acc1 = 0.f, ws0 = 0.f, ws1 = 0.f;
    for (int j = jb; j < je; j++) {
        int s = srcs[j];
        float e0 = als[(size_t)s * 4 + h0] + ad0; e0 = (e0 >= 0.f) ? e0 : 0.2f * e0;
        float e1 = als[(size_t)s * 4 + h1] + ad1; e1 = (e1 >= 0.f) ? e1 : 0.2f * e1;
        float w0 = __expf(e0), w1 = __expf(e1);
        ws0 += w0; ws1 += w1;
        acc0 += w0 * b2f(hb[(size_t)s * DIM + lane]);
        acc1 += w1 * b2f(hb[(size_t)s * DIM + 64 + lane]);
    }
    ob[(size_t)w * DIM + lane]      = f2b(acc0 / ws0 + bias[lane]);
    ob[(size_t)w * DIM + 64 + lane] = f2b(acc1 / ws1 + bias[64 + lane]);
}

__global__ void calc_pos(const int* __restrict__ genre, int* __restrict__ pos,
                         int* __restrict__ cnt, int NM)
{
    int i = blockIdx.x * blockDim.x + threadIdx.x;
    if (i < NM) pos[i] = atomicAdd(&cnt[genre[i]], 1);
}

__global__ void build_y(const float* __restrict__ acc, const int* __restrict__ midx,
                        const int* __restrict__ genre, const int* __restrict__ pos,
                        float* __restrict__ y, ushort* __restrict__ yb)
{
    int i = blockIdx.x, c = threadIdx.x;
    int g = genre[i], p = pos[i];
    float v = acc[(size_t)midx[i] * DIM + c];
    size_t o = ((size_t)g * L_MAX + p) * DIM + c;
    y[o] = v; yb[o] = f2b(v);
}

// ======== barrier-free flash attention: V^T pre-transposed in global ========
#define SP 40    /* P row stride in shorts (80 B, 16B-aligned) */

__global__ __launch_bounds__(256) void flash_attn(
    const ushort* __restrict__ qk, const ushort* __restrict__ vtg,
    const int* __restrict__ cnt, ushort* __restrict__ o)
{
    __shared__ ushort Pb[4][32 * SP];     // 10240 B, wave-private tiles

    const int qt = blockIdx.x, hh = blockIdx.y, g = blockIdx.z;
    const int t = threadIdx.x, wave = t >> 6, lane = t & 63;
    const int quad = lane >> 4, l16 = lane & 15;
    const int L = cnt[g];
    const float scale = 0.17677669529663687f;   // 1/sqrt(32)
    const ushort* base = qk + (size_t)g * L_MAX * 256;
    const ushort* vb0 = vtg + (size_t)(hh * 32 + l16) * NROWS + g * L_MAX;
    const ushort* vb1 = vb0 + (size_t)16 * NROWS;

    const int q0 = qt * 128 + wave * 32;
    bf16x8 a0 = load8s(base + (size_t)min(q0 + l16,      L_MAX - 1) * 256 + hh * 32 + quad * 8);
    bf16x8 a1 = load8s(base + (size_t)min(q0 + 16 + l16, L_MAX - 1) * 256 + hh * 32 + quad * 8);

    f32x4 oacc[2][2] = {};        // [dhalf][qhalf], O^T layout
    float rsum[2] = {0.f, 0.f};
    ushort* P = Pb[wave];

    for (int kt = 0; kt < 704; kt += 32) {
        bf16x8 b0 = load8s(base + (size_t)min(kt + l16,      L_MAX - 1) * 256 + 128 + hh * 32 + quad * 8);
        bf16x8 b1 = load8s(base + (size_t)min(kt + 16 + l16, L_MAX - 1) * 256 + 128 + hh * 32 + quad * 8);
        f32x4 z = {};
        f32x4 st00 = MFMA16(b0, a0, z, 0, 0, 0);   // S^T[k][q]
        f32x4 st01 = MFMA16(b0, a1, z, 0, 0, 0);
        f32x4 st10 = MFMA16(b1, a0, z, 0, 0, 0);
        f32x4 st11 = MFMA16(b1, a1, z, 0, 0, 0);

        const int kc0 = kt + quad * 4, kc1 = kt + 16 + quad * 4;
#pragma unroll
        for (int qh = 0; qh < 2; qh++) {
            const f32x4 sA = qh ? st01 : st00;
            const f32x4 sB = qh ? st11 : st10;
            float w[8];
#pragma unroll
            for (int r = 0; r < 4; r++) {
                w[r]     = (kc0 + r < L) ? __expf(sA[r] * scale) : 0.f;
                w[4 + r] = (kc1 + r < L) ? __expf(sB[r] * scale) : 0.f;
                rsum[qh] += w[r] + w[4 + r];
            }
            ushort4 pk0, pk1;
            pk0.x = f2b(w[0]); pk0.y = f2b(w[1]); pk0.z = f2b(w[2]); pk0.w = f2b(w[3]);
            pk1.x = f2b(w[4]); pk1.y = f2b(w[5]); pk1.z = f2b(w[6]); pk1.w = f2b(w[7]);
            *(ushort4*)(P + (qh * 16 + l16) * SP + quad * 4)      = pk0;
            *(ushort4*)(P + (qh * 16 + l16) * SP + 16 + quad * 4) = pk1;
        }
        bf16x8 p0 = load8s(P + (size_t)l16 * SP + quad * 8);
        bf16x8 p1 = load8s(P + (size_t)(16 + l16) * SP + quad * 8);
        bf16x8 v0 = load8s(vb0 + kt + quad * 8);
        bf16x8 v1 = load8s(vb1 + kt + quad * 8);
        oacc[0][0] = MFMA16(v0, p0, oacc[0][0], 0, 0, 0);
        oacc[0][1] = MFMA16(v0, p1, oacc[0][1], 0, 0, 0);
        oacc[1][0] = MFMA16(v1, p0, oacc[1][0], 0, 0, 0);
        oacc[1][1] = MFMA16(v1, p1, oacc[1][1], 0, 0, 0);
    }

#pragma unroll
    for (int qh = 0; qh < 2; qh++) {
        float s = rsum[qh];
        s += __shfl_xor(s, 16, 64);
        s += __shfl_xor(s, 32, 64);
        const int q = q0 + qh * 16 + l16;
        if (q < L_MAX) {
            const float inv = 1.f / s;
#pragma unroll
            for (int dh = 0; dh < 2; dh++) {
                ushort4 pk;
                pk.x = f2b(oacc[dh][qh][0] * inv);
                pk.y = f2b(oacc[dh][qh][1] * inv);
                pk.z = f2b(oacc[dh][qh][2] * inv);
                pk.w = f2b(oacc[dh][qh][3] * inv);
                *(ushort4*)(o + ((size_t)(g * L_MAX + q)) * DIM + hh * 32 + dh * 16 + quad * 4) = pk;
            }
        }
    }
}

// y = LN(y + res) * g + b; writes fp32 y and bf16 yb
__global__ __launch_bounds__(128) void ln_res(
    float* __restrict__ y, const float* __restrict__ res,
    const float* __restrict__ g, const float* __restrict__ b,
    ushort* __restrict__ yb)
{
    __shared__ float sh[2], sh2[2];
    const int r = blockIdx.x, t = threadIdx.x;
    const size_t base = (size_t)r * DIM;
    float v = y[base + t] + res[base + t];
    float s = v;
    for (int off = 32; off; off >>= 1) s += __shfl_down(s, off, 64);
    if ((t & 63) == 0) sh[t >> 6] = s;
    __syncthreads();
    const float mean = (sh[0] + sh[1]) * (1.f / 128.f);
    const float d = v - mean;
    float q = d * d;
    for (int off = 32; off; off >>= 1) q += __shfl_down(q, off, 64);
    if ((t & 63) == 0) sh2[t >> 6] = q;
    __syncthreads();
    const float var = (sh2[0] + sh2[1]) * (1.f / 128.f);
    float o = d * rsqrtf(var + 1e-5f) * g[t] + b[t];
    y[base + t] = o; yb[base + t] = f2b(o);
}

// parallel mean-pool: grid (genre, 17 segments of 40 rows)
__global__ __launch_bounds__(256) void pool_partial(
    const float* __restrict__ y, const int* __restrict__ cnt, float* __restrict__ pooled)
{
    __shared__ float sh[128];
    const int g = blockIdx.x, seg = blockIdx.y, t = threadIdx.x;
    const int c = t & 127, h = t >> 7;
    const int L = cnt[g];
    const int k0 = seg * 40, k1 = min(k0 + 40, L);
    float s = 0.f;
    for (int k = k0 + h; k < k1; k += 2) s += y[((size_t)g * L_MAX + k) * DIM + c];
    if (h) sh[c] = s;
    __syncthreads();
    if (!h) {
        float tot = s + sh[c];
        if (k0 < L) atomicAdd(&pooled[g * DIM + c], tot / (float)max(L, 1));
    }
}

__global__ void build_fin(const float* __restrict__ acc, const float* __restrict__ pooled,
                          const int* __restrict__ midx, const int* __restrict__ genre,
                          ushort* __restrict__ A2)
{
    const int i = blockIdx.x, t = threadIdx.x;
    float v = (t < 128) ? acc[(size_t)midx[i] * DIM + t]
                        : pooled[genre[i] * DIM + (t - 128)];
    A2[(size_t)i * 256 + t] = f2b(v);
}

__global__ void scatter_movies(const float* __restrict__ fused, const int* __restrict__ midx,
                               float* __restrict__ out)
{
    const int i = blockIdx.x, c = threadIdx.x;
    out[(size_t)midx[i] * DIM + c] = fused[(size_t)i * DIM + c];
}

extern "C" void kernel_launch(void* const* d_in, const int* in_sizes, int n_in,
                              void* d_out, int out_size, void* d_ws, size_t ws_size,
                              hipStream_t stream)
{
    const float* x      = (const float*)d_in[0];
    const int* e[3]     = { (const int*)d_in[1], (const int*)d_in[2], (const int*)d_in[3] };
    const int* midx     = (const int*)d_in[4];
    const int* genre    = (const int*)d_in[5];
    const float* gatW   = (const float*)d_in[6];
    const float* attS   = (const float*)d_in[7];
    const float* attD   = (const float*)d_in[8];
    const float* gatB   = (const float*)d_in[9];
    const float* decW   = (const float*)d_in[10];
    const float* decB   = (const float*)d_in[11];
    const float* qkvW   = (const float*)d_in[12];
    const float* qkvB   = (const float*)d_in[13];
    const float* outW   = (const float*)d_in[14];
    const float* outB   = (const float*)d_in[15];
    const float* ln1g   = (const float*)d_in[16];
    const float* ln1b   = (const float*)d_in[17];
    const float* ln2g   = (const float*)d_in[18];
    const float* ln2b   = (const float*)d_in[19];
    const float* fw1    = (const float*)d_in[20];
    const float* fb1    = (const float*)d_in[21];
    const float* fw2    = (const float*)d_in[22];
    const float* fb2    = (const float*)d_in[23];
    const float* fusW   = (const float*)d_in[24];
    const float* fusB   = (const float*)d_in[25];
    float* out = (float*)d_out;

    // ---- workspace layout (float offsets from R) ----
    float* ws  = (float*)d_ws;
    float* acc = ws;                              // 6,400,000 f32
    float* R   = ws + 6400000;
    // stage A:
    ushort* xb   = (ushort*)(R);                  // 6.4M shorts
    ushort* hb   = (ushort*)(R + 3200000);        // 6.4M shorts
    ushort* gbx  = (ushort*)(R + 6400000);        // 6.4M shorts
    float*  als  = R + 9600000;                   // 200,000
    float*  ald  = R + 9800000;                   // 200,000
    int*   bcur  = (int*)(R + 10000000);          // 4,704 (3*98 x 16-int lines)
    int*   ebuf  = (int*)(R + 10004736);          // 1,354,752
    int*   off3  = (int*)(R + 11359488);          // 150,000
    int*   deg3  = (int*)(R + 11509488);          // 150,000
    int*   srcs3 = (int*)(R + 11659488);          // 1,505,280
    ushort* gatWb= (ushort*)(R + 13164768);       // 49,152 shorts
    ushort* decWb= (ushort*)(R + 13189344);       // 49,152 shorts
    // stage B (aliases stage A):
    float*  ybuf  = R;                            // 2,611,200
    float*  tmp   = R + 2611200;                  // 2,611,200
    ushort* ybx   = (ushort*)(R + 5222400);       // 2,611,200 shorts
    ushort* attnb = (ushort*)(R + 6528000);       // 2,611,200 shorts
    ushort* qkvb  = (ushort*)(R + 7833600);       // 5,222,400 shorts (Q,K stride 256)
    ushort* vtg   = (ushort*)(R + 10444800);      // 2,611,200 shorts (V^T [128][20400])
    ushort* midb  = (ushort*)(R + 11750400);      // 20,889,600 shorts
    ushort* finb  = midb;                         // 5,222,400 shorts
    float*  pooled= R + 22195200;                 // 3,840
    int*    cntb  = (int*)(R + 22199040);         // 32
    int*    posb  = cntb + 32;                    // 20,400
    ushort* qkvWb = (ushort*)(R + 22220000);      // 196,608 shorts
    ushort* outWb = (ushort*)(R + 22318304);      // 65,536 shorts
    ushort* fw1b  = (ushort*)(R + 22351072);      // 1,048,576 shorts
    ushort* fw2b  = (ushort*)(R + 22875360);      // 1,048,576 shorts
    ushort* fusWb = (ushort*)(R + 23399648);      // 32,768 shorts

    const float decay[3] = { 1.0f, 0.90483741803595952f, 0.81873075307798182f };

    // ================= weight conversions (one launch) + x =================
    cvt_w<<<dim3(512, 7), 256, 0, stream>>>(
        gatW, decW, qkvW, outW, fw1, fw2, fusW,
        gatWb, decWb, qkvWb, outWb, fw1b, fw2b, fusWb);
    cvt32<<<(6400000 / 8 + 255) / 256, 256, 0, stream>>>(x, xb, 6400000 / 8);

    // ================= bucketed CSR build (all 3 hops) =================
    csr_initb<<<(3 * NBKT + 255) / 256, 256, 0, stream>>>(bcur);
    csr_route<<<dim3((N_EDGES + 4095) / 4096, 3), 256, 0, stream>>>(
        e[0], e[1], e[2], bcur, ebuf);
    csr_build<<<dim3(NBKT, 3), 256, 0, stream>>>(bcur, ebuf, off3, deg3, srcs3);

    // ================= Stage A: 3-hop GAT =================
    for (int k = 0; k < 3; k++) {
        gemm_lds<128, 0, 0, 1><<<dim3(391, 1), 256, 0, stream>>>(
            xb, gatWb + k * DIM * DIM, nullptr, hb, N_NODES, DIM, DIM, 1.f);
        gat_al<<<(N_NODES * 4 + 255) / 256, 256, 0, stream>>>(
            hb, attS + k * DIM, attD + k * DIM, als, ald, N_NODES);
        gat_gather<<<(N_NODES * 64 + 255) / 256, 256, 0, stream>>>(
            off3 + (size_t)k * N_NODES, deg3 + (size_t)k * N_NODES,
            srcs3 + (size_t)k * SPGB, hb, als, ald, gatB + k * DIM, gbx);
        if (k == 0)
            gemm_lds<128, 1, 0, 0><<<dim3(391, 1), 256, 0, stream>>>(
                gbx, decWb, decB, acc, N_NODES, DIM, DIM, 1.f);
        else
            gemm_lds<128, 1, 1, 0><<<dim3(391, 1), 256, 0, stream>>>(
                gbx, decWb + k * DIM * DIM, decB + k * DIM, acc, N_NODES, DIM, DIM, decay[k]);
    }

    // ================= Stage B: genre transformer =================
    hipMemsetAsync(cntb, 0, 32 * 4, stream);
    calc_pos<<<(N_MOVIE + 255) / 256, 256, 0, stream>>>(genre, posb, cntb, N_MOVIE);
    build_y<<<N_MOVIE, 128, 0, stream>>>(acc, midx, genre, posb, ybuf, ybx);

    const int CH_ROWS = 10200;   // 2 FFN chunks
    for (int l = 0; l < N_LAYERS; l++) {
        gemm_lds<128, 0, 0, 1><<<dim3(160, 2), 256, 0, stream>>>(
            ybx, qkvWb + (size_t)l * 384 * DIM, qkvB + l * 384, qkvb, NROWS, 256, DIM, 1.f);
        gemm_lds<128, 0, 0, 2><<<dim3(160, 1), 256, 0, stream>>>(
            ybx, qkvWb + (size_t)l * 384 * DIM + 256 * DIM, qkvB + l * 384 + 256,
            vtg, NROWS, DIM, DIM, 1.f);
        flash_attn<<<dim3(6, 4, 30), 256, 0, stream>>>(qkvb, vtg, cntb, attnb);
        gemm_lds<64, 0, 0, 0><<<dim3(319, 1), 256, 0, stream>>>(
            attnb, outWb + (size_t)l * DIM * DIM, outB + l * DIM, tmp, NROWS, DIM, DIM, 1.f);
        ln_res<<<NROWS, 128, 0, stream>>>(ybuf, tmp, ln1g + l * DIM, ln1b + l * DIM, ybx);
        for (int ch = 0; ch < 2; ch++) {
            const size_t ro = (size_t)ch * CH_ROWS * DIM;
            gemm_lds<128, 2, 0, 1><<<dim3(80, 16), 256, 0, stream>>>(
                ybx + ro, fw1b + (size_t)l * FF * DIM, fb1 + l * FF,
                midb, CH_ROWS, FF, DIM, 1.f);
            gemm_lds<64, 0, 0, 0><<<dim3(160, 1), 256, 0, stream>>>(
                midb, fw2b + (size_t)l * FF * DIM, fb2 + l * DIM,
                tmp + ro, CH_ROWS, DIM, FF, 1.f);
        }
        ln_res<<<NROWS, 128, 0, stream>>>(ybuf, tmp, ln2g + l * DIM, ln2b + l * DIM, ybx);
    }

    hipMemsetAsync(pooled, 0, 3840 * 4, stream);
    pool_partial<<<dim3(N_GENRE, 17), 256, 0, stream>>>(ybuf, cntb, pooled);
    build_fin<<<N_MOVIE, 256, 0, stream>>>(acc, pooled, midx, genre, finb);
    gemm_lds<64, 1, 0, 0><<<dim3(319, 1), 256, 0, stream>>>(
        finb, fusWb, fusB, tmp, NROWS, DIM, 256, 1.f);

    hipMemcpyAsync(out, acc, (size_t)6400000 * 4, hipMemcpyDeviceToDevice, stream);
    scatter_movies<<<N_MOVIE, 128, 0, stream>>>(tmp, midx, out);
}